// Round 1
// baseline (2436.611 us; speedup 1.0000x reference)
//
#include <hip/hip_runtime.h>
#include <hip/hip_bf16.h>
#include <math.h>

#define N_USERS    100000
#define N_ITEMS    50000
#define N_ENTITIES 200000
#define N_REL      20
#define EMB        64
#define HOPS       2
#define MARGIN_CCL 0.8f
#define NUM_NEG    64
#define ANGLE_W    0.1f
#define ANGLE_DROP 0.5f
#define N_EDGES    1000000
#define NNZ        1000000
#define N_TRIPLETS 200000
#define BATCH      4096
#define EPSF       1e-6f

// butterfly reduce across the 64-lane wave; all lanes get the sum
__device__ inline float wave_red(float v) {
    for (int o = 1; o < 64; o <<= 1) v += __shfl_xor(v, o, 64);
    return v;
}

__global__ void count_kernel(const int* __restrict__ head, float* __restrict__ cnt) {
    int e = blockIdx.x * blockDim.x + threadIdx.x;
    if (e < N_EDGES) unsafeAtomicAdd(&cnt[head[e]], 1.0f);
}

// entity_agg[head] += ent_cur[tail] * relw[type-1]
__global__ void kg_scatter(const int* __restrict__ head, const int* __restrict__ tail,
                           const int* __restrict__ etype, const float* __restrict__ relw,
                           const float* __restrict__ ent_cur, float* __restrict__ ent_agg) {
    int tid = blockIdx.x * blockDim.x + threadIdx.x;
    int e = tid >> 6;
    int d = tid & 63;
    if (e >= N_EDGES) return;
    int h = head[e], t = tail[e], r = etype[e] - 1;
    float v = ent_cur[t * EMB + d] * relw[r * EMB + d];
    unsafeAtomicAdd(&ent_agg[h * EMB + d], v);
}

// usr_agg[rows] += vals*ent_cur[cols];  ucf[rows] += vals*cf_cur[cols]
__global__ void user_scatter(const int* __restrict__ rows, const int* __restrict__ cols,
                             const float* __restrict__ vals,
                             const float* __restrict__ ent_cur, const float* __restrict__ cf_cur,
                             float* __restrict__ usr_agg, float* __restrict__ ucf) {
    int tid = blockIdx.x * blockDim.x + threadIdx.x;
    int i = tid >> 6;
    int d = tid & 63;
    if (i >= NNZ) return;
    int r = rows[i], c = cols[i];
    float v = vals[i];
    unsafeAtomicAdd(&usr_agg[r * EMB + d], v * ent_cur[c * EMB + d]);
    unsafeAtomicAdd(&ucf[r * EMB + d],     v * cf_cur[c * EMB + d]);
}

// cf_agg[cols] += vals*ucf[rows]
__global__ void item_scatter(const int* __restrict__ rows, const int* __restrict__ cols,
                             const float* __restrict__ vals,
                             const float* __restrict__ ucf, float* __restrict__ cf_agg) {
    int tid = blockIdx.x * blockDim.x + threadIdx.x;
    int i = tid >> 6;
    int d = tid & 63;
    if (i >= NNZ) return;
    int r = rows[i], c = cols[i];
    float v = vals[i];
    unsafeAtomicAdd(&cf_agg[c * EMB + d], v * ucf[r * EMB + d]);
}

// normalize agg/denom in place (becomes next ent_cur); res[:N_ITEMS] += normalized
__global__ void norm_ent(const float* __restrict__ cnt, float* __restrict__ agg,
                         float* __restrict__ res) {
    int row = blockIdx.x * 4 + (threadIdx.x >> 6);
    int lane = threadIdx.x & 63;
    if (row >= N_ENTITIES) return;
    float dn = fmaxf(cnt[row], 1.0f);
    float v = agg[row * EMB + lane] / dn;
    float ss = wave_red(v * v);
    float o = v / fmaxf(sqrtf(ss), 1e-12f);
    agg[row * EMB + lane] = o;
    if (row < N_ITEMS) res[row * EMB + lane] += o;
}

__global__ void norm_user(const float* __restrict__ agg, float* __restrict__ res) {
    int row = blockIdx.x * 4 + (threadIdx.x >> 6);
    int lane = threadIdx.x & 63;
    if (row >= N_USERS) return;
    float v = agg[row * EMB + lane];
    float ss = wave_red(v * v);
    float o = v / fmaxf(sqrtf(ss), 1e-12f);
    res[row * EMB + lane] += o;
}

// normalize cf agg in place (becomes next cf_cur); res += normalized
__global__ void norm_cf(float* __restrict__ agg, float* __restrict__ res) {
    int row = blockIdx.x * 4 + (threadIdx.x >> 6);
    int lane = threadIdx.x & 63;
    if (row >= N_ITEMS) return;
    float v = agg[row * EMB + lane];
    float ss = wave_red(v * v);
    float o = v / fmaxf(sqrtf(ss), 1e-12f);
    agg[row * EMB + lane] = o;
    res[row * EMB + lane] += o;
}

// one wave (64 threads) per batch element; lane = embedding dim
__global__ void loss1_kernel(const int* __restrict__ user, const int* __restrict__ pos,
                             const int* __restrict__ neg, const float* __restrict__ usr_res,
                             const float* __restrict__ ent_res, const float* __restrict__ cf_res,
                             float* __restrict__ l1p) {
    int b = blockIdx.x;
    int lane = threadIdx.x;
    int uid = user[b];
    float uv = usr_res[uid * EMB + lane];
    float u = uv / fmaxf(sqrtf(wave_red(uv * uv)), 1e-12f);
    int pid = pos[b];
    float pv = ent_res[pid * EMB + lane];
    float p = pv / fmaxf(sqrtf(wave_red(pv * pv)), 1e-12f);
    float cv = cf_res[pid * EMB + lane];
    float pc = cv / fmaxf(sqrtf(wave_red(cv * cv)), 1e-12f);
    float dp = wave_red(u * p) + wave_red(u * pc);
    float ui_pos = fmaxf(2.0f - dp, 0.0f);
    float sum_n = 0.f, cnt_n = 0.f, sum_c = 0.f, cnt_c = 0.f;
    const int* nb = neg + b * NUM_NEG;
    for (int j = 0; j < NUM_NEG; ++j) {
        int nid = nb[j];
        float nv = ent_res[nid * EMB + lane];
        float ssn = wave_red(nv * nv);
        float dn = wave_red(u * nv);
        float s = fmaxf(dn / fmaxf(sqrtf(ssn), 1e-12f) - MARGIN_CCL, 0.0f);
        sum_n += s; if (s > 0.0f) cnt_n += 1.0f;
        float ncv = cf_res[nid * EMB + lane];
        float ssc = wave_red(ncv * ncv);
        float dc = wave_red(u * ncv);
        float sc = fmaxf(dc / fmaxf(sqrtf(ssc), 1e-12f) - MARGIN_CCL, 0.0f);
        sum_c += sc; if (sc > 0.0f) cnt_c += 1.0f;
    }
    if (lane == 0)
        l1p[b] = ui_pos + sum_n / (cnt_n + 1e-5f) + sum_c / (cnt_c + 1e-5f);
}

// one wave per triplet
__global__ void angle_kernel(const float* __restrict__ ent0,
                             const int* __restrict__ th, const int* __restrict__ tt,
                             float* __restrict__ l2p) {
    int trip = blockIdx.x * 4 + (threadIdx.x >> 6);
    int lane = threadIdx.x & 63;
    if (trip >= N_TRIPLETS) return;
    int h = th[trip], t = tt[trip];
    float hv = ent0[h * EMB + lane] * ANGLE_DROP;
    float tv = ent0[t * EMB + lane] * ANGLE_DROP;
    float s_hh = wave_red(hv * hv);
    float s_tt = wave_red(tv * tv);
    float s_ht = wave_red(hv * tv);
    float dv = hv - tv;
    float s_dd = wave_red(dv * dv);
    if (lane == 0) {
        float nu = sqrtf(s_hh), nvn = sqrtf(s_tt);
        (void)nvn;
        float dp = s_ht;
        float ed = sqrtf(s_dd);
        float sqnu = fminf(fmaxf(s_hh, 0.0f), 1.0f - EPSF);
        float ha_arg = fminf(fmaxf(0.1f * (1.0f - sqnu) / sqrtf(sqnu), -1.0f + EPSF), 1.0f - EPSF);
        float half = asinf(ha_arg);
        float num = dp * (1.0f + s_hh) - s_hh * (1.0f + s_tt);
        float den = nu * ed * sqrtf(fmaxf(1.0f + s_tt * s_hh - 2.0f * dp, EPSF)) + EPSF;
        float ang = acosf(fminf(fmaxf(num / den, -1.0f + EPSF), 1.0f - EPSF));
        l2p[trip] = fmaxf(ang - half, 0.0f);
    }
}

__global__ void finalize_kernel(const float* __restrict__ l1p, const float* __restrict__ l2p,
                                float* __restrict__ out) {
    __shared__ float sb[256];
    float acc1 = 0.f;
    for (int i = threadIdx.x; i < BATCH; i += 256) acc1 += l1p[i];
    float acc2 = 0.f;
    for (int i = threadIdx.x; i < N_TRIPLETS; i += 256) acc2 += l2p[i];
    sb[threadIdx.x] = acc1 / (float)BATCH + ANGLE_W * acc2 / (float)N_TRIPLETS;
    __syncthreads();
    for (int s = 128; s > 0; s >>= 1) {
        if (threadIdx.x < s) sb[threadIdx.x] += sb[threadIdx.x + s];
        __syncthreads();
    }
    if (threadIdx.x == 0) out[0] = sb[0];
}

extern "C" void kernel_launch(void* const* d_in, const int* in_sizes, int n_in,
                              void* d_out, int out_size, void* d_ws, size_t ws_size,
                              hipStream_t stream) {
    const float* all_embed = (const float*)d_in[0];
    const float* item_cf0  = (const float*)d_in[1];
    const float* relw      = (const float*)d_in[2];
    const float* vals      = (const float*)d_in[3];
    const int* user        = (const int*)d_in[4];
    const int* pos_item    = (const int*)d_in[5];
    const int* neg_item    = (const int*)d_in[6];
    const int* edge_head   = (const int*)d_in[7];
    const int* edge_tail   = edge_head + N_EDGES;
    const int* etype       = (const int*)d_in[8];
    const int* irows       = (const int*)d_in[9];
    const int* icols       = (const int*)d_in[10];
    const int* th          = (const int*)d_in[11];
    const int* tt          = (const int*)d_in[12];
    float* out             = (float*)d_out;

    float* w = (float*)d_ws;
    size_t off = 0;
    float* ent_a   = w + off; off += (size_t)N_ENTITIES * EMB;
    float* ent_b   = w + off; off += (size_t)N_ENTITIES * EMB;
    float* ent_res = w + off; off += (size_t)N_ITEMS * EMB;     // only items are read from ent_res
    float* usr_agg = w + off; off += (size_t)N_USERS * EMB;
    float* usr_res = w + off; off += (size_t)N_USERS * EMB;
    float* ucf     = w + off; off += (size_t)N_USERS * EMB;
    float* cf_a    = w + off; off += (size_t)N_ITEMS * EMB;
    float* cf_b    = w + off; off += (size_t)N_ITEMS * EMB;
    float* cf_res  = w + off; off += (size_t)N_ITEMS * EMB;
    float* cnt     = w + off; off += (size_t)N_ENTITIES;
    float* l1p     = w + off; off += (size_t)BATCH;
    float* l2p     = w + off; off += (size_t)N_TRIPLETS;

    const float* ent0 = all_embed + (size_t)N_USERS * EMB;

    // init residuals / current buffers
    hipMemcpyAsync(ent_a,   ent0,      (size_t)N_ENTITIES * EMB * 4, hipMemcpyDeviceToDevice, stream);
    hipMemcpyAsync(ent_res, ent0,      (size_t)N_ITEMS    * EMB * 4, hipMemcpyDeviceToDevice, stream);
    hipMemcpyAsync(usr_res, all_embed, (size_t)N_USERS    * EMB * 4, hipMemcpyDeviceToDevice, stream);
    hipMemcpyAsync(cf_a,    item_cf0,  (size_t)N_ITEMS    * EMB * 4, hipMemcpyDeviceToDevice, stream);
    hipMemcpyAsync(cf_res,  item_cf0,  (size_t)N_ITEMS    * EMB * 4, hipMemcpyDeviceToDevice, stream);

    hipMemsetAsync(cnt, 0, (size_t)N_ENTITIES * 4, stream);
    count_kernel<<<(N_EDGES + 255) / 256, 256, 0, stream>>>(edge_head, cnt);

    float* ent_cur = ent_a; float* ent_agg = ent_b;
    float* cf_cur  = cf_a;  float* cf_agg  = cf_b;

    const int scat_grid = (N_EDGES * 64) / 256;   // 250000
    const int nnz_grid  = (NNZ * 64) / 256;       // 250000

    for (int hop = 0; hop < HOPS; ++hop) {
        hipMemsetAsync(ent_agg, 0, (size_t)N_ENTITIES * EMB * 4, stream);
        hipMemsetAsync(usr_agg, 0, (size_t)N_USERS    * EMB * 4, stream);
        hipMemsetAsync(ucf,     0, (size_t)N_USERS    * EMB * 4, stream);
        hipMemsetAsync(cf_agg,  0, (size_t)N_ITEMS    * EMB * 4, stream);

        kg_scatter<<<scat_grid, 256, 0, stream>>>(edge_head, edge_tail, etype, relw, ent_cur, ent_agg);
        user_scatter<<<nnz_grid, 256, 0, stream>>>(irows, icols, vals, ent_cur, cf_cur, usr_agg, ucf);
        item_scatter<<<nnz_grid, 256, 0, stream>>>(irows, icols, vals, ucf, cf_agg);

        norm_ent<<<(N_ENTITIES + 3) / 4, 256, 0, stream>>>(cnt, ent_agg, ent_res);
        norm_user<<<(N_USERS + 3) / 4, 256, 0, stream>>>(usr_agg, usr_res);
        norm_cf<<<(N_ITEMS + 3) / 4, 256, 0, stream>>>(cf_agg, cf_res);

        float* tmp = ent_cur; ent_cur = ent_agg; ent_agg = tmp;
        tmp = cf_cur; cf_cur = cf_agg; cf_agg = tmp;
    }

    loss1_kernel<<<BATCH, 64, 0, stream>>>(user, pos_item, neg_item, usr_res, ent_res, cf_res, l1p);
    angle_kernel<<<(N_TRIPLETS + 3) / 4, 256, 0, stream>>>(ent0, th, tt, l2p);
    finalize_kernel<<<1, 256, 0, stream>>>(l1p, l2p, out);
}

// Round 2
// 1337.156 us; speedup vs baseline: 1.8222x; 1.8222x over previous
//
#include <hip/hip_runtime.h>
#include <math.h>

#define N_USERS    100000
#define N_ITEMS    50000
#define N_ENTITIES 200000
#define N_REL      20
#define EMB        64
#define HOPS       2
#define MARGIN_CCL 0.8f
#define NUM_NEG    64
#define ANGLE_W    0.1f
#define ANGLE_DROP 0.5f
#define N_EDGES    1000000
#define NNZ        1000000
#define N_TRIPLETS 200000
#define BATCH      4096
#define EPSF       1e-6f

// butterfly reduce across the 64-lane wave; all lanes get the sum
__device__ inline float wave_red(float v) {
    for (int o = 1; o < 64; o <<= 1) v += __shfl_xor(v, o, 64);
    return v;
}

// ------------------------- CSR build: histogram -------------------------
__global__ void hist_edges(const int* __restrict__ head, int* __restrict__ cnt_e) {
    int e = blockIdx.x * blockDim.x + threadIdx.x;
    if (e < N_EDGES) atomicAdd(&cnt_e[head[e]], 1);
}

__global__ void hist_inter(const int* __restrict__ rows, const int* __restrict__ cols,
                           int* __restrict__ cnt_u, int* __restrict__ cnt_i) {
    int i = blockIdx.x * blockDim.x + threadIdx.x;
    if (i < NNZ) {
        atomicAdd(&cnt_u[rows[i]], 1);
        atomicAdd(&cnt_i[cols[i]], 1);
    }
}

// ------------------------- 2-level exclusive scan -------------------------
// level 1: each block scans 1024 elements (4/thread), writes exclusive scan + block total
__global__ void scan_l1(const int* __restrict__ in, int* __restrict__ out,
                        int* __restrict__ partials, int N) {
    int base = blockIdx.x * 1024 + threadIdx.x * 4;
    int a0 = 0, a1 = 0, a2 = 0, a3 = 0;
    if (base + 0 < N) a0 = in[base + 0];
    if (base + 1 < N) a1 = in[base + 1];
    if (base + 2 < N) a2 = in[base + 2];
    if (base + 3 < N) a3 = in[base + 3];
    int tot = a0 + a1 + a2 + a3;
    __shared__ int s[256];
    s[threadIdx.x] = tot;
    __syncthreads();
    for (int d = 1; d < 256; d <<= 1) {
        int x = 0;
        if (threadIdx.x >= d) x = s[threadIdx.x - d];
        __syncthreads();
        s[threadIdx.x] += x;
        __syncthreads();
    }
    int excl = (threadIdx.x == 0) ? 0 : s[threadIdx.x - 1];
    if (threadIdx.x == 255) partials[blockIdx.x] = s[255];
    int r = excl;
    if (base + 0 < N) out[base + 0] = r; r += a0;
    if (base + 1 < N) out[base + 1] = r; r += a1;
    if (base + 2 < N) out[base + 2] = r; r += a2;
    if (base + 3 < N) out[base + 3] = r;
}

// level 2: single block exclusive-scans the partials (nb <= 256)
__global__ void scan_l2(int* __restrict__ partials, int nb) {
    __shared__ int s[256];
    int t = threadIdx.x;
    int v = (t < nb) ? partials[t] : 0;
    s[t] = v;
    __syncthreads();
    for (int d = 1; d < 256; d <<= 1) {
        int x = 0;
        if (t >= d) x = s[t - d];
        __syncthreads();
        s[t] += x;
        __syncthreads();
    }
    int excl = (t == 0) ? 0 : s[t - 1];
    if (t < nb) partials[t] = excl;
}

// level 3: add block offsets; also copy to cursor array and write off[N]=total
__global__ void scan_l3(int* __restrict__ out, int* __restrict__ cur,
                        const int* __restrict__ partials, int N, int total) {
    int i = blockIdx.x * 256 + threadIdx.x;
    if (i < N) {
        int v = out[i] + partials[i >> 10];
        out[i] = v;
        cur[i] = v;
    }
    if (i == 0) out[N] = total;
}

// ------------------------- CSR build: placement -------------------------
__global__ void place_edges(const int* __restrict__ head, const int* __restrict__ tail,
                            const int* __restrict__ etype, int* __restrict__ cur_e,
                            int* __restrict__ kg_pack) {
    int e = blockIdx.x * blockDim.x + threadIdx.x;
    if (e >= N_EDGES) return;
    int p = atomicAdd(&cur_e[head[e]], 1);
    kg_pack[p] = tail[e] | ((etype[e] - 1) << 18);   // tail<2^18, rel<32
}

__global__ void place_inter(const int* __restrict__ rows, const int* __restrict__ cols,
                            const float* __restrict__ vals,
                            int* __restrict__ cur_u, int* __restrict__ cur_i,
                            int* __restrict__ u_col, float* __restrict__ u_val,
                            int* __restrict__ i_row, float* __restrict__ i_val) {
    int i = blockIdx.x * blockDim.x + threadIdx.x;
    if (i >= NNZ) return;
    int r = rows[i], c = cols[i];
    float v = vals[i];
    int pu = atomicAdd(&cur_u[r], 1);
    u_col[pu] = c; u_val[pu] = v;
    int pi = atomicAdd(&cur_i[c], 1);
    i_row[pi] = r; i_val[pi] = v;
}

// ------------------------- hop kernels (gather + fused norm/residual) -------------------------
// one wave per entity row: mean over incident edges of ent_cur[tail]*relw[rel], l2norm,
// write next-hop table; add into ent_res (items only); normalize res in place on last hop.
__global__ void kg_agg(const int* __restrict__ off, const int* __restrict__ pack,
                       const float* __restrict__ relw, const float* __restrict__ src,
                       float* __restrict__ dst, float* __restrict__ res, int last_hop) {
    __shared__ float srel[(N_REL - 1) * EMB];
    for (int i = threadIdx.x; i < (N_REL - 1) * EMB; i += 256) srel[i] = relw[i];
    __syncthreads();
    int row = blockIdx.x * 4 + (threadIdx.x >> 6);
    int lane = threadIdx.x & 63;
    int s = off[row], e = off[row + 1];
    float acc = 0.f;
    int k = s;
    while (k < e) {
        int m = e - k; if (m > 64) m = 64;
        int pk = (lane < m) ? pack[k + lane] : 0;
        for (int j = 0; j < m; ++j) {
            int pj = __shfl(pk, j, 64);
            int t  = pj & 0x3FFFF;
            int rl = pj >> 18;
            acc += src[t * EMB + lane] * srel[rl * EMB + lane];
        }
        k += m;
    }
    float deg = (float)(e - s);
    float v = acc / fmaxf(deg, 1.0f);
    float o = v / fmaxf(sqrtf(wave_red(v * v)), 1e-12f);
    dst[row * EMB + lane] = o;
    if (row < N_ITEMS) {
        float rr = res[row * EMB + lane] + o;
        if (last_hop) rr = rr / fmaxf(sqrtf(wave_red(rr * rr)), 1e-12f);
        res[row * EMB + lane] = rr;
    }
}

// one wave per user row: usr_agg = sum v*ent_cur[col]; ucf = sum v*cf_cur[col] (raw).
__global__ void user_agg(const int* __restrict__ off, const int* __restrict__ u_col,
                         const float* __restrict__ u_val, const float* __restrict__ ent_cur,
                         const float* __restrict__ cf_cur, float* __restrict__ usr_res,
                         float* __restrict__ ucf, int last_hop) {
    int row = blockIdx.x * 4 + (threadIdx.x >> 6);
    int lane = threadIdx.x & 63;
    int s = off[row], e = off[row + 1];
    float au = 0.f, ac = 0.f;
    int k = s;
    while (k < e) {
        int m = e - k; if (m > 64) m = 64;
        int c  = (lane < m) ? u_col[k + lane] : 0;
        float v = (lane < m) ? u_val[k + lane] : 0.f;
        for (int j = 0; j < m; ++j) {
            int cj = __shfl(c, j, 64);
            float vj = __shfl(v, j, 64);
            au += vj * ent_cur[cj * EMB + lane];
            ac += vj * cf_cur[cj * EMB + lane];
        }
        k += m;
    }
    float o = au / fmaxf(sqrtf(wave_red(au * au)), 1e-12f);
    float rr = usr_res[row * EMB + lane] + o;
    if (last_hop) rr = rr / fmaxf(sqrtf(wave_red(rr * rr)), 1e-12f);
    usr_res[row * EMB + lane] = rr;
    ucf[row * EMB + lane] = ac;
}

// one wave per item col: cf_agg = sum v*ucf[row]; l2norm; residual; last-hop normalize.
__global__ void item_agg(const int* __restrict__ off, const int* __restrict__ i_row,
                         const float* __restrict__ i_val, const float* __restrict__ ucf,
                         float* __restrict__ dst, float* __restrict__ res, int last_hop) {
    int row = blockIdx.x * 4 + (threadIdx.x >> 6);
    int lane = threadIdx.x & 63;
    int s = off[row], e = off[row + 1];
    float acc = 0.f;
    int k = s;
    while (k < e) {
        int m = e - k; if (m > 64) m = 64;
        int r  = (lane < m) ? i_row[k + lane] : 0;
        float v = (lane < m) ? i_val[k + lane] : 0.f;
        for (int j = 0; j < m; ++j) {
            int rj = __shfl(r, j, 64);
            float vj = __shfl(v, j, 64);
            acc += vj * ucf[rj * EMB + lane];
        }
        k += m;
    }
    float o = acc / fmaxf(sqrtf(wave_red(acc * acc)), 1e-12f);
    dst[row * EMB + lane] = o;
    float rr = res[row * EMB + lane] + o;
    if (last_hop) rr = rr / fmaxf(sqrtf(wave_red(rr * rr)), 1e-12f);
    res[row * EMB + lane] = rr;
}

// ------------------------- losses -------------------------
// tables are pre-normalized (last-hop in-place normalize); one wave per batch element
__global__ void loss1_kernel(const int* __restrict__ user, const int* __restrict__ pos,
                             const int* __restrict__ neg, const float* __restrict__ usr_res,
                             const float* __restrict__ ent_res, const float* __restrict__ cf_res,
                             float* __restrict__ l1p) {
    int b = blockIdx.x * 4 + (threadIdx.x >> 6);
    int lane = threadIdx.x & 63;
    int uid = user[b];
    float u = usr_res[uid * EMB + lane];
    int pid = pos[b];
    float p  = ent_res[pid * EMB + lane];
    float pc = cf_res[pid * EMB + lane];
    float dp = wave_red(u * (p + pc));
    float ui_pos = fmaxf(2.0f - dp, 0.0f);
    float sum_n = 0.f, cnt_n = 0.f, sum_c = 0.f, cnt_c = 0.f;
    const int* nb = neg + b * NUM_NEG;
    for (int j = 0; j < NUM_NEG; ++j) {
        int nid = nb[j];
        float dn = wave_red(u * ent_res[nid * EMB + lane]);
        float dc = wave_red(u * cf_res[nid * EMB + lane]);
        float s  = fmaxf(dn - MARGIN_CCL, 0.0f);
        float sc = fmaxf(dc - MARGIN_CCL, 0.0f);
        sum_n += s; if (s > 0.0f) cnt_n += 1.0f;
        sum_c += sc; if (sc > 0.0f) cnt_c += 1.0f;
    }
    if (lane == 0)
        l1p[b] = ui_pos + sum_n / (cnt_n + 1e-5f) + sum_c / (cnt_c + 1e-5f);
}

__global__ void angle_kernel(const float* __restrict__ ent0,
                             const int* __restrict__ th, const int* __restrict__ tt,
                             float* __restrict__ l2p) {
    int trip = blockIdx.x * 4 + (threadIdx.x >> 6);
    int lane = threadIdx.x & 63;
    if (trip >= N_TRIPLETS) return;
    int h = th[trip], t = tt[trip];
    float hv = ent0[h * EMB + lane] * ANGLE_DROP;
    float tv = ent0[t * EMB + lane] * ANGLE_DROP;
    float s_hh = wave_red(hv * hv);
    float s_tt = wave_red(tv * tv);
    float s_ht = wave_red(hv * tv);
    float dv = hv - tv;
    float s_dd = wave_red(dv * dv);
    if (lane == 0) {
        float nu = sqrtf(s_hh);
        float dp = s_ht;
        float ed = sqrtf(s_dd);
        float sqnu = fminf(fmaxf(s_hh, 0.0f), 1.0f - EPSF);
        float ha_arg = fminf(fmaxf(0.1f * (1.0f - sqnu) / sqrtf(sqnu), -1.0f + EPSF), 1.0f - EPSF);
        float half = asinf(ha_arg);
        float num = dp * (1.0f + s_hh) - s_hh * (1.0f + s_tt);
        float den = nu * ed * sqrtf(fmaxf(1.0f + s_tt * s_hh - 2.0f * dp, EPSF)) + EPSF;
        float ang = acosf(fminf(fmaxf(num / den, -1.0f + EPSF), 1.0f - EPSF));
        l2p[trip] = fmaxf(ang - half, 0.0f);
    }
}

__global__ void finalize_kernel(const float* __restrict__ l1p, const float* __restrict__ l2p,
                                float* __restrict__ out) {
    __shared__ float sb[256];
    float acc1 = 0.f;
    for (int i = threadIdx.x; i < BATCH; i += 256) acc1 += l1p[i];
    float acc2 = 0.f;
    for (int i = threadIdx.x; i < N_TRIPLETS; i += 256) acc2 += l2p[i];
    sb[threadIdx.x] = acc1 / (float)BATCH + ANGLE_W * acc2 / (float)N_TRIPLETS;
    __syncthreads();
    for (int s = 128; s > 0; s >>= 1) {
        if (threadIdx.x < s) sb[threadIdx.x] += sb[threadIdx.x + s];
        __syncthreads();
    }
    if (threadIdx.x == 0) out[0] = sb[0];
}

extern "C" void kernel_launch(void* const* d_in, const int* in_sizes, int n_in,
                              void* d_out, int out_size, void* d_ws, size_t ws_size,
                              hipStream_t stream) {
    const float* all_embed = (const float*)d_in[0];
    const float* item_cf0  = (const float*)d_in[1];
    const float* relw      = (const float*)d_in[2];
    const float* vals      = (const float*)d_in[3];
    const int* user        = (const int*)d_in[4];
    const int* pos_item    = (const int*)d_in[5];
    const int* neg_item    = (const int*)d_in[6];
    const int* edge_head   = (const int*)d_in[7];
    const int* edge_tail   = edge_head + N_EDGES;
    const int* etype       = (const int*)d_in[8];
    const int* irows       = (const int*)d_in[9];
    const int* icols       = (const int*)d_in[10];
    const int* th          = (const int*)d_in[11];
    const int* tt          = (const int*)d_in[12];
    float* out             = (float*)d_out;

    // ---------------- workspace layout (floats) ----------------
    float* w = (float*)d_ws;
    size_t off = 0;
    float* ent_a   = w + off; off += (size_t)N_ENTITIES * EMB;  // 12.8M
    float* ent_b   = w + off; off += (size_t)N_ENTITIES * EMB;  // 12.8M
    float* ent_res = w + off; off += (size_t)N_ITEMS * EMB;     // items only
    float* usr_res = w + off; off += (size_t)N_USERS * EMB;
    float* ucf     = w + off; off += (size_t)N_USERS * EMB;
    float* cf_a    = w + off; off += (size_t)N_ITEMS * EMB;
    float* cf_b    = w + off; off += (size_t)N_ITEMS * EMB;
    float* cf_res  = w + off; off += (size_t)N_ITEMS * EMB;
    float* u_val   = w + off; off += (size_t)NNZ;
    float* i_val   = w + off; off += (size_t)NNZ;
    float* l1p     = w + off; off += (size_t)BATCH;
    float* l2p     = w + off; off += (size_t)N_TRIPLETS;
    int* iw = (int*)(w + off);
    size_t ioff = 0;
    int* cnt_e  = iw + ioff; ioff += N_ENTITIES;
    int* cnt_u  = iw + ioff; ioff += N_USERS;
    int* cnt_i  = iw + ioff; ioff += N_ITEMS;
    int* off_e  = iw + ioff; ioff += N_ENTITIES + 1;
    int* off_u  = iw + ioff; ioff += N_USERS + 1;
    int* off_i  = iw + ioff; ioff += N_ITEMS + 1;
    int* cur_e  = iw + ioff; ioff += N_ENTITIES;
    int* cur_u  = iw + ioff; ioff += N_USERS;
    int* cur_i  = iw + ioff; ioff += N_ITEMS;
    int* kg_pack = iw + ioff; ioff += N_EDGES;
    int* u_col   = iw + ioff; ioff += NNZ;
    int* i_row   = iw + ioff; ioff += NNZ;
    int* part_e  = iw + ioff; ioff += 256;
    int* part_u  = iw + ioff; ioff += 256;
    int* part_i  = iw + ioff; ioff += 256;

    const float* ent0 = all_embed + (size_t)N_USERS * EMB;

    // ---------------- CSR build (shared by both hops) ----------------
    hipMemsetAsync(cnt_e, 0, (size_t)N_ENTITIES * 4, stream);
    hipMemsetAsync(cnt_u, 0, (size_t)N_USERS * 4, stream);
    hipMemsetAsync(cnt_i, 0, (size_t)N_ITEMS * 4, stream);
    hist_edges<<<(N_EDGES + 255) / 256, 256, 0, stream>>>(edge_head, cnt_e);
    hist_inter<<<(NNZ + 255) / 256, 256, 0, stream>>>(irows, icols, cnt_u, cnt_i);

    const int nb_e = (N_ENTITIES + 1023) / 1024;  // 196
    const int nb_u = (N_USERS + 1023) / 1024;     // 98
    const int nb_i = (N_ITEMS + 1023) / 1024;     // 49
    scan_l1<<<nb_e, 256, 0, stream>>>(cnt_e, off_e, part_e, N_ENTITIES);
    scan_l2<<<1, 256, 0, stream>>>(part_e, nb_e);
    scan_l3<<<(N_ENTITIES + 255) / 256, 256, 0, stream>>>(off_e, cur_e, part_e, N_ENTITIES, N_EDGES);
    scan_l1<<<nb_u, 256, 0, stream>>>(cnt_u, off_u, part_u, N_USERS);
    scan_l2<<<1, 256, 0, stream>>>(part_u, nb_u);
    scan_l3<<<(N_USERS + 255) / 256, 256, 0, stream>>>(off_u, cur_u, part_u, N_USERS, NNZ);
    scan_l1<<<nb_i, 256, 0, stream>>>(cnt_i, off_i, part_i, N_ITEMS);
    scan_l2<<<1, 256, 0, stream>>>(part_i, nb_i);
    scan_l3<<<(N_ITEMS + 255) / 256, 256, 0, stream>>>(off_i, cur_i, part_i, N_ITEMS, NNZ);

    place_edges<<<(N_EDGES + 255) / 256, 256, 0, stream>>>(edge_head, edge_tail, etype, cur_e, kg_pack);
    place_inter<<<(NNZ + 255) / 256, 256, 0, stream>>>(irows, icols, vals, cur_u, cur_i,
                                                       u_col, u_val, i_row, i_val);

    // ---------------- init residual / current tables ----------------
    hipMemcpyAsync(ent_a,   ent0,      (size_t)N_ENTITIES * EMB * 4, hipMemcpyDeviceToDevice, stream);
    hipMemcpyAsync(ent_res, ent0,      (size_t)N_ITEMS    * EMB * 4, hipMemcpyDeviceToDevice, stream);
    hipMemcpyAsync(usr_res, all_embed, (size_t)N_USERS    * EMB * 4, hipMemcpyDeviceToDevice, stream);
    hipMemcpyAsync(cf_a,    item_cf0,  (size_t)N_ITEMS    * EMB * 4, hipMemcpyDeviceToDevice, stream);
    hipMemcpyAsync(cf_res,  item_cf0,  (size_t)N_ITEMS    * EMB * 4, hipMemcpyDeviceToDevice, stream);

    float* ent_cur = ent_a; float* ent_nxt = ent_b;
    float* cf_cur  = cf_a;  float* cf_nxt  = cf_b;

    for (int hop = 0; hop < HOPS; ++hop) {
        int last = (hop == HOPS - 1) ? 1 : 0;
        kg_agg<<<N_ENTITIES / 4, 256, 0, stream>>>(off_e, kg_pack, relw, ent_cur, ent_nxt, ent_res, last);
        user_agg<<<N_USERS / 4, 256, 0, stream>>>(off_u, u_col, u_val, ent_cur, cf_cur, usr_res, ucf, last);
        item_agg<<<N_ITEMS / 4, 256, 0, stream>>>(off_i, i_row, i_val, ucf, cf_nxt, cf_res, last);
        float* tmp = ent_cur; ent_cur = ent_nxt; ent_nxt = tmp;
        tmp = cf_cur; cf_cur = cf_nxt; cf_nxt = tmp;
    }

    loss1_kernel<<<BATCH / 4, 256, 0, stream>>>(user, pos_item, neg_item, usr_res, ent_res, cf_res, l1p);
    angle_kernel<<<(N_TRIPLETS + 3) / 4, 256, 0, stream>>>(ent0, th, tt, l2p);
    finalize_kernel<<<1, 256, 0, stream>>>(l1p, l2p, out);
}

// Round 3
// 918.144 us; speedup vs baseline: 2.6538x; 1.4564x over previous
//
#include <hip/hip_runtime.h>
#include <math.h>

#define N_USERS    100000
#define N_ITEMS    50000
#define N_ENTITIES 200000
#define N_REL      20
#define EMB        64
#define HOPS       2
#define MARGIN_CCL 0.8f
#define NUM_NEG    64
#define ANGLE_W    0.1f
#define ANGLE_DROP 0.5f
#define N_EDGES    1000000
#define NNZ        1000000
#define N_TRIPLETS 200000
#define BATCH      4096
#define EPSF       1e-6f

#define ANGLE_BLOCKS (N_TRIPLETS / 16)   // 12500

__device__ inline float dot4(float4 a, float4 b) {
    return a.x * b.x + a.y * b.y + a.z * b.z + a.w * b.w;
}
// sum across the 4 groups of 16 (lanes with equal q) — result replicated in all lanes
__device__ inline float4 cross_group_sum(float4 a) {
    a.x += __shfl_xor(a.x, 16, 64); a.y += __shfl_xor(a.y, 16, 64);
    a.z += __shfl_xor(a.z, 16, 64); a.w += __shfl_xor(a.w, 16, 64);
    a.x += __shfl_xor(a.x, 32, 64); a.y += __shfl_xor(a.y, 32, 64);
    a.z += __shfl_xor(a.z, 32, 64); a.w += __shfl_xor(a.w, 32, 64);
    return a;
}
// sum within each group of 16 lanes — result replicated within the group
__device__ inline float grp_red16(float v) {
    v += __shfl_xor(v, 1, 64); v += __shfl_xor(v, 2, 64);
    v += __shfl_xor(v, 4, 64); v += __shfl_xor(v, 8, 64);
    return v;
}
__device__ inline float cross_grp_scalar(float v) {
    v += __shfl_xor(v, 16, 64); v += __shfl_xor(v, 32, 64);
    return v;
}

// ------------------------- CSR build: histogram -------------------------
__global__ void hist_edges(const int* __restrict__ head, int* __restrict__ cnt_e) {
    int e = blockIdx.x * blockDim.x + threadIdx.x;
    if (e < N_EDGES) atomicAdd(&cnt_e[head[e]], 1);
}

__global__ void hist_inter(const int* __restrict__ rows, const int* __restrict__ cols,
                           int* __restrict__ cnt_u, int* __restrict__ cnt_i) {
    int i = blockIdx.x * blockDim.x + threadIdx.x;
    if (i < NNZ) {
        atomicAdd(&cnt_u[rows[i]], 1);
        atomicAdd(&cnt_i[cols[i]], 1);
    }
}

// ------------------------- 2-level exclusive scan -------------------------
__global__ void scan_l1(const int* __restrict__ in, int* __restrict__ out,
                        int* __restrict__ partials, int N) {
    int base = blockIdx.x * 1024 + threadIdx.x * 4;
    int a0 = 0, a1 = 0, a2 = 0, a3 = 0;
    if (base + 0 < N) a0 = in[base + 0];
    if (base + 1 < N) a1 = in[base + 1];
    if (base + 2 < N) a2 = in[base + 2];
    if (base + 3 < N) a3 = in[base + 3];
    int tot = a0 + a1 + a2 + a3;
    __shared__ int s[256];
    s[threadIdx.x] = tot;
    __syncthreads();
    for (int d = 1; d < 256; d <<= 1) {
        int x = 0;
        if (threadIdx.x >= d) x = s[threadIdx.x - d];
        __syncthreads();
        s[threadIdx.x] += x;
        __syncthreads();
    }
    int excl = (threadIdx.x == 0) ? 0 : s[threadIdx.x - 1];
    if (threadIdx.x == 255) partials[blockIdx.x] = s[255];
    int r = excl;
    if (base + 0 < N) out[base + 0] = r; r += a0;
    if (base + 1 < N) out[base + 1] = r; r += a1;
    if (base + 2 < N) out[base + 2] = r; r += a2;
    if (base + 3 < N) out[base + 3] = r;
}

__global__ void scan_l2(int* __restrict__ partials, int nb) {
    __shared__ int s[256];
    int t = threadIdx.x;
    int v = (t < nb) ? partials[t] : 0;
    s[t] = v;
    __syncthreads();
    for (int d = 1; d < 256; d <<= 1) {
        int x = 0;
        if (t >= d) x = s[t - d];
        __syncthreads();
        s[t] += x;
        __syncthreads();
    }
    int excl = (t == 0) ? 0 : s[t - 1];
    if (t < nb) partials[t] = excl;
}

__global__ void scan_l3(int* __restrict__ out, int* __restrict__ cur,
                        const int* __restrict__ partials, int N, int total) {
    int i = blockIdx.x * 256 + threadIdx.x;
    if (i < N) {
        int v = out[i] + partials[i >> 10];
        out[i] = v;
        cur[i] = v;
    }
    if (i == 0) out[N] = total;
}

// ------------------------- CSR build: placement -------------------------
__global__ void place_edges(const int* __restrict__ head, const int* __restrict__ tail,
                            const int* __restrict__ etype, int* __restrict__ cur_e,
                            int* __restrict__ kg_pack) {
    int e = blockIdx.x * blockDim.x + threadIdx.x;
    if (e >= N_EDGES) return;
    int p = atomicAdd(&cur_e[head[e]], 1);
    kg_pack[p] = tail[e] | ((etype[e] - 1) << 18);   // tail<2^18, rel<32
}

__global__ void place_inter(const int* __restrict__ rows, const int* __restrict__ cols,
                            const float* __restrict__ vals,
                            int* __restrict__ cur_u, int* __restrict__ cur_i,
                            int* __restrict__ u_col, float* __restrict__ u_val,
                            int* __restrict__ i_row, float* __restrict__ i_val) {
    int i = blockIdx.x * blockDim.x + threadIdx.x;
    if (i >= NNZ) return;
    int r = rows[i], c = cols[i];
    float v = vals[i];
    int pu = atomicAdd(&cur_u[r], 1);
    u_col[pu] = c; u_val[pu] = v;
    int pi = atomicAdd(&cur_i[c], 1);
    i_row[pi] = r; i_val[pi] = v;
}

// ------------------------- hop kernels (float4 gather, 4 groups x 16 lanes) ----------
// wave per entity row; lane = 16*g + q, group g handles edge (k+g), q indexes float4 dims
__global__ void kg_agg(const int* __restrict__ off, const int* __restrict__ pack,
                       const float* __restrict__ relw, const float4* __restrict__ src,
                       float4* __restrict__ dst, float4* __restrict__ res, int last_hop) {
    __shared__ float4 srel[(N_REL - 1) * 17];   // stride 17 -> 4 groups hit distinct banks
    const float4* relw4 = (const float4*)relw;
    for (int i = threadIdx.x; i < (N_REL - 1) * 16; i += 256)
        srel[(i >> 4) * 17 + (i & 15)] = relw4[i];
    __syncthreads();
    int row = blockIdx.x * 4 + (threadIdx.x >> 6);
    int lane = threadIdx.x & 63;
    int g = lane >> 4, q = lane & 15;
    int s = off[row], e = off[row + 1];
    float4 acc = make_float4(0.f, 0.f, 0.f, 0.f);
    int k = s;
    for (; k + 8 <= e; k += 8) {
        int p0 = pack[k + g], p1 = pack[k + 4 + g];
        float4 a0 = src[(p0 & 0x3FFFF) * 16 + q];
        float4 b0 = srel[(p0 >> 18) * 17 + q];
        float4 a1 = src[(p1 & 0x3FFFF) * 16 + q];
        float4 b1 = srel[(p1 >> 18) * 17 + q];
        acc.x += a0.x * b0.x + a1.x * b1.x;
        acc.y += a0.y * b0.y + a1.y * b1.y;
        acc.z += a0.z * b0.z + a1.z * b1.z;
        acc.w += a0.w * b0.w + a1.w * b1.w;
    }
    for (; k < e; k += 4) {
        int idx = k + g;
        if (idx < e) {
            int p0 = pack[idx];
            float4 a0 = src[(p0 & 0x3FFFF) * 16 + q];
            float4 b0 = srel[(p0 >> 18) * 17 + q];
            acc.x += a0.x * b0.x; acc.y += a0.y * b0.y;
            acc.z += a0.z * b0.z; acc.w += a0.w * b0.w;
        }
    }
    acc = cross_group_sum(acc);
    float inv = 1.0f / fmaxf((float)(e - s), 1.0f);
    acc.x *= inv; acc.y *= inv; acc.z *= inv; acc.w *= inv;
    float rn = 1.0f / fmaxf(sqrtf(grp_red16(dot4(acc, acc))), 1e-12f);
    float4 o = make_float4(acc.x * rn, acc.y * rn, acc.z * rn, acc.w * rn);
    if (g == 0) dst[row * 16 + q] = o;
    if (row < N_ITEMS) {
        float4 rr = res[row * 16 + q];
        rr.x += o.x; rr.y += o.y; rr.z += o.z; rr.w += o.w;
        if (last_hop) {
            float rn2 = 1.0f / fmaxf(sqrtf(grp_red16(dot4(rr, rr))), 1e-12f);
            rr.x *= rn2; rr.y *= rn2; rr.z *= rn2; rr.w *= rn2;
        }
        if (g == 0) res[row * 16 + q] = rr;
    }
}

// wave per user row: au = sum v*ent[col]; ac = sum v*cf[col] (raw)
__global__ void user_agg(const int* __restrict__ off, const int* __restrict__ u_col,
                         const float* __restrict__ u_val, const float4* __restrict__ ent_cur,
                         const float4* __restrict__ cf_cur, float4* __restrict__ usr_res,
                         float4* __restrict__ ucf, int last_hop) {
    int row = blockIdx.x * 4 + (threadIdx.x >> 6);
    int lane = threadIdx.x & 63;
    int g = lane >> 4, q = lane & 15;
    int s = off[row], e = off[row + 1];
    float4 au = make_float4(0.f, 0.f, 0.f, 0.f);
    float4 ac = make_float4(0.f, 0.f, 0.f, 0.f);
    int k = s;
    for (; k + 8 <= e; k += 8) {
        int c0 = u_col[k + g];     float v0 = u_val[k + g];
        int c1 = u_col[k + 4 + g]; float v1 = u_val[k + 4 + g];
        float4 e0 = ent_cur[c0 * 16 + q], f0 = cf_cur[c0 * 16 + q];
        float4 e1 = ent_cur[c1 * 16 + q], f1 = cf_cur[c1 * 16 + q];
        au.x += v0 * e0.x + v1 * e1.x; au.y += v0 * e0.y + v1 * e1.y;
        au.z += v0 * e0.z + v1 * e1.z; au.w += v0 * e0.w + v1 * e1.w;
        ac.x += v0 * f0.x + v1 * f1.x; ac.y += v0 * f0.y + v1 * f1.y;
        ac.z += v0 * f0.z + v1 * f1.z; ac.w += v0 * f0.w + v1 * f1.w;
    }
    for (; k < e; k += 4) {
        int idx = k + g;
        if (idx < e) {
            int c0 = u_col[idx]; float v0 = u_val[idx];
            float4 e0 = ent_cur[c0 * 16 + q], f0 = cf_cur[c0 * 16 + q];
            au.x += v0 * e0.x; au.y += v0 * e0.y; au.z += v0 * e0.z; au.w += v0 * e0.w;
            ac.x += v0 * f0.x; ac.y += v0 * f0.y; ac.z += v0 * f0.z; ac.w += v0 * f0.w;
        }
    }
    au = cross_group_sum(au);
    ac = cross_group_sum(ac);
    float rn = 1.0f / fmaxf(sqrtf(grp_red16(dot4(au, au))), 1e-12f);
    float4 rr = usr_res[row * 16 + q];
    rr.x += au.x * rn; rr.y += au.y * rn; rr.z += au.z * rn; rr.w += au.w * rn;
    if (last_hop) {
        float rn2 = 1.0f / fmaxf(sqrtf(grp_red16(dot4(rr, rr))), 1e-12f);
        rr.x *= rn2; rr.y *= rn2; rr.z *= rn2; rr.w *= rn2;
    }
    if (g == 0) {
        usr_res[row * 16 + q] = rr;
        ucf[row * 16 + q] = ac;
    }
}

// wave per item col: acc = sum v*ucf[row]; l2norm; residual
__global__ void item_agg(const int* __restrict__ off, const int* __restrict__ i_row,
                         const float* __restrict__ i_val, const float4* __restrict__ ucf,
                         float4* __restrict__ dst, float4* __restrict__ res, int last_hop) {
    int row = blockIdx.x * 4 + (threadIdx.x >> 6);
    int lane = threadIdx.x & 63;
    int g = lane >> 4, q = lane & 15;
    int s = off[row], e = off[row + 1];
    float4 acc = make_float4(0.f, 0.f, 0.f, 0.f);
    int k = s;
    for (; k + 8 <= e; k += 8) {
        int r0 = i_row[k + g];     float v0 = i_val[k + g];
        int r1 = i_row[k + 4 + g]; float v1 = i_val[k + 4 + g];
        float4 a0 = ucf[r0 * 16 + q];
        float4 a1 = ucf[r1 * 16 + q];
        acc.x += v0 * a0.x + v1 * a1.x; acc.y += v0 * a0.y + v1 * a1.y;
        acc.z += v0 * a0.z + v1 * a1.z; acc.w += v0 * a0.w + v1 * a1.w;
    }
    for (; k < e; k += 4) {
        int idx = k + g;
        if (idx < e) {
            int r0 = i_row[idx]; float v0 = i_val[idx];
            float4 a0 = ucf[r0 * 16 + q];
            acc.x += v0 * a0.x; acc.y += v0 * a0.y;
            acc.z += v0 * a0.z; acc.w += v0 * a0.w;
        }
    }
    acc = cross_group_sum(acc);
    float rn = 1.0f / fmaxf(sqrtf(grp_red16(dot4(acc, acc))), 1e-12f);
    float4 o = make_float4(acc.x * rn, acc.y * rn, acc.z * rn, acc.w * rn);
    if (g == 0) dst[row * 16 + q] = o;
    float4 rr = res[row * 16 + q];
    rr.x += o.x; rr.y += o.y; rr.z += o.z; rr.w += o.w;
    if (last_hop) {
        float rn2 = 1.0f / fmaxf(sqrtf(grp_red16(dot4(rr, rr))), 1e-12f);
        rr.x *= rn2; rr.y *= rn2; rr.z *= rn2; rr.w *= rn2;
    }
    if (g == 0) res[row * 16 + q] = rr;
}

// ------------------------- losses -------------------------
// tables pre-normalized; wave per batch element; 4 negatives per group-step, unrolled x2
__global__ void loss1_kernel(const int* __restrict__ user, const int* __restrict__ pos,
                             const int* __restrict__ neg, const float4* __restrict__ usr_res,
                             const float4* __restrict__ ent_res, const float4* __restrict__ cf_res,
                             float* __restrict__ l1p) {
    int b = blockIdx.x * 4 + (threadIdx.x >> 6);
    int lane = threadIdx.x & 63;
    int g = lane >> 4, q = lane & 15;
    int uid = user[b], pid = pos[b];
    float4 u = usr_res[uid * 16 + q];
    float4 p = ent_res[pid * 16 + q];
    float4 pc = cf_res[pid * 16 + q];
    float dp = grp_red16(dot4(u, p) + dot4(u, pc));
    float ui_pos = fmaxf(2.0f - dp, 0.0f);
    float sum_n = 0.f, cnt_n = 0.f, sum_c = 0.f, cnt_c = 0.f;
    const int* nb = neg + b * NUM_NEG;
    for (int j = 0; j < NUM_NEG; j += 8) {
        int n0 = nb[j + g], n1 = nb[j + 4 + g];
        float4 e0 = ent_res[n0 * 16 + q], c0 = cf_res[n0 * 16 + q];
        float4 e1 = ent_res[n1 * 16 + q], c1 = cf_res[n1 * 16 + q];
        float dn0 = grp_red16(dot4(u, e0));
        float dc0 = grp_red16(dot4(u, c0));
        float dn1 = grp_red16(dot4(u, e1));
        float dc1 = grp_red16(dot4(u, c1));
        float s0 = fmaxf(dn0 - MARGIN_CCL, 0.f); sum_n += s0; if (s0 > 0.f) cnt_n += 1.f;
        float s1 = fmaxf(dn1 - MARGIN_CCL, 0.f); sum_n += s1; if (s1 > 0.f) cnt_n += 1.f;
        float t0 = fmaxf(dc0 - MARGIN_CCL, 0.f); sum_c += t0; if (t0 > 0.f) cnt_c += 1.f;
        float t1 = fmaxf(dc1 - MARGIN_CCL, 0.f); sum_c += t1; if (t1 > 0.f) cnt_c += 1.f;
    }
    sum_n = cross_grp_scalar(sum_n); cnt_n = cross_grp_scalar(cnt_n);
    sum_c = cross_grp_scalar(sum_c); cnt_c = cross_grp_scalar(cnt_c);
    if (lane == 0)
        l1p[b] = ui_pos + sum_n / (cnt_n + 1e-5f) + sum_c / (cnt_c + 1e-5f);
}

// 16 triplets per block (4 waves x 4 groups); per-block partial sum
__global__ void angle_kernel(const float4* __restrict__ ent0,
                             const int* __restrict__ th, const int* __restrict__ tt,
                             float* __restrict__ l2blk) {
    int lane = threadIdx.x & 63;
    int g = lane >> 4, q = lane & 15;
    int trip = blockIdx.x * 16 + (threadIdx.x >> 6) * 4 + g;
    int h = th[trip], t = tt[trip];
    float4 hv = ent0[h * 16 + q];
    float4 tv = ent0[t * 16 + q];
    hv.x *= ANGLE_DROP; hv.y *= ANGLE_DROP; hv.z *= ANGLE_DROP; hv.w *= ANGLE_DROP;
    tv.x *= ANGLE_DROP; tv.y *= ANGLE_DROP; tv.z *= ANGLE_DROP; tv.w *= ANGLE_DROP;
    float4 dv = make_float4(hv.x - tv.x, hv.y - tv.y, hv.z - tv.z, hv.w - tv.w);
    float s_hh = grp_red16(dot4(hv, hv));
    float s_tt = grp_red16(dot4(tv, tv));
    float s_ht = grp_red16(dot4(hv, tv));
    float s_dd = grp_red16(dot4(dv, dv));
    __shared__ float sb[16];
    if (q == 0) {
        float nu = sqrtf(s_hh);
        float ed = sqrtf(s_dd);
        float sqnu = fminf(fmaxf(s_hh, 0.0f), 1.0f - EPSF);
        float ha_arg = fminf(fmaxf(0.1f * (1.0f - sqnu) / sqrtf(sqnu), -1.0f + EPSF), 1.0f - EPSF);
        float half = asinf(ha_arg);
        float num = s_ht * (1.0f + s_hh) - s_hh * (1.0f + s_tt);
        float den = nu * ed * sqrtf(fmaxf(1.0f + s_tt * s_hh - 2.0f * s_ht, EPSF)) + EPSF;
        float ang = acosf(fminf(fmaxf(num / den, -1.0f + EPSF), 1.0f - EPSF));
        sb[threadIdx.x >> 4] = fmaxf(ang - half, 0.0f);
    }
    __syncthreads();
    if (threadIdx.x == 0) {
        float tot = 0.f;
        #pragma unroll
        for (int i = 0; i < 16; ++i) tot += sb[i];
        l2blk[blockIdx.x] = tot;
    }
}

__global__ void finalize_kernel(const float* __restrict__ l1p, const float* __restrict__ l2b,
                                float* __restrict__ out) {
    __shared__ float sb[1024];
    float a1 = 0.f;
    for (int i = threadIdx.x; i < BATCH; i += 1024) a1 += l1p[i];
    float a2 = 0.f;
    for (int i = threadIdx.x; i < ANGLE_BLOCKS; i += 1024) a2 += l2b[i];
    sb[threadIdx.x] = a1 / (float)BATCH + ANGLE_W * a2 / (float)N_TRIPLETS;
    __syncthreads();
    for (int s = 512; s > 0; s >>= 1) {
        if (threadIdx.x < s) sb[threadIdx.x] += sb[threadIdx.x + s];
        __syncthreads();
    }
    if (threadIdx.x == 0) out[0] = sb[0];
}

extern "C" void kernel_launch(void* const* d_in, const int* in_sizes, int n_in,
                              void* d_out, int out_size, void* d_ws, size_t ws_size,
                              hipStream_t stream) {
    const float* all_embed = (const float*)d_in[0];
    const float* item_cf0  = (const float*)d_in[1];
    const float* relw      = (const float*)d_in[2];
    const float* vals      = (const float*)d_in[3];
    const int* user        = (const int*)d_in[4];
    const int* pos_item    = (const int*)d_in[5];
    const int* neg_item    = (const int*)d_in[6];
    const int* edge_head   = (const int*)d_in[7];
    const int* edge_tail   = edge_head + N_EDGES;
    const int* etype       = (const int*)d_in[8];
    const int* irows       = (const int*)d_in[9];
    const int* icols       = (const int*)d_in[10];
    const int* th          = (const int*)d_in[11];
    const int* tt          = (const int*)d_in[12];
    float* out             = (float*)d_out;

    // ---------------- workspace layout (floats) ----------------
    float* w = (float*)d_ws;
    size_t off = 0;
    float* ent_a   = w + off; off += (size_t)N_ENTITIES * EMB;
    float* ent_b   = w + off; off += (size_t)N_ENTITIES * EMB;
    float* ent_res = w + off; off += (size_t)N_ITEMS * EMB;     // items only
    float* usr_res = w + off; off += (size_t)N_USERS * EMB;
    float* ucf     = w + off; off += (size_t)N_USERS * EMB;
    float* cf_a    = w + off; off += (size_t)N_ITEMS * EMB;
    float* cf_b    = w + off; off += (size_t)N_ITEMS * EMB;
    float* cf_res  = w + off; off += (size_t)N_ITEMS * EMB;
    float* u_val   = w + off; off += (size_t)NNZ;
    float* i_val   = w + off; off += (size_t)NNZ;
    float* l1p     = w + off; off += (size_t)BATCH;
    float* l2blk   = w + off; off += (size_t)ANGLE_BLOCKS;
    int* iw = (int*)(w + off);
    size_t ioff = 0;
    int* cnt_e  = iw + ioff; ioff += N_ENTITIES;
    int* cnt_u  = iw + ioff; ioff += N_USERS;
    int* cnt_i  = iw + ioff; ioff += N_ITEMS;
    int* off_e  = iw + ioff; ioff += N_ENTITIES + 1;
    int* off_u  = iw + ioff; ioff += N_USERS + 1;
    int* off_i  = iw + ioff; ioff += N_ITEMS + 1;
    int* cur_e  = iw + ioff; ioff += N_ENTITIES;
    int* cur_u  = iw + ioff; ioff += N_USERS;
    int* cur_i  = iw + ioff; ioff += N_ITEMS;
    int* kg_pack = iw + ioff; ioff += N_EDGES;
    int* u_col   = iw + ioff; ioff += NNZ;
    int* i_row   = iw + ioff; ioff += NNZ;
    int* part_e  = iw + ioff; ioff += 256;
    int* part_u  = iw + ioff; ioff += 256;
    int* part_i  = iw + ioff; ioff += 256;

    const float* ent0 = all_embed + (size_t)N_USERS * EMB;

    // ---------------- CSR build (shared by both hops) ----------------
    hipMemsetAsync(cnt_e, 0, (size_t)N_ENTITIES * 4, stream);
    hipMemsetAsync(cnt_u, 0, (size_t)N_USERS * 4, stream);
    hipMemsetAsync(cnt_i, 0, (size_t)N_ITEMS * 4, stream);
    hist_edges<<<(N_EDGES + 255) / 256, 256, 0, stream>>>(edge_head, cnt_e);
    hist_inter<<<(NNZ + 255) / 256, 256, 0, stream>>>(irows, icols, cnt_u, cnt_i);

    const int nb_e = (N_ENTITIES + 1023) / 1024;
    const int nb_u = (N_USERS + 1023) / 1024;
    const int nb_i = (N_ITEMS + 1023) / 1024;
    scan_l1<<<nb_e, 256, 0, stream>>>(cnt_e, off_e, part_e, N_ENTITIES);
    scan_l2<<<1, 256, 0, stream>>>(part_e, nb_e);
    scan_l3<<<(N_ENTITIES + 255) / 256, 256, 0, stream>>>(off_e, cur_e, part_e, N_ENTITIES, N_EDGES);
    scan_l1<<<nb_u, 256, 0, stream>>>(cnt_u, off_u, part_u, N_USERS);
    scan_l2<<<1, 256, 0, stream>>>(part_u, nb_u);
    scan_l3<<<(N_USERS + 255) / 256, 256, 0, stream>>>(off_u, cur_u, part_u, N_USERS, NNZ);
    scan_l1<<<nb_i, 256, 0, stream>>>(cnt_i, off_i, part_i, N_ITEMS);
    scan_l2<<<1, 256, 0, stream>>>(part_i, nb_i);
    scan_l3<<<(N_ITEMS + 255) / 256, 256, 0, stream>>>(off_i, cur_i, part_i, N_ITEMS, NNZ);

    place_edges<<<(N_EDGES + 255) / 256, 256, 0, stream>>>(edge_head, edge_tail, etype, cur_e, kg_pack);
    place_inter<<<(NNZ + 255) / 256, 256, 0, stream>>>(irows, icols, vals, cur_u, cur_i,
                                                       u_col, u_val, i_row, i_val);

    // ---------------- init residual / current tables ----------------
    hipMemcpyAsync(ent_a,   ent0,      (size_t)N_ENTITIES * EMB * 4, hipMemcpyDeviceToDevice, stream);
    hipMemcpyAsync(ent_res, ent0,      (size_t)N_ITEMS    * EMB * 4, hipMemcpyDeviceToDevice, stream);
    hipMemcpyAsync(usr_res, all_embed, (size_t)N_USERS    * EMB * 4, hipMemcpyDeviceToDevice, stream);
    hipMemcpyAsync(cf_a,    item_cf0,  (size_t)N_ITEMS    * EMB * 4, hipMemcpyDeviceToDevice, stream);
    hipMemcpyAsync(cf_res,  item_cf0,  (size_t)N_ITEMS    * EMB * 4, hipMemcpyDeviceToDevice, stream);

    float* ent_cur = ent_a; float* ent_nxt = ent_b;
    float* cf_cur  = cf_a;  float* cf_nxt  = cf_b;

    for (int hop = 0; hop < HOPS; ++hop) {
        int last = (hop == HOPS - 1) ? 1 : 0;
        kg_agg<<<N_ENTITIES / 4, 256, 0, stream>>>(off_e, kg_pack, relw, (const float4*)ent_cur,
                                                   (float4*)ent_nxt, (float4*)ent_res, last);
        user_agg<<<N_USERS / 4, 256, 0, stream>>>(off_u, u_col, u_val, (const float4*)ent_cur,
                                                  (const float4*)cf_cur, (float4*)usr_res,
                                                  (float4*)ucf, last);
        item_agg<<<N_ITEMS / 4, 256, 0, stream>>>(off_i, i_row, i_val, (const float4*)ucf,
                                                  (float4*)cf_nxt, (float4*)cf_res, last);
        float* tmp = ent_cur; ent_cur = ent_nxt; ent_nxt = tmp;
        tmp = cf_cur; cf_cur = cf_nxt; cf_nxt = tmp;
    }

    loss1_kernel<<<BATCH / 4, 256, 0, stream>>>(user, pos_item, neg_item, (const float4*)usr_res,
                                                (const float4*)ent_res, (const float4*)cf_res, l1p);
    angle_kernel<<<ANGLE_BLOCKS, 256, 0, stream>>>((const float4*)ent0, th, tt, l2blk);
    finalize_kernel<<<1, 1024, 0, stream>>>(l1p, l2blk, out);
}

// Round 4
// 902.411 us; speedup vs baseline: 2.7001x; 1.0174x over previous
//
#include <hip/hip_runtime.h>
#include <math.h>

#define N_USERS    100000
#define N_ITEMS    50000
#define N_ENTITIES 200000
#define N_REL      20
#define EMB        64
#define HOPS       2
#define MARGIN_CCL 0.8f
#define NUM_NEG    64
#define ANGLE_W    0.1f
#define ANGLE_DROP 0.5f
#define N_EDGES    1000000
#define NNZ        1000000
#define N_TRIPLETS 200000
#define BATCH      4096
#define EPSF       1e-6f

#define ANGLE_BLOCKS (N_TRIPLETS / 16)   // 12500

typedef _Float16 half4_t __attribute__((ext_vector_type(4)));

__device__ inline float4 h2f(half4_t h) {
    return make_float4((float)h.x, (float)h.y, (float)h.z, (float)h.w);
}
__device__ inline half4_t f2h(float4 f) {
    half4_t h; h.x = (_Float16)f.x; h.y = (_Float16)f.y;
    h.z = (_Float16)f.z; h.w = (_Float16)f.w; return h;
}
__device__ inline float dot4(float4 a, float4 b) {
    return a.x * b.x + a.y * b.y + a.z * b.z + a.w * b.w;
}
// sum across the 4 groups of 16 (lanes with equal q) — result replicated in all lanes
__device__ inline float4 cross_group_sum(float4 a) {
    a.x += __shfl_xor(a.x, 16, 64); a.y += __shfl_xor(a.y, 16, 64);
    a.z += __shfl_xor(a.z, 16, 64); a.w += __shfl_xor(a.w, 16, 64);
    a.x += __shfl_xor(a.x, 32, 64); a.y += __shfl_xor(a.y, 32, 64);
    a.z += __shfl_xor(a.z, 32, 64); a.w += __shfl_xor(a.w, 32, 64);
    return a;
}
// sum within each group of 16 lanes — result replicated within the group
__device__ inline float grp_red16(float v) {
    v += __shfl_xor(v, 1, 64); v += __shfl_xor(v, 2, 64);
    v += __shfl_xor(v, 4, 64); v += __shfl_xor(v, 8, 64);
    return v;
}
__device__ inline float cross_grp_scalar(float v) {
    v += __shfl_xor(v, 16, 64); v += __shfl_xor(v, 32, 64);
    return v;
}

// ------------------------- fp32 -> fp16 table conversion -------------------------
__global__ void f32_to_f16(const float4* __restrict__ in, half4_t* __restrict__ out, int n4) {
    int i = blockIdx.x * blockDim.x + threadIdx.x;
    if (i < n4) out[i] = f2h(in[i]);
}

// ------------------------- CSR build: histogram -------------------------
__global__ void hist_edges(const int* __restrict__ head, int* __restrict__ cnt_e) {
    int e = blockIdx.x * blockDim.x + threadIdx.x;
    if (e < N_EDGES) atomicAdd(&cnt_e[head[e]], 1);
}

__global__ void hist_inter(const int* __restrict__ rows, const int* __restrict__ cols,
                           int* __restrict__ cnt_u, int* __restrict__ cnt_i) {
    int i = blockIdx.x * blockDim.x + threadIdx.x;
    if (i < NNZ) {
        atomicAdd(&cnt_u[rows[i]], 1);
        atomicAdd(&cnt_i[cols[i]], 1);
    }
}

// ------------------------- 2-level exclusive scan -------------------------
__global__ void scan_l1(const int* __restrict__ in, int* __restrict__ out,
                        int* __restrict__ partials, int N) {
    int base = blockIdx.x * 1024 + threadIdx.x * 4;
    int a0 = 0, a1 = 0, a2 = 0, a3 = 0;
    if (base + 0 < N) a0 = in[base + 0];
    if (base + 1 < N) a1 = in[base + 1];
    if (base + 2 < N) a2 = in[base + 2];
    if (base + 3 < N) a3 = in[base + 3];
    int tot = a0 + a1 + a2 + a3;
    __shared__ int s[256];
    s[threadIdx.x] = tot;
    __syncthreads();
    for (int d = 1; d < 256; d <<= 1) {
        int x = 0;
        if (threadIdx.x >= d) x = s[threadIdx.x - d];
        __syncthreads();
        s[threadIdx.x] += x;
        __syncthreads();
    }
    int excl = (threadIdx.x == 0) ? 0 : s[threadIdx.x - 1];
    if (threadIdx.x == 255) partials[blockIdx.x] = s[255];
    int r = excl;
    if (base + 0 < N) out[base + 0] = r; r += a0;
    if (base + 1 < N) out[base + 1] = r; r += a1;
    if (base + 2 < N) out[base + 2] = r; r += a2;
    if (base + 3 < N) out[base + 3] = r;
}

__global__ void scan_l2(int* __restrict__ partials, int nb) {
    __shared__ int s[256];
    int t = threadIdx.x;
    int v = (t < nb) ? partials[t] : 0;
    s[t] = v;
    __syncthreads();
    for (int d = 1; d < 256; d <<= 1) {
        int x = 0;
        if (t >= d) x = s[t - d];
        __syncthreads();
        s[t] += x;
        __syncthreads();
    }
    int excl = (t == 0) ? 0 : s[t - 1];
    if (t < nb) partials[t] = excl;
}

__global__ void scan_l3(int* __restrict__ out, int* __restrict__ cur,
                        const int* __restrict__ partials, int N, int total) {
    int i = blockIdx.x * 256 + threadIdx.x;
    if (i < N) {
        int v = out[i] + partials[i >> 10];
        out[i] = v;
        cur[i] = v;
    }
    if (i == 0) out[N] = total;
}

// ------------------------- CSR build: placement -------------------------
__global__ void place_edges(const int* __restrict__ head, const int* __restrict__ tail,
                            const int* __restrict__ etype, int* __restrict__ cur_e,
                            int* __restrict__ kg_pack) {
    int e = blockIdx.x * blockDim.x + threadIdx.x;
    if (e >= N_EDGES) return;
    int p = atomicAdd(&cur_e[head[e]], 1);
    kg_pack[p] = tail[e] | ((etype[e] - 1) << 18);   // tail<2^18, rel<32
}

__global__ void place_inter(const int* __restrict__ rows, const int* __restrict__ cols,
                            const float* __restrict__ vals,
                            int* __restrict__ cur_u, int* __restrict__ cur_i,
                            int2* __restrict__ u_pack, int2* __restrict__ i_pack) {
    int i = blockIdx.x * blockDim.x + threadIdx.x;
    if (i >= NNZ) return;
    int r = rows[i], c = cols[i];
    int vb = __float_as_int(vals[i]);
    int pu = atomicAdd(&cur_u[r], 1);
    u_pack[pu] = make_int2(c, vb);
    int pi = atomicAdd(&cur_i[c], 1);
    i_pack[pi] = make_int2(r, vb);
}

// ------------------------- hop kernels (fp16 gather, 4 groups x 16 lanes) ----------
// wave per entity row; lane = 16*g + q, group g handles edge (k+g), q indexes half4 dims
__global__ void kg_agg(const int* __restrict__ off, const int* __restrict__ pack,
                       const float* __restrict__ relw, const half4_t* __restrict__ src,
                       half4_t* __restrict__ dst, half4_t* __restrict__ res,
                       const float4* __restrict__ res_init, int first, int last) {
    __shared__ float4 srel[(N_REL - 1) * 17];   // stride 17 -> 4 groups hit distinct banks
    const float4* relw4 = (const float4*)relw;
    for (int i = threadIdx.x; i < (N_REL - 1) * 16; i += 256)
        srel[(i >> 4) * 17 + (i & 15)] = relw4[i];
    __syncthreads();
    int row = blockIdx.x * 4 + (threadIdx.x >> 6);
    int lane = threadIdx.x & 63;
    int g = lane >> 4, q = lane & 15;
    int s = off[row], e = off[row + 1];
    float4 acc = make_float4(0.f, 0.f, 0.f, 0.f);
    int k = s;
    for (; k + 8 <= e; k += 8) {
        int p0 = pack[k + g], p1 = pack[k + 4 + g];
        float4 a0 = h2f(src[(p0 & 0x3FFFF) * 16 + q]);
        float4 b0 = srel[(p0 >> 18) * 17 + q];
        float4 a1 = h2f(src[(p1 & 0x3FFFF) * 16 + q]);
        float4 b1 = srel[(p1 >> 18) * 17 + q];
        acc.x += a0.x * b0.x + a1.x * b1.x;
        acc.y += a0.y * b0.y + a1.y * b1.y;
        acc.z += a0.z * b0.z + a1.z * b1.z;
        acc.w += a0.w * b0.w + a1.w * b1.w;
    }
    for (; k < e; k += 4) {
        int idx = k + g;
        if (idx < e) {
            int p0 = pack[idx];
            float4 a0 = h2f(src[(p0 & 0x3FFFF) * 16 + q]);
            float4 b0 = srel[(p0 >> 18) * 17 + q];
            acc.x += a0.x * b0.x; acc.y += a0.y * b0.y;
            acc.z += a0.z * b0.z; acc.w += a0.w * b0.w;
        }
    }
    acc = cross_group_sum(acc);
    float inv = 1.0f / fmaxf((float)(e - s), 1.0f);
    acc.x *= inv; acc.y *= inv; acc.z *= inv; acc.w *= inv;
    float rn = 1.0f / fmaxf(sqrtf(grp_red16(dot4(acc, acc))), 1e-12f);
    float4 o = make_float4(acc.x * rn, acc.y * rn, acc.z * rn, acc.w * rn);
    if (g == 0) dst[row * 16 + q] = f2h(o);
    if (row < N_ITEMS) {
        float4 rr = first ? res_init[row * 16 + q] : h2f(res[row * 16 + q]);
        rr.x += o.x; rr.y += o.y; rr.z += o.z; rr.w += o.w;
        if (last) {
            float rn2 = 1.0f / fmaxf(sqrtf(grp_red16(dot4(rr, rr))), 1e-12f);
            rr.x *= rn2; rr.y *= rn2; rr.z *= rn2; rr.w *= rn2;
        }
        if (g == 0) res[row * 16 + q] = f2h(rr);
    }
}

// wave per user row: au = sum v*ent[col]; ac = sum v*cf[col] (raw)
__global__ void user_agg(const int* __restrict__ off, const int2* __restrict__ u_pack,
                         const half4_t* __restrict__ ent_cur, const half4_t* __restrict__ cf_cur,
                         half4_t* __restrict__ usr_res, const float4* __restrict__ res_init,
                         half4_t* __restrict__ ucf, int first, int last) {
    int row = blockIdx.x * 4 + (threadIdx.x >> 6);
    int lane = threadIdx.x & 63;
    int g = lane >> 4, q = lane & 15;
    int s = off[row], e = off[row + 1];
    float4 au = make_float4(0.f, 0.f, 0.f, 0.f);
    float4 ac = make_float4(0.f, 0.f, 0.f, 0.f);
    int k = s;
    for (; k + 8 <= e; k += 8) {
        int2 p0 = u_pack[k + g];
        int2 p1 = u_pack[k + 4 + g];
        float v0 = __int_as_float(p0.y), v1 = __int_as_float(p1.y);
        float4 e0 = h2f(ent_cur[p0.x * 16 + q]), f0 = h2f(cf_cur[p0.x * 16 + q]);
        float4 e1 = h2f(ent_cur[p1.x * 16 + q]), f1 = h2f(cf_cur[p1.x * 16 + q]);
        au.x += v0 * e0.x + v1 * e1.x; au.y += v0 * e0.y + v1 * e1.y;
        au.z += v0 * e0.z + v1 * e1.z; au.w += v0 * e0.w + v1 * e1.w;
        ac.x += v0 * f0.x + v1 * f1.x; ac.y += v0 * f0.y + v1 * f1.y;
        ac.z += v0 * f0.z + v1 * f1.z; ac.w += v0 * f0.w + v1 * f1.w;
    }
    for (; k < e; k += 4) {
        int idx = k + g;
        if (idx < e) {
            int2 p0 = u_pack[idx];
            float v0 = __int_as_float(p0.y);
            float4 e0 = h2f(ent_cur[p0.x * 16 + q]), f0 = h2f(cf_cur[p0.x * 16 + q]);
            au.x += v0 * e0.x; au.y += v0 * e0.y; au.z += v0 * e0.z; au.w += v0 * e0.w;
            ac.x += v0 * f0.x; ac.y += v0 * f0.y; ac.z += v0 * f0.z; ac.w += v0 * f0.w;
        }
    }
    au = cross_group_sum(au);
    ac = cross_group_sum(ac);
    float rn = 1.0f / fmaxf(sqrtf(grp_red16(dot4(au, au))), 1e-12f);
    float4 rr = first ? res_init[row * 16 + q] : h2f(usr_res[row * 16 + q]);
    rr.x += au.x * rn; rr.y += au.y * rn; rr.z += au.z * rn; rr.w += au.w * rn;
    if (last) {
        float rn2 = 1.0f / fmaxf(sqrtf(grp_red16(dot4(rr, rr))), 1e-12f);
        rr.x *= rn2; rr.y *= rn2; rr.z *= rn2; rr.w *= rn2;
    }
    if (g == 0) {
        usr_res[row * 16 + q] = f2h(rr);
        ucf[row * 16 + q] = f2h(ac);
    }
}

// wave per item col: acc = sum v*ucf[row]; l2norm; residual
__global__ void item_agg(const int* __restrict__ off, const int2* __restrict__ i_pack,
                         const half4_t* __restrict__ ucf, half4_t* __restrict__ dst,
                         half4_t* __restrict__ res, const float4* __restrict__ res_init,
                         int first, int last) {
    int row = blockIdx.x * 4 + (threadIdx.x >> 6);
    int lane = threadIdx.x & 63;
    int g = lane >> 4, q = lane & 15;
    int s = off[row], e = off[row + 1];
    float4 acc = make_float4(0.f, 0.f, 0.f, 0.f);
    int k = s;
    for (; k + 8 <= e; k += 8) {
        int2 p0 = i_pack[k + g];
        int2 p1 = i_pack[k + 4 + g];
        float v0 = __int_as_float(p0.y), v1 = __int_as_float(p1.y);
        float4 a0 = h2f(ucf[p0.x * 16 + q]);
        float4 a1 = h2f(ucf[p1.x * 16 + q]);
        acc.x += v0 * a0.x + v1 * a1.x; acc.y += v0 * a0.y + v1 * a1.y;
        acc.z += v0 * a0.z + v1 * a1.z; acc.w += v0 * a0.w + v1 * a1.w;
    }
    for (; k < e; k += 4) {
        int idx = k + g;
        if (idx < e) {
            int2 p0 = i_pack[idx];
            float v0 = __int_as_float(p0.y);
            float4 a0 = h2f(ucf[p0.x * 16 + q]);
            acc.x += v0 * a0.x; acc.y += v0 * a0.y;
            acc.z += v0 * a0.z; acc.w += v0 * a0.w;
        }
    }
    acc = cross_group_sum(acc);
    float rn = 1.0f / fmaxf(sqrtf(grp_red16(dot4(acc, acc))), 1e-12f);
    float4 o = make_float4(acc.x * rn, acc.y * rn, acc.z * rn, acc.w * rn);
    if (g == 0) dst[row * 16 + q] = f2h(o);
    float4 rr = first ? res_init[row * 16 + q] : h2f(res[row * 16 + q]);
    rr.x += o.x; rr.y += o.y; rr.z += o.z; rr.w += o.w;
    if (last) {
        float rn2 = 1.0f / fmaxf(sqrtf(grp_red16(dot4(rr, rr))), 1e-12f);
        rr.x *= rn2; rr.y *= rn2; rr.z *= rn2; rr.w *= rn2;
    }
    if (g == 0) res[row * 16 + q] = f2h(rr);
}

// ------------------------- losses -------------------------
// tables pre-normalized fp16; wave per batch element; 4 negatives per group-step, x2 unroll
__global__ void loss1_kernel(const int* __restrict__ user, const int* __restrict__ pos,
                             const int* __restrict__ neg, const half4_t* __restrict__ usr_res,
                             const half4_t* __restrict__ ent_res, const half4_t* __restrict__ cf_res,
                             float* __restrict__ l1p) {
    int b = blockIdx.x * 4 + (threadIdx.x >> 6);
    int lane = threadIdx.x & 63;
    int g = lane >> 4, q = lane & 15;
    int uid = user[b], pid = pos[b];
    float4 u = h2f(usr_res[uid * 16 + q]);
    float4 p = h2f(ent_res[pid * 16 + q]);
    float4 pc = h2f(cf_res[pid * 16 + q]);
    float dp = grp_red16(dot4(u, p) + dot4(u, pc));
    float ui_pos = fmaxf(2.0f - dp, 0.0f);
    float sum_n = 0.f, cnt_n = 0.f, sum_c = 0.f, cnt_c = 0.f;
    const int* nb = neg + b * NUM_NEG;
    for (int j = 0; j < NUM_NEG; j += 8) {
        int n0 = nb[j + g], n1 = nb[j + 4 + g];
        float4 e0 = h2f(ent_res[n0 * 16 + q]), c0 = h2f(cf_res[n0 * 16 + q]);
        float4 e1 = h2f(ent_res[n1 * 16 + q]), c1 = h2f(cf_res[n1 * 16 + q]);
        float dn0 = grp_red16(dot4(u, e0));
        float dc0 = grp_red16(dot4(u, c0));
        float dn1 = grp_red16(dot4(u, e1));
        float dc1 = grp_red16(dot4(u, c1));
        float s0 = fmaxf(dn0 - MARGIN_CCL, 0.f); sum_n += s0; if (s0 > 0.f) cnt_n += 1.f;
        float s1 = fmaxf(dn1 - MARGIN_CCL, 0.f); sum_n += s1; if (s1 > 0.f) cnt_n += 1.f;
        float t0 = fmaxf(dc0 - MARGIN_CCL, 0.f); sum_c += t0; if (t0 > 0.f) cnt_c += 1.f;
        float t1 = fmaxf(dc1 - MARGIN_CCL, 0.f); sum_c += t1; if (t1 > 0.f) cnt_c += 1.f;
    }
    sum_n = cross_grp_scalar(sum_n); cnt_n = cross_grp_scalar(cnt_n);
    sum_c = cross_grp_scalar(sum_c); cnt_c = cross_grp_scalar(cnt_c);
    if (lane == 0)
        l1p[b] = ui_pos + sum_n / (cnt_n + 1e-5f) + sum_c / (cnt_c + 1e-5f);
}

// 16 triplets per block (4 waves x 4 groups); per-block partial sum
__global__ void angle_kernel(const float4* __restrict__ ent0,
                             const int* __restrict__ th, const int* __restrict__ tt,
                             float* __restrict__ l2blk) {
    int lane = threadIdx.x & 63;
    int g = lane >> 4, q = lane & 15;
    int trip = blockIdx.x * 16 + (threadIdx.x >> 6) * 4 + g;
    int h = th[trip], t = tt[trip];
    float4 hv = ent0[h * 16 + q];
    float4 tv = ent0[t * 16 + q];
    hv.x *= ANGLE_DROP; hv.y *= ANGLE_DROP; hv.z *= ANGLE_DROP; hv.w *= ANGLE_DROP;
    tv.x *= ANGLE_DROP; tv.y *= ANGLE_DROP; tv.z *= ANGLE_DROP; tv.w *= ANGLE_DROP;
    float4 dv = make_float4(hv.x - tv.x, hv.y - tv.y, hv.z - tv.z, hv.w - tv.w);
    float s_hh = grp_red16(dot4(hv, hv));
    float s_tt = grp_red16(dot4(tv, tv));
    float s_ht = grp_red16(dot4(hv, tv));
    float s_dd = grp_red16(dot4(dv, dv));
    __shared__ float sb[16];
    if (q == 0) {
        float nu = sqrtf(s_hh);
        float ed = sqrtf(s_dd);
        float sqnu = fminf(fmaxf(s_hh, 0.0f), 1.0f - EPSF);
        float ha_arg = fminf(fmaxf(0.1f * (1.0f - sqnu) / sqrtf(sqnu), -1.0f + EPSF), 1.0f - EPSF);
        float half_ap = asinf(ha_arg);
        float num = s_ht * (1.0f + s_hh) - s_hh * (1.0f + s_tt);
        float den = nu * ed * sqrtf(fmaxf(1.0f + s_tt * s_hh - 2.0f * s_ht, EPSF)) + EPSF;
        float ang = acosf(fminf(fmaxf(num / den, -1.0f + EPSF), 1.0f - EPSF));
        sb[threadIdx.x >> 4] = fmaxf(ang - half_ap, 0.0f);
    }
    __syncthreads();
    if (threadIdx.x == 0) {
        float tot = 0.f;
        #pragma unroll
        for (int i = 0; i < 16; ++i) tot += sb[i];
        l2blk[blockIdx.x] = tot;
    }
}

__global__ void finalize_kernel(const float* __restrict__ l1p, const float* __restrict__ l2b,
                                float* __restrict__ out) {
    __shared__ float sb[1024];
    float a1 = 0.f;
    for (int i = threadIdx.x; i < BATCH; i += 1024) a1 += l1p[i];
    float a2 = 0.f;
    for (int i = threadIdx.x; i < ANGLE_BLOCKS; i += 1024) a2 += l2b[i];
    sb[threadIdx.x] = a1 / (float)BATCH + ANGLE_W * a2 / (float)N_TRIPLETS;
    __syncthreads();
    for (int s = 512; s > 0; s >>= 1) {
        if (threadIdx.x < s) sb[threadIdx.x] += sb[threadIdx.x + s];
        __syncthreads();
    }
    if (threadIdx.x == 0) out[0] = sb[0];
}

extern "C" void kernel_launch(void* const* d_in, const int* in_sizes, int n_in,
                              void* d_out, int out_size, void* d_ws, size_t ws_size,
                              hipStream_t stream) {
    const float* all_embed = (const float*)d_in[0];
    const float* item_cf0  = (const float*)d_in[1];
    const float* relw      = (const float*)d_in[2];
    const float* vals      = (const float*)d_in[3];
    const int* user        = (const int*)d_in[4];
    const int* pos_item    = (const int*)d_in[5];
    const int* neg_item    = (const int*)d_in[6];
    const int* edge_head   = (const int*)d_in[7];
    const int* edge_tail   = edge_head + N_EDGES;
    const int* etype       = (const int*)d_in[8];
    const int* irows       = (const int*)d_in[9];
    const int* icols       = (const int*)d_in[10];
    const int* th          = (const int*)d_in[11];
    const int* tt          = (const int*)d_in[12];
    float* out             = (float*)d_out;

    // ---------------- workspace layout (256 B aligned chunks) ----------------
    char* base = (char*)d_ws;
    size_t woff = 0;
    auto alloc = [&](size_t bytes) -> void* {
        void* p = base + woff;
        woff = (woff + bytes + 255) & ~(size_t)255;
        return p;
    };
    half4_t* ent_a   = (half4_t*)alloc((size_t)N_ENTITIES * EMB * 2);
    half4_t* ent_b   = (half4_t*)alloc((size_t)N_ENTITIES * EMB * 2);
    half4_t* cf_a    = (half4_t*)alloc((size_t)N_ITEMS * EMB * 2);
    half4_t* cf_b    = (half4_t*)alloc((size_t)N_ITEMS * EMB * 2);
    half4_t* ucf     = (half4_t*)alloc((size_t)N_USERS * EMB * 2);
    half4_t* ent_res = (half4_t*)alloc((size_t)N_ITEMS * EMB * 2);
    half4_t* usr_res = (half4_t*)alloc((size_t)N_USERS * EMB * 2);
    half4_t* cf_res  = (half4_t*)alloc((size_t)N_ITEMS * EMB * 2);
    int2* u_pack     = (int2*)alloc((size_t)NNZ * 8);
    int2* i_pack     = (int2*)alloc((size_t)NNZ * 8);
    int* kg_pack     = (int*)alloc((size_t)N_EDGES * 4);
    float* l1p       = (float*)alloc((size_t)BATCH * 4);
    float* l2blk     = (float*)alloc((size_t)ANGLE_BLOCKS * 4);
    int* cnt_e       = (int*)alloc((size_t)N_ENTITIES * 4);
    int* cnt_u       = (int*)alloc((size_t)N_USERS * 4);
    int* cnt_i       = (int*)alloc((size_t)N_ITEMS * 4);
    int* off_e       = (int*)alloc((size_t)(N_ENTITIES + 1) * 4);
    int* off_u       = (int*)alloc((size_t)(N_USERS + 1) * 4);
    int* off_i       = (int*)alloc((size_t)(N_ITEMS + 1) * 4);
    int* cur_e       = (int*)alloc((size_t)N_ENTITIES * 4);
    int* cur_u       = (int*)alloc((size_t)N_USERS * 4);
    int* cur_i       = (int*)alloc((size_t)N_ITEMS * 4);
    int* part_e      = (int*)alloc(256 * 4);
    int* part_u      = (int*)alloc(256 * 4);
    int* part_i      = (int*)alloc(256 * 4);

    const float* ent0 = all_embed + (size_t)N_USERS * EMB;

    // ---------------- fp16 conversions of hop-0 tables ----------------
    f32_to_f16<<<(N_ENTITIES * 16 + 255) / 256, 256, 0, stream>>>((const float4*)ent0, ent_a,
                                                                  N_ENTITIES * 16);
    f32_to_f16<<<(N_ITEMS * 16 + 255) / 256, 256, 0, stream>>>((const float4*)item_cf0, cf_a,
                                                               N_ITEMS * 16);

    // ---------------- CSR build (shared by both hops) ----------------
    hipMemsetAsync(cnt_e, 0, (size_t)N_ENTITIES * 4, stream);
    hipMemsetAsync(cnt_u, 0, (size_t)N_USERS * 4, stream);
    hipMemsetAsync(cnt_i, 0, (size_t)N_ITEMS * 4, stream);
    hist_edges<<<(N_EDGES + 255) / 256, 256, 0, stream>>>(edge_head, cnt_e);
    hist_inter<<<(NNZ + 255) / 256, 256, 0, stream>>>(irows, icols, cnt_u, cnt_i);

    const int nb_e = (N_ENTITIES + 1023) / 1024;
    const int nb_u = (N_USERS + 1023) / 1024;
    const int nb_i = (N_ITEMS + 1023) / 1024;
    scan_l1<<<nb_e, 256, 0, stream>>>(cnt_e, off_e, part_e, N_ENTITIES);
    scan_l2<<<1, 256, 0, stream>>>(part_e, nb_e);
    scan_l3<<<(N_ENTITIES + 255) / 256, 256, 0, stream>>>(off_e, cur_e, part_e, N_ENTITIES, N_EDGES);
    scan_l1<<<nb_u, 256, 0, stream>>>(cnt_u, off_u, part_u, N_USERS);
    scan_l2<<<1, 256, 0, stream>>>(part_u, nb_u);
    scan_l3<<<(N_USERS + 255) / 256, 256, 0, stream>>>(off_u, cur_u, part_u, N_USERS, NNZ);
    scan_l1<<<nb_i, 256, 0, stream>>>(cnt_i, off_i, part_i, N_ITEMS);
    scan_l2<<<1, 256, 0, stream>>>(part_i, nb_i);
    scan_l3<<<(N_ITEMS + 255) / 256, 256, 0, stream>>>(off_i, cur_i, part_i, N_ITEMS, NNZ);

    place_edges<<<(N_EDGES + 255) / 256, 256, 0, stream>>>(edge_head, edge_tail, etype, cur_e, kg_pack);
    place_inter<<<(NNZ + 255) / 256, 256, 0, stream>>>(irows, icols, vals, cur_u, cur_i,
                                                       u_pack, i_pack);

    // ---------------- hops ----------------
    half4_t* ent_cur = ent_a; half4_t* ent_nxt = ent_b;
    half4_t* cf_cur  = cf_a;  half4_t* cf_nxt  = cf_b;

    for (int hop = 0; hop < HOPS; ++hop) {
        int first = (hop == 0) ? 1 : 0;
        int last = (hop == HOPS - 1) ? 1 : 0;
        kg_agg<<<N_ENTITIES / 4, 256, 0, stream>>>(off_e, kg_pack, relw, ent_cur, ent_nxt,
                                                   ent_res, (const float4*)ent0, first, last);
        user_agg<<<N_USERS / 4, 256, 0, stream>>>(off_u, u_pack, ent_cur, cf_cur, usr_res,
                                                  (const float4*)all_embed, ucf, first, last);
        item_agg<<<N_ITEMS / 4, 256, 0, stream>>>(off_i, i_pack, ucf, cf_nxt, cf_res,
                                                  (const float4*)item_cf0, first, last);
        half4_t* tmp = ent_cur; ent_cur = ent_nxt; ent_nxt = tmp;
        tmp = cf_cur; cf_cur = cf_nxt; cf_nxt = tmp;
    }

    loss1_kernel<<<BATCH / 4, 256, 0, stream>>>(user, pos_item, neg_item, usr_res,
                                                ent_res, cf_res, l1p);
    angle_kernel<<<ANGLE_BLOCKS, 256, 0, stream>>>((const float4*)ent0, th, tt, l2blk);
    finalize_kernel<<<1, 1024, 0, stream>>>(l1p, l2blk, out);
}

// Round 5
// 788.542 us; speedup vs baseline: 3.0900x; 1.1444x over previous
//
#include <hip/hip_runtime.h>
#include <math.h>

#define N_USERS    100000
#define N_ITEMS    50000
#define N_ENTITIES 200000
#define N_REL      20
#define EMB        64
#define HOPS       2
#define MARGIN_CCL 0.8f
#define NUM_NEG    64
#define ANGLE_W    0.1f
#define ANGLE_DROP 0.5f
#define N_EDGES    1000000
#define NNZ        1000000
#define N_TRIPLETS 200000
#define BATCH      4096
#define EPSF       1e-6f

#define ANGLE_BLOCKS (N_TRIPLETS / 16)   // 12500
#define TILE1 4096
#define NBUCK 196                        // ceil(200000/1024) = ceil(100000/512) = ceil(50000/256)
#define BCAP  9216                       // bucket capacity cap (mean 5120, sd ~71)

typedef _Float16 half4_t __attribute__((ext_vector_type(4)));

__device__ inline float4 h2f(half4_t h) {
    return make_float4((float)h.x, (float)h.y, (float)h.z, (float)h.w);
}
__device__ inline half4_t f2h(float4 f) {
    half4_t h; h.x = (_Float16)f.x; h.y = (_Float16)f.y;
    h.z = (_Float16)f.z; h.w = (_Float16)f.w; return h;
}
__device__ inline float dot4(float4 a, float4 b) {
    return a.x * b.x + a.y * b.y + a.z * b.z + a.w * b.w;
}
__device__ inline float4 cross_group_sum(float4 a) {
    a.x += __shfl_xor(a.x, 16, 64); a.y += __shfl_xor(a.y, 16, 64);
    a.z += __shfl_xor(a.z, 16, 64); a.w += __shfl_xor(a.w, 16, 64);
    a.x += __shfl_xor(a.x, 32, 64); a.y += __shfl_xor(a.y, 32, 64);
    a.z += __shfl_xor(a.z, 32, 64); a.w += __shfl_xor(a.w, 32, 64);
    return a;
}
__device__ inline float grp_red16(float v) {
    v += __shfl_xor(v, 1, 64); v += __shfl_xor(v, 2, 64);
    v += __shfl_xor(v, 4, 64); v += __shfl_xor(v, 8, 64);
    return v;
}
__device__ inline float cross_grp_scalar(float v) {
    v += __shfl_xor(v, 16, 64); v += __shfl_xor(v, 32, 64);
    return v;
}

// ------------------------- fp32 -> fp16 table conversion -------------------------
__global__ void f32_to_f16(const float4* __restrict__ in, half4_t* __restrict__ out, int n4) {
    int i = blockIdx.x * blockDim.x + threadIdx.x;
    if (i < n4) out[i] = f2h(in[i]);
}

// ------------------------- CSR build: histogram -------------------------
__global__ void hist_edges(const int* __restrict__ head, int* __restrict__ cnt_e) {
    int e = blockIdx.x * blockDim.x + threadIdx.x;
    if (e < N_EDGES) atomicAdd(&cnt_e[head[e]], 1);
}

__global__ void hist_inter(const int* __restrict__ rows, const int* __restrict__ cols,
                           int* __restrict__ cnt_u, int* __restrict__ cnt_i) {
    int i = blockIdx.x * blockDim.x + threadIdx.x;
    if (i < NNZ) {
        atomicAdd(&cnt_u[rows[i]], 1);
        atomicAdd(&cnt_i[cols[i]], 1);
    }
}

// ------------------------- 2-level exclusive scan -------------------------
__global__ void scan_l1(const int* __restrict__ in, int* __restrict__ out,
                        int* __restrict__ partials, int N) {
    int base = blockIdx.x * 1024 + threadIdx.x * 4;
    int a0 = 0, a1 = 0, a2 = 0, a3 = 0;
    if (base + 0 < N) a0 = in[base + 0];
    if (base + 1 < N) a1 = in[base + 1];
    if (base + 2 < N) a2 = in[base + 2];
    if (base + 3 < N) a3 = in[base + 3];
    int tot = a0 + a1 + a2 + a3;
    __shared__ int s[256];
    s[threadIdx.x] = tot;
    __syncthreads();
    for (int d = 1; d < 256; d <<= 1) {
        int x = 0;
        if (threadIdx.x >= d) x = s[threadIdx.x - d];
        __syncthreads();
        s[threadIdx.x] += x;
        __syncthreads();
    }
    int excl = (threadIdx.x == 0) ? 0 : s[threadIdx.x - 1];
    if (threadIdx.x == 255) partials[blockIdx.x] = s[255];
    int r = excl;
    if (base + 0 < N) out[base + 0] = r; r += a0;
    if (base + 1 < N) out[base + 1] = r; r += a1;
    if (base + 2 < N) out[base + 2] = r; r += a2;
    if (base + 3 < N) out[base + 3] = r;
}

__global__ void scan_l2(int* __restrict__ partials, int nb) {
    __shared__ int s[256];
    int t = threadIdx.x;
    int v = (t < nb) ? partials[t] : 0;
    s[t] = v;
    __syncthreads();
    for (int d = 1; d < 256; d <<= 1) {
        int x = 0;
        if (t >= d) x = s[t - d];
        __syncthreads();
        s[t] += x;
        __syncthreads();
    }
    int excl = (t == 0) ? 0 : s[t - 1];
    if (t < nb) partials[t] = excl;
}

__global__ void scan_l3(int* __restrict__ out, const int* __restrict__ partials,
                        int N, int total) {
    int i = blockIdx.x * 256 + threadIdx.x;
    if (i < N) out[i] = out[i] + partials[i >> 10];
    if (i == 0) out[N] = total;
}

// bucket cursors = CSR offsets at bucket starts
__global__ void init_bcur(const int* __restrict__ off_e, const int* __restrict__ off_u,
                          const int* __restrict__ off_i, int* __restrict__ be,
                          int* __restrict__ bu, int* __restrict__ bi) {
    int t = threadIdx.x;
    be[t] = off_e[min(t << 10, N_ENTITIES)];
    bu[t] = off_u[min(t << 9, N_USERS)];
    bi[t] = off_i[min(t << 8, N_ITEMS)];
}

// ------------------------- phase 1: LDS-binned placement (coalesced stores) -------------
__global__ void phase1_edges(const int* __restrict__ head, const int* __restrict__ tail,
                             const int* __restrict__ etype, int* __restrict__ bcur,
                             int* __restrict__ keys, int* __restrict__ pay) {
    __shared__ int lhist[256], lstart[256], lcur[256], gbase[256];
    __shared__ int key_st[TILE1];
    __shared__ int pay_st[TILE1];
    int t = threadIdx.x;
    int tstart = blockIdx.x * TILE1;
    int valid = min(TILE1, N_EDGES - tstart);
    lhist[t] = 0;
    __syncthreads();
    for (int i = t; i < valid; i += 256) atomicAdd(&lhist[head[tstart + i] >> 10], 1);
    __syncthreads();
    int v = lhist[t];
    lstart[t] = v;
    __syncthreads();
    for (int d = 1; d < 256; d <<= 1) {
        int x = (t >= d) ? lstart[t - d] : 0;
        __syncthreads();
        lstart[t] += x;
        __syncthreads();
    }
    int excl = lstart[t] - v;
    lstart[t] = excl;
    lcur[t] = excl;
    gbase[t] = atomicAdd(&bcur[t], v);
    __syncthreads();
    for (int i = t; i < valid; i += 256) {
        int h = head[tstart + i];
        int p = tail[tstart + i] | ((etype[tstart + i] - 1) << 18);
        int sp = atomicAdd(&lcur[h >> 10], 1);
        key_st[sp] = h;
        pay_st[sp] = p;
    }
    __syncthreads();
    for (int j = t; j < valid; j += 256) {
        int k = key_st[j];
        int b = k >> 10;
        int pos = gbase[b] + (j - lstart[b]);
        keys[pos] = k;
        pay[pos] = pay_st[j];
    }
}

__global__ void phase1_inter(const int* __restrict__ key_arr, const int* __restrict__ other,
                             const float* __restrict__ vals, int* __restrict__ bcur,
                             int* __restrict__ keys, int2* __restrict__ pay, int shift) {
    __shared__ int lhist[256], lstart[256], lcur[256], gbase[256];
    __shared__ int key_st[TILE1];
    __shared__ int2 pay_st[TILE1];
    int t = threadIdx.x;
    int tstart = blockIdx.x * TILE1;
    int valid = min(TILE1, NNZ - tstart);
    lhist[t] = 0;
    __syncthreads();
    for (int i = t; i < valid; i += 256) atomicAdd(&lhist[key_arr[tstart + i] >> shift], 1);
    __syncthreads();
    int v = lhist[t];
    lstart[t] = v;
    __syncthreads();
    for (int d = 1; d < 256; d <<= 1) {
        int x = (t >= d) ? lstart[t - d] : 0;
        __syncthreads();
        lstart[t] += x;
        __syncthreads();
    }
    int excl = lstart[t] - v;
    lstart[t] = excl;
    lcur[t] = excl;
    gbase[t] = atomicAdd(&bcur[t], v);
    __syncthreads();
    for (int i = t; i < valid; i += 256) {
        int k = key_arr[tstart + i];
        int2 p = make_int2(other[tstart + i], __float_as_int(vals[tstart + i]));
        int sp = atomicAdd(&lcur[k >> shift], 1);
        key_st[sp] = k;
        pay_st[sp] = p;
    }
    __syncthreads();
    for (int j = t; j < valid; j += 256) {
        int k = key_st[j];
        int b = k >> shift;
        int pos = gbase[b] + (j - lstart[b]);
        keys[pos] = k;
        pay[pos] = pay_st[j];
    }
}

// ------------------------- phase 2: in-bucket ordering via LDS -------------------------
__global__ void phase2_edges(const int* __restrict__ off, const int* __restrict__ keys,
                             int* __restrict__ pay) {
    __shared__ int lcur[1024];
    __shared__ int lout[BCAP];
    int b = blockIdx.x, t = threadIdx.x;
    int rs = b << 10;
    int re = min(rs + 1024, N_ENTITIES);
    int base = off[rs];
    int len = off[re] - base;
    for (int r = t; r < re - rs; r += 256) lcur[r] = off[rs + r] - base;
    __syncthreads();
    for (int j = t; j < len; j += 256) {
        int k = keys[base + j];
        int slot = atomicAdd(&lcur[k - rs], 1);
        lout[slot] = pay[base + j];
    }
    __syncthreads();
    for (int j = t; j < len; j += 256) pay[base + j] = lout[j];
}

__global__ void phase2_inter(const int* __restrict__ off, const int* __restrict__ keys,
                             int2* __restrict__ pay, int shift, int n_rows) {
    __shared__ int lcur[512];
    __shared__ int2 lout[BCAP];
    int b = blockIdx.x, t = threadIdx.x;
    int rs = b << shift;
    int re = min(rs + (1 << shift), n_rows);
    int base = off[rs];
    int len = off[re] - base;
    for (int r = t; r < re - rs; r += 256) lcur[r] = off[rs + r] - base;
    __syncthreads();
    for (int j = t; j < len; j += 256) {
        int k = keys[base + j];
        int slot = atomicAdd(&lcur[k - rs], 1);
        lout[slot] = pay[base + j];
    }
    __syncthreads();
    for (int j = t; j < len; j += 256) pay[base + j] = lout[j];
}

// ------------------------- hop kernels (fp16 gather, 4 groups x 16 lanes) ----------
__global__ void kg_agg(const int* __restrict__ off, const int* __restrict__ pack,
                       const float* __restrict__ relw, const half4_t* __restrict__ src,
                       half4_t* __restrict__ dst, half4_t* __restrict__ res,
                       const float4* __restrict__ res_init, int first, int last) {
    __shared__ float4 srel[(N_REL - 1) * 17];
    const float4* relw4 = (const float4*)relw;
    for (int i = threadIdx.x; i < (N_REL - 1) * 16; i += 256)
        srel[(i >> 4) * 17 + (i & 15)] = relw4[i];
    __syncthreads();
    int row = blockIdx.x * 4 + (threadIdx.x >> 6);
    int lane = threadIdx.x & 63;
    int g = lane >> 4, q = lane & 15;
    int s = off[row], e = off[row + 1];
    float4 acc = make_float4(0.f, 0.f, 0.f, 0.f);
    int k = s;
    for (; k + 16 <= e; k += 16) {
        int p0 = pack[k + g], p1 = pack[k + 4 + g];
        int p2 = pack[k + 8 + g], p3 = pack[k + 12 + g];
        float4 a0 = h2f(src[(p0 & 0x3FFFF) * 16 + q]); float4 b0 = srel[(p0 >> 18) * 17 + q];
        float4 a1 = h2f(src[(p1 & 0x3FFFF) * 16 + q]); float4 b1 = srel[(p1 >> 18) * 17 + q];
        float4 a2 = h2f(src[(p2 & 0x3FFFF) * 16 + q]); float4 b2 = srel[(p2 >> 18) * 17 + q];
        float4 a3 = h2f(src[(p3 & 0x3FFFF) * 16 + q]); float4 b3 = srel[(p3 >> 18) * 17 + q];
        acc.x += a0.x * b0.x + a1.x * b1.x + a2.x * b2.x + a3.x * b3.x;
        acc.y += a0.y * b0.y + a1.y * b1.y + a2.y * b2.y + a3.y * b3.y;
        acc.z += a0.z * b0.z + a1.z * b1.z + a2.z * b2.z + a3.z * b3.z;
        acc.w += a0.w * b0.w + a1.w * b1.w + a2.w * b2.w + a3.w * b3.w;
    }
    for (; k < e; k += 4) {
        int idx = k + g;
        if (idx < e) {
            int p0 = pack[idx];
            float4 a0 = h2f(src[(p0 & 0x3FFFF) * 16 + q]);
            float4 b0 = srel[(p0 >> 18) * 17 + q];
            acc.x += a0.x * b0.x; acc.y += a0.y * b0.y;
            acc.z += a0.z * b0.z; acc.w += a0.w * b0.w;
        }
    }
    acc = cross_group_sum(acc);
    float inv = 1.0f / fmaxf((float)(e - s), 1.0f);
    acc.x *= inv; acc.y *= inv; acc.z *= inv; acc.w *= inv;
    float rn = 1.0f / fmaxf(sqrtf(grp_red16(dot4(acc, acc))), 1e-12f);
    float4 o = make_float4(acc.x * rn, acc.y * rn, acc.z * rn, acc.w * rn);
    if (g == 0) dst[row * 16 + q] = f2h(o);
    if (row < N_ITEMS) {
        float4 rr = first ? res_init[row * 16 + q] : h2f(res[row * 16 + q]);
        rr.x += o.x; rr.y += o.y; rr.z += o.z; rr.w += o.w;
        if (last) {
            float rn2 = 1.0f / fmaxf(sqrtf(grp_red16(dot4(rr, rr))), 1e-12f);
            rr.x *= rn2; rr.y *= rn2; rr.z *= rn2; rr.w *= rn2;
        }
        if (g == 0) res[row * 16 + q] = f2h(rr);
    }
}

__global__ void user_agg(const int* __restrict__ off, const int2* __restrict__ u_pack,
                         const half4_t* __restrict__ ent_cur, const half4_t* __restrict__ cf_cur,
                         half4_t* __restrict__ usr_res, const float4* __restrict__ res_init,
                         half4_t* __restrict__ ucf, int first, int last) {
    int row = blockIdx.x * 4 + (threadIdx.x >> 6);
    int lane = threadIdx.x & 63;
    int g = lane >> 4, q = lane & 15;
    int s = off[row], e = off[row + 1];
    float4 au = make_float4(0.f, 0.f, 0.f, 0.f);
    float4 ac = make_float4(0.f, 0.f, 0.f, 0.f);
    int k = s;
    for (; k + 8 <= e; k += 8) {
        int2 p0 = u_pack[k + g];
        int2 p1 = u_pack[k + 4 + g];
        float v0 = __int_as_float(p0.y), v1 = __int_as_float(p1.y);
        float4 e0 = h2f(ent_cur[p0.x * 16 + q]), f0 = h2f(cf_cur[p0.x * 16 + q]);
        float4 e1 = h2f(ent_cur[p1.x * 16 + q]), f1 = h2f(cf_cur[p1.x * 16 + q]);
        au.x += v0 * e0.x + v1 * e1.x; au.y += v0 * e0.y + v1 * e1.y;
        au.z += v0 * e0.z + v1 * e1.z; au.w += v0 * e0.w + v1 * e1.w;
        ac.x += v0 * f0.x + v1 * f1.x; ac.y += v0 * f0.y + v1 * f1.y;
        ac.z += v0 * f0.z + v1 * f1.z; ac.w += v0 * f0.w + v1 * f1.w;
    }
    for (; k < e; k += 4) {
        int idx = k + g;
        if (idx < e) {
            int2 p0 = u_pack[idx];
            float v0 = __int_as_float(p0.y);
            float4 e0 = h2f(ent_cur[p0.x * 16 + q]), f0 = h2f(cf_cur[p0.x * 16 + q]);
            au.x += v0 * e0.x; au.y += v0 * e0.y; au.z += v0 * e0.z; au.w += v0 * e0.w;
            ac.x += v0 * f0.x; ac.y += v0 * f0.y; ac.z += v0 * f0.z; ac.w += v0 * f0.w;
        }
    }
    au = cross_group_sum(au);
    ac = cross_group_sum(ac);
    float rn = 1.0f / fmaxf(sqrtf(grp_red16(dot4(au, au))), 1e-12f);
    float4 rr = first ? res_init[row * 16 + q] : h2f(usr_res[row * 16 + q]);
    rr.x += au.x * rn; rr.y += au.y * rn; rr.z += au.z * rn; rr.w += au.w * rn;
    if (last) {
        float rn2 = 1.0f / fmaxf(sqrtf(grp_red16(dot4(rr, rr))), 1e-12f);
        rr.x *= rn2; rr.y *= rn2; rr.z *= rn2; rr.w *= rn2;
    }
    if (g == 0) {
        usr_res[row * 16 + q] = f2h(rr);
        ucf[row * 16 + q] = f2h(ac);
    }
}

__global__ void item_agg(const int* __restrict__ off, const int2* __restrict__ i_pack,
                         const half4_t* __restrict__ ucf, half4_t* __restrict__ dst,
                         half4_t* __restrict__ res, const float4* __restrict__ res_init,
                         int first, int last) {
    int row = blockIdx.x * 4 + (threadIdx.x >> 6);
    int lane = threadIdx.x & 63;
    int g = lane >> 4, q = lane & 15;
    int s = off[row], e = off[row + 1];
    float4 acc = make_float4(0.f, 0.f, 0.f, 0.f);
    int k = s;
    for (; k + 16 <= e; k += 16) {
        int2 p0 = i_pack[k + g];
        int2 p1 = i_pack[k + 4 + g];
        int2 p2 = i_pack[k + 8 + g];
        int2 p3 = i_pack[k + 12 + g];
        float v0 = __int_as_float(p0.y), v1 = __int_as_float(p1.y);
        float v2 = __int_as_float(p2.y), v3 = __int_as_float(p3.y);
        float4 a0 = h2f(ucf[p0.x * 16 + q]);
        float4 a1 = h2f(ucf[p1.x * 16 + q]);
        float4 a2 = h2f(ucf[p2.x * 16 + q]);
        float4 a3 = h2f(ucf[p3.x * 16 + q]);
        acc.x += v0 * a0.x + v1 * a1.x + v2 * a2.x + v3 * a3.x;
        acc.y += v0 * a0.y + v1 * a1.y + v2 * a2.y + v3 * a3.y;
        acc.z += v0 * a0.z + v1 * a1.z + v2 * a2.z + v3 * a3.z;
        acc.w += v0 * a0.w + v1 * a1.w + v2 * a2.w + v3 * a3.w;
    }
    for (; k < e; k += 4) {
        int idx = k + g;
        if (idx < e) {
            int2 p0 = i_pack[idx];
            float v0 = __int_as_float(p0.y);
            float4 a0 = h2f(ucf[p0.x * 16 + q]);
            acc.x += v0 * a0.x; acc.y += v0 * a0.y;
            acc.z += v0 * a0.z; acc.w += v0 * a0.w;
        }
    }
    acc = cross_group_sum(acc);
    float rn = 1.0f / fmaxf(sqrtf(grp_red16(dot4(acc, acc))), 1e-12f);
    float4 o = make_float4(acc.x * rn, acc.y * rn, acc.z * rn, acc.w * rn);
    if (g == 0) dst[row * 16 + q] = f2h(o);
    float4 rr = first ? res_init[row * 16 + q] : h2f(res[row * 16 + q]);
    rr.x += o.x; rr.y += o.y; rr.z += o.z; rr.w += o.w;
    if (last) {
        float rn2 = 1.0f / fmaxf(sqrtf(grp_red16(dot4(rr, rr))), 1e-12f);
        rr.x *= rn2; rr.y *= rn2; rr.z *= rn2; rr.w *= rn2;
    }
    if (g == 0) res[row * 16 + q] = f2h(rr);
}

// ------------------------- losses -------------------------
__global__ void loss1_kernel(const int* __restrict__ user, const int* __restrict__ pos,
                             const int* __restrict__ neg, const half4_t* __restrict__ usr_res,
                             const half4_t* __restrict__ ent_res, const half4_t* __restrict__ cf_res,
                             float* __restrict__ l1p) {
    int b = blockIdx.x * 4 + (threadIdx.x >> 6);
    int lane = threadIdx.x & 63;
    int g = lane >> 4, q = lane & 15;
    int uid = user[b], pid = pos[b];
    float4 u = h2f(usr_res[uid * 16 + q]);
    float4 p = h2f(ent_res[pid * 16 + q]);
    float4 pc = h2f(cf_res[pid * 16 + q]);
    float dp = grp_red16(dot4(u, p) + dot4(u, pc));
    float ui_pos = fmaxf(2.0f - dp, 0.0f);
    float sum_n = 0.f, cnt_n = 0.f, sum_c = 0.f, cnt_c = 0.f;
    const int* nb = neg + b * NUM_NEG;
    for (int j = 0; j < NUM_NEG; j += 8) {
        int n0 = nb[j + g], n1 = nb[j + 4 + g];
        float4 e0 = h2f(ent_res[n0 * 16 + q]), c0 = h2f(cf_res[n0 * 16 + q]);
        float4 e1 = h2f(ent_res[n1 * 16 + q]), c1 = h2f(cf_res[n1 * 16 + q]);
        float dn0 = grp_red16(dot4(u, e0));
        float dc0 = grp_red16(dot4(u, c0));
        float dn1 = grp_red16(dot4(u, e1));
        float dc1 = grp_red16(dot4(u, c1));
        float s0 = fmaxf(dn0 - MARGIN_CCL, 0.f); sum_n += s0; if (s0 > 0.f) cnt_n += 1.f;
        float s1 = fmaxf(dn1 - MARGIN_CCL, 0.f); sum_n += s1; if (s1 > 0.f) cnt_n += 1.f;
        float t0 = fmaxf(dc0 - MARGIN_CCL, 0.f); sum_c += t0; if (t0 > 0.f) cnt_c += 1.f;
        float t1 = fmaxf(dc1 - MARGIN_CCL, 0.f); sum_c += t1; if (t1 > 0.f) cnt_c += 1.f;
    }
    sum_n = cross_grp_scalar(sum_n); cnt_n = cross_grp_scalar(cnt_n);
    sum_c = cross_grp_scalar(sum_c); cnt_c = cross_grp_scalar(cnt_c);
    if (lane == 0)
        l1p[b] = ui_pos + sum_n / (cnt_n + 1e-5f) + sum_c / (cnt_c + 1e-5f);
}

__global__ void angle_kernel(const float4* __restrict__ ent0,
                             const int* __restrict__ th, const int* __restrict__ tt,
                             float* __restrict__ l2blk) {
    int lane = threadIdx.x & 63;
    int g = lane >> 4, q = lane & 15;
    int trip = blockIdx.x * 16 + (threadIdx.x >> 6) * 4 + g;
    int h = th[trip], t = tt[trip];
    float4 hv = ent0[h * 16 + q];
    float4 tv = ent0[t * 16 + q];
    hv.x *= ANGLE_DROP; hv.y *= ANGLE_DROP; hv.z *= ANGLE_DROP; hv.w *= ANGLE_DROP;
    tv.x *= ANGLE_DROP; tv.y *= ANGLE_DROP; tv.z *= ANGLE_DROP; tv.w *= ANGLE_DROP;
    float4 dv = make_float4(hv.x - tv.x, hv.y - tv.y, hv.z - tv.z, hv.w - tv.w);
    float s_hh = grp_red16(dot4(hv, hv));
    float s_tt = grp_red16(dot4(tv, tv));
    float s_ht = grp_red16(dot4(hv, tv));
    float s_dd = grp_red16(dot4(dv, dv));
    __shared__ float sb[16];
    if (q == 0) {
        float nu = sqrtf(s_hh);
        float ed = sqrtf(s_dd);
        float sqnu = fminf(fmaxf(s_hh, 0.0f), 1.0f - EPSF);
        float ha_arg = fminf(fmaxf(0.1f * (1.0f - sqnu) / sqrtf(sqnu), -1.0f + EPSF), 1.0f - EPSF);
        float half_ap = asinf(ha_arg);
        float num = s_ht * (1.0f + s_hh) - s_hh * (1.0f + s_tt);
        float den = nu * ed * sqrtf(fmaxf(1.0f + s_tt * s_hh - 2.0f * s_ht, EPSF)) + EPSF;
        float ang = acosf(fminf(fmaxf(num / den, -1.0f + EPSF), 1.0f - EPSF));
        sb[threadIdx.x >> 4] = fmaxf(ang - half_ap, 0.0f);
    }
    __syncthreads();
    if (threadIdx.x == 0) {
        float tot = 0.f;
        #pragma unroll
        for (int i = 0; i < 16; ++i) tot += sb[i];
        l2blk[blockIdx.x] = tot;
    }
}

__global__ void finalize_kernel(const float* __restrict__ l1p, const float* __restrict__ l2b,
                                float* __restrict__ out) {
    __shared__ float sb[1024];
    float a1 = 0.f;
    for (int i = threadIdx.x; i < BATCH; i += 1024) a1 += l1p[i];
    float a2 = 0.f;
    for (int i = threadIdx.x; i < ANGLE_BLOCKS; i += 1024) a2 += l2b[i];
    sb[threadIdx.x] = a1 / (float)BATCH + ANGLE_W * a2 / (float)N_TRIPLETS;
    __syncthreads();
    for (int s = 512; s > 0; s >>= 1) {
        if (threadIdx.x < s) sb[threadIdx.x] += sb[threadIdx.x + s];
        __syncthreads();
    }
    if (threadIdx.x == 0) out[0] = sb[0];
}

extern "C" void kernel_launch(void* const* d_in, const int* in_sizes, int n_in,
                              void* d_out, int out_size, void* d_ws, size_t ws_size,
                              hipStream_t stream) {
    const float* all_embed = (const float*)d_in[0];
    const float* item_cf0  = (const float*)d_in[1];
    const float* relw      = (const float*)d_in[2];
    const float* vals      = (const float*)d_in[3];
    const int* user        = (const int*)d_in[4];
    const int* pos_item    = (const int*)d_in[5];
    const int* neg_item    = (const int*)d_in[6];
    const int* edge_head   = (const int*)d_in[7];
    const int* edge_tail   = edge_head + N_EDGES;
    const int* etype       = (const int*)d_in[8];
    const int* irows       = (const int*)d_in[9];
    const int* icols       = (const int*)d_in[10];
    const int* th          = (const int*)d_in[11];
    const int* tt          = (const int*)d_in[12];
    float* out             = (float*)d_out;

    // ---------------- workspace layout (256 B aligned chunks) ----------------
    char* base = (char*)d_ws;
    size_t woff = 0;
    auto alloc = [&](size_t bytes) -> void* {
        void* p = base + woff;
        woff = (woff + bytes + 255) & ~(size_t)255;
        return p;
    };
    half4_t* ent_a   = (half4_t*)alloc((size_t)N_ENTITIES * EMB * 2);
    half4_t* ent_b   = (half4_t*)alloc((size_t)N_ENTITIES * EMB * 2);
    half4_t* cf_a    = (half4_t*)alloc((size_t)N_ITEMS * EMB * 2);
    half4_t* cf_b    = (half4_t*)alloc((size_t)N_ITEMS * EMB * 2);
    half4_t* ucf     = (half4_t*)alloc((size_t)N_USERS * EMB * 2);
    half4_t* ent_res = (half4_t*)alloc((size_t)N_ITEMS * EMB * 2);
    half4_t* usr_res = (half4_t*)alloc((size_t)N_USERS * EMB * 2);
    half4_t* cf_res  = (half4_t*)alloc((size_t)N_ITEMS * EMB * 2);
    int2* u_pack     = (int2*)alloc((size_t)NNZ * 8);
    int2* i_pack     = (int2*)alloc((size_t)NNZ * 8);
    int* kg_pack     = (int*)alloc((size_t)N_EDGES * 4);
    int* keys_e      = (int*)alloc((size_t)N_EDGES * 4);
    int* keys_u      = (int*)alloc((size_t)NNZ * 4);
    int* keys_i      = (int*)alloc((size_t)NNZ * 4);
    float* l1p       = (float*)alloc((size_t)BATCH * 4);
    float* l2blk     = (float*)alloc((size_t)ANGLE_BLOCKS * 4);
    int* cnt_e       = (int*)alloc((size_t)N_ENTITIES * 4);
    int* cnt_u       = (int*)alloc((size_t)N_USERS * 4);
    int* cnt_i       = (int*)alloc((size_t)N_ITEMS * 4);
    int* off_e       = (int*)alloc((size_t)(N_ENTITIES + 1) * 4);
    int* off_u       = (int*)alloc((size_t)(N_USERS + 1) * 4);
    int* off_i       = (int*)alloc((size_t)(N_ITEMS + 1) * 4);
    int* bcur_e      = (int*)alloc(256 * 4);
    int* bcur_u      = (int*)alloc(256 * 4);
    int* bcur_i      = (int*)alloc(256 * 4);
    int* part_e      = (int*)alloc(256 * 4);
    int* part_u      = (int*)alloc(256 * 4);
    int* part_i      = (int*)alloc(256 * 4);

    const float* ent0 = all_embed + (size_t)N_USERS * EMB;

    // ---------------- fp16 conversions of hop-0 tables ----------------
    f32_to_f16<<<(N_ENTITIES * 16 + 255) / 256, 256, 0, stream>>>((const float4*)ent0, ent_a,
                                                                  N_ENTITIES * 16);
    f32_to_f16<<<(N_ITEMS * 16 + 255) / 256, 256, 0, stream>>>((const float4*)item_cf0, cf_a,
                                                               N_ITEMS * 16);

    // ---------------- CSR build ----------------
    hipMemsetAsync(cnt_e, 0, (size_t)N_ENTITIES * 4, stream);
    hipMemsetAsync(cnt_u, 0, (size_t)N_USERS * 4, stream);
    hipMemsetAsync(cnt_i, 0, (size_t)N_ITEMS * 4, stream);
    hist_edges<<<(N_EDGES + 255) / 256, 256, 0, stream>>>(edge_head, cnt_e);
    hist_inter<<<(NNZ + 255) / 256, 256, 0, stream>>>(irows, icols, cnt_u, cnt_i);

    const int nb_e = (N_ENTITIES + 1023) / 1024;
    const int nb_u = (N_USERS + 1023) / 1024;
    const int nb_i = (N_ITEMS + 1023) / 1024;
    scan_l1<<<nb_e, 256, 0, stream>>>(cnt_e, off_e, part_e, N_ENTITIES);
    scan_l2<<<1, 256, 0, stream>>>(part_e, nb_e);
    scan_l3<<<(N_ENTITIES + 255) / 256, 256, 0, stream>>>(off_e, part_e, N_ENTITIES, N_EDGES);
    scan_l1<<<nb_u, 256, 0, stream>>>(cnt_u, off_u, part_u, N_USERS);
    scan_l2<<<1, 256, 0, stream>>>(part_u, nb_u);
    scan_l3<<<(N_USERS + 255) / 256, 256, 0, stream>>>(off_u, part_u, N_USERS, NNZ);
    scan_l1<<<nb_i, 256, 0, stream>>>(cnt_i, off_i, part_i, N_ITEMS);
    scan_l2<<<1, 256, 0, stream>>>(part_i, nb_i);
    scan_l3<<<(N_ITEMS + 255) / 256, 256, 0, stream>>>(off_i, part_i, N_ITEMS, NNZ);

    init_bcur<<<1, 256, 0, stream>>>(off_e, off_u, off_i, bcur_e, bcur_u, bcur_i);

    const int np1_e = (N_EDGES + TILE1 - 1) / TILE1;
    const int np1_n = (NNZ + TILE1 - 1) / TILE1;
    phase1_edges<<<np1_e, 256, 0, stream>>>(edge_head, edge_tail, etype, bcur_e, keys_e, kg_pack);
    phase1_inter<<<np1_n, 256, 0, stream>>>(irows, icols, vals, bcur_u, keys_u, u_pack, 9);
    phase1_inter<<<np1_n, 256, 0, stream>>>(icols, irows, vals, bcur_i, keys_i, i_pack, 8);

    phase2_edges<<<NBUCK, 256, 0, stream>>>(off_e, keys_e, kg_pack);
    phase2_inter<<<NBUCK, 256, 0, stream>>>(off_u, keys_u, u_pack, 9, N_USERS);
    phase2_inter<<<NBUCK, 256, 0, stream>>>(off_i, keys_i, i_pack, 8, N_ITEMS);

    // ---------------- hops ----------------
    half4_t* ent_cur = ent_a; half4_t* ent_nxt = ent_b;
    half4_t* cf_cur  = cf_a;  half4_t* cf_nxt  = cf_b;

    for (int hop = 0; hop < HOPS; ++hop) {
        int first = (hop == 0) ? 1 : 0;
        int last = (hop == HOPS - 1) ? 1 : 0;
        kg_agg<<<N_ENTITIES / 4, 256, 0, stream>>>(off_e, kg_pack, relw, ent_cur, ent_nxt,
                                                   ent_res, (const float4*)ent0, first, last);
        user_agg<<<N_USERS / 4, 256, 0, stream>>>(off_u, u_pack, ent_cur, cf_cur, usr_res,
                                                  (const float4*)all_embed, ucf, first, last);
        item_agg<<<N_ITEMS / 4, 256, 0, stream>>>(off_i, i_pack, ucf, cf_nxt, cf_res,
                                                  (const float4*)item_cf0, first, last);
        half4_t* tmp = ent_cur; ent_cur = ent_nxt; ent_nxt = tmp;
        tmp = cf_cur; cf_cur = cf_nxt; cf_nxt = tmp;
    }

    loss1_kernel<<<BATCH / 4, 256, 0, stream>>>(user, pos_item, neg_item, usr_res,
                                                ent_res, cf_res, l1p);
    angle_kernel<<<ANGLE_BLOCKS, 256, 0, stream>>>((const float4*)ent0, th, tt, l2blk);
    finalize_kernel<<<1, 1024, 0, stream>>>(l1p, l2blk, out);
}

// Round 6
// 625.131 us; speedup vs baseline: 3.8978x; 1.2614x over previous
//
#include <hip/hip_runtime.h>
#include <math.h>

#define N_USERS    100000
#define N_ITEMS    50000
#define N_ENTITIES 200000
#define N_REL      20
#define EMB        64
#define HOPS       2
#define MARGIN_CCL 0.8f
#define NUM_NEG    64
#define ANGLE_W    0.1f
#define ANGLE_DROP 0.5f
#define N_EDGES    1000000
#define NNZ        1000000
#define N_TRIPLETS 200000
#define BATCH      4096
#define EPSF       1e-6f

#define ANGLE_BLOCKS (N_TRIPLETS / 16)   // 12500
#define TILE1 4096
#define NBUCK 196
#define BCAP  9216

typedef _Float16 half4_t __attribute__((ext_vector_type(4)));
typedef _Float16 half8_t __attribute__((ext_vector_type(8)));
typedef float float8_t __attribute__((ext_vector_type(8)));

__device__ inline float4 h2f(half4_t h) {
    return make_float4((float)h.x, (float)h.y, (float)h.z, (float)h.w);
}
__device__ inline half4_t f2h(float4 f) {
    half4_t h; h.x = (_Float16)f.x; h.y = (_Float16)f.y;
    h.z = (_Float16)f.z; h.w = (_Float16)f.w; return h;
}
__device__ inline float8_t h8_to_f8(half8_t h) { return __builtin_convertvector(h, float8_t); }
__device__ inline half8_t f8_to_h8(float8_t f) { return __builtin_convertvector(f, half8_t); }
__device__ inline half8_t h8_zero() {
    half8_t z;
    #pragma unroll
    for (int i = 0; i < 8; ++i) z[i] = (_Float16)0.0f;
    return z;
}
__device__ inline float sum_sq8(float8_t f) {
    float s = 0.f;
    #pragma unroll
    for (int i = 0; i < 8; ++i) s += f[i] * f[i];
    return s;
}
__device__ inline float8_t f8_from2(float4 lo, float4 hi) {
    float8_t f;
    f[0] = lo.x; f[1] = lo.y; f[2] = lo.z; f[3] = lo.w;
    f[4] = hi.x; f[5] = hi.y; f[6] = hi.z; f[7] = hi.w;
    return f;
}
// sum within each group of 8 lanes — replicated within group
__device__ inline float grp_red8(float v) {
    v += __shfl_xor(v, 1, 64); v += __shfl_xor(v, 2, 64); v += __shfl_xor(v, 4, 64);
    return v;
}
// (loss1 helpers: 16-lane groups)
__device__ inline float dot4(float4 a, float4 b) {
    return a.x * b.x + a.y * b.y + a.z * b.z + a.w * b.w;
}
__device__ inline float grp_red16(float v) {
    v += __shfl_xor(v, 1, 64); v += __shfl_xor(v, 2, 64);
    v += __shfl_xor(v, 4, 64); v += __shfl_xor(v, 8, 64);
    return v;
}
__device__ inline float cross_grp_scalar(float v) {
    v += __shfl_xor(v, 16, 64); v += __shfl_xor(v, 32, 64);
    return v;
}

// ------------------------- fp32 -> fp16 table conversion -------------------------
__global__ void f32_to_f16(const float4* __restrict__ in, half4_t* __restrict__ out, int n4) {
    int i = blockIdx.x * blockDim.x + threadIdx.x;
    if (i < n4) out[i] = f2h(h2f(f2h(make_float4(in[i].x, in[i].y, in[i].z, in[i].w))));
}

// ------------------------- CSR build: histogram -------------------------
__global__ void hist_edges(const int* __restrict__ head, int* __restrict__ cnt_e) {
    int e = blockIdx.x * blockDim.x + threadIdx.x;
    if (e < N_EDGES) atomicAdd(&cnt_e[head[e]], 1);
}

__global__ void hist_inter(const int* __restrict__ rows, const int* __restrict__ cols,
                           int* __restrict__ cnt_u, int* __restrict__ cnt_i) {
    int i = blockIdx.x * blockDim.x + threadIdx.x;
    if (i < NNZ) {
        atomicAdd(&cnt_u[rows[i]], 1);
        atomicAdd(&cnt_i[cols[i]], 1);
    }
}

// ------------------------- 2-level exclusive scan -------------------------
__global__ void scan_l1(const int* __restrict__ in, int* __restrict__ out,
                        int* __restrict__ partials, int N) {
    int base = blockIdx.x * 1024 + threadIdx.x * 4;
    int a0 = 0, a1 = 0, a2 = 0, a3 = 0;
    if (base + 0 < N) a0 = in[base + 0];
    if (base + 1 < N) a1 = in[base + 1];
    if (base + 2 < N) a2 = in[base + 2];
    if (base + 3 < N) a3 = in[base + 3];
    int tot = a0 + a1 + a2 + a3;
    __shared__ int s[256];
    s[threadIdx.x] = tot;
    __syncthreads();
    for (int d = 1; d < 256; d <<= 1) {
        int x = 0;
        if (threadIdx.x >= d) x = s[threadIdx.x - d];
        __syncthreads();
        s[threadIdx.x] += x;
        __syncthreads();
    }
    int excl = (threadIdx.x == 0) ? 0 : s[threadIdx.x - 1];
    if (threadIdx.x == 255) partials[blockIdx.x] = s[255];
    int r = excl;
    if (base + 0 < N) out[base + 0] = r; r += a0;
    if (base + 1 < N) out[base + 1] = r; r += a1;
    if (base + 2 < N) out[base + 2] = r; r += a2;
    if (base + 3 < N) out[base + 3] = r;
}

__global__ void scan_l2(int* __restrict__ partials, int nb) {
    __shared__ int s[256];
    int t = threadIdx.x;
    int v = (t < nb) ? partials[t] : 0;
    s[t] = v;
    __syncthreads();
    for (int d = 1; d < 256; d <<= 1) {
        int x = 0;
        if (t >= d) x = s[t - d];
        __syncthreads();
        s[t] += x;
        __syncthreads();
    }
    int excl = (t == 0) ? 0 : s[t - 1];
    if (t < nb) partials[t] = excl;
}

__global__ void scan_l3(int* __restrict__ out, const int* __restrict__ partials,
                        int N, int total) {
    int i = blockIdx.x * 256 + threadIdx.x;
    if (i < N) out[i] = out[i] + partials[i >> 10];
    if (i == 0) out[N] = total;
}

__global__ void init_bcur(const int* __restrict__ off_e, const int* __restrict__ off_u,
                          const int* __restrict__ off_i, int* __restrict__ be,
                          int* __restrict__ bu, int* __restrict__ bi) {
    int t = threadIdx.x;
    be[t] = off_e[min(t << 10, N_ENTITIES)];
    bu[t] = off_u[min(t << 9, N_USERS)];
    bi[t] = off_i[min(t << 8, N_ITEMS)];
}

// ------------------------- phase 1: LDS-binned placement -------------------------
__global__ void phase1_edges(const int* __restrict__ head, const int* __restrict__ tail,
                             const int* __restrict__ etype, int* __restrict__ bcur,
                             int* __restrict__ keys, int* __restrict__ pay) {
    __shared__ int lhist[256], lstart[256], lcur[256], gbase[256];
    __shared__ int key_st[TILE1];
    __shared__ int pay_st[TILE1];
    int t = threadIdx.x;
    int tstart = blockIdx.x * TILE1;
    int valid = min(TILE1, N_EDGES - tstart);
    lhist[t] = 0;
    __syncthreads();
    for (int i = t; i < valid; i += 256) atomicAdd(&lhist[head[tstart + i] >> 10], 1);
    __syncthreads();
    int v = lhist[t];
    lstart[t] = v;
    __syncthreads();
    for (int d = 1; d < 256; d <<= 1) {
        int x = (t >= d) ? lstart[t - d] : 0;
        __syncthreads();
        lstart[t] += x;
        __syncthreads();
    }
    int excl = lstart[t] - v;
    lstart[t] = excl;
    lcur[t] = excl;
    gbase[t] = atomicAdd(&bcur[t], v);
    __syncthreads();
    for (int i = t; i < valid; i += 256) {
        int h = head[tstart + i];
        int p = tail[tstart + i] | ((etype[tstart + i] - 1) << 18);
        int sp = atomicAdd(&lcur[h >> 10], 1);
        key_st[sp] = h;
        pay_st[sp] = p;
    }
    __syncthreads();
    for (int j = t; j < valid; j += 256) {
        int k = key_st[j];
        int b = k >> 10;
        int pos = gbase[b] + (j - lstart[b]);
        keys[pos] = k;
        pay[pos] = pay_st[j];
    }
}

__global__ void phase1_inter(const int* __restrict__ key_arr, const int* __restrict__ other,
                             const float* __restrict__ vals, int* __restrict__ bcur,
                             int* __restrict__ keys, int2* __restrict__ pay, int shift) {
    __shared__ int lhist[256], lstart[256], lcur[256], gbase[256];
    __shared__ int key_st[TILE1];
    __shared__ int2 pay_st[TILE1];
    int t = threadIdx.x;
    int tstart = blockIdx.x * TILE1;
    int valid = min(TILE1, NNZ - tstart);
    lhist[t] = 0;
    __syncthreads();
    for (int i = t; i < valid; i += 256) atomicAdd(&lhist[key_arr[tstart + i] >> shift], 1);
    __syncthreads();
    int v = lhist[t];
    lstart[t] = v;
    __syncthreads();
    for (int d = 1; d < 256; d <<= 1) {
        int x = (t >= d) ? lstart[t - d] : 0;
        __syncthreads();
        lstart[t] += x;
        __syncthreads();
    }
    int excl = lstart[t] - v;
    lstart[t] = excl;
    lcur[t] = excl;
    gbase[t] = atomicAdd(&bcur[t], v);
    __syncthreads();
    for (int i = t; i < valid; i += 256) {
        int k = key_arr[tstart + i];
        int2 p = make_int2(other[tstart + i], __float_as_int(vals[tstart + i]));
        int sp = atomicAdd(&lcur[k >> shift], 1);
        key_st[sp] = k;
        pay_st[sp] = p;
    }
    __syncthreads();
    for (int j = t; j < valid; j += 256) {
        int k = key_st[j];
        int b = k >> shift;
        int pos = gbase[b] + (j - lstart[b]);
        keys[pos] = k;
        pay[pos] = pay_st[j];
    }
}

// ------------------------- phase 2: in-bucket ordering via LDS -------------------------
__global__ void phase2_edges(const int* __restrict__ off, const int* __restrict__ keys,
                             int* __restrict__ pay) {
    __shared__ int lcur[1024];
    __shared__ int lout[BCAP];
    int b = blockIdx.x, t = threadIdx.x;
    int rs = b << 10;
    int re = min(rs + 1024, N_ENTITIES);
    int base = off[rs];
    int len = off[re] - base;
    for (int r = t; r < re - rs; r += 256) lcur[r] = off[rs + r] - base;
    __syncthreads();
    for (int j = t; j < len; j += 256) {
        int k = keys[base + j];
        int slot = atomicAdd(&lcur[k - rs], 1);
        lout[slot] = pay[base + j];
    }
    __syncthreads();
    for (int j = t; j < len; j += 256) pay[base + j] = lout[j];
}

__global__ void phase2_inter(const int* __restrict__ off, const int* __restrict__ keys,
                             int2* __restrict__ pay, int shift, int n_rows) {
    __shared__ int lcur[512];
    __shared__ int2 lout[BCAP];
    int b = blockIdx.x, t = threadIdx.x;
    int rs = b << shift;
    int re = min(rs + (1 << shift), n_rows);
    int base = off[rs];
    int len = off[re] - base;
    for (int r = t; r < re - rs; r += 256) lcur[r] = off[rs + r] - base;
    __syncthreads();
    for (int j = t; j < len; j += 256) {
        int k = keys[base + j];
        int slot = atomicAdd(&lcur[k - rs], 1);
        lout[slot] = pay[base + j];
    }
    __syncthreads();
    for (int j = t; j < len; j += 256) pay[base + j] = lout[j];
}

// ------------------------- hop kernels: group-per-row, 8 lanes x half8 -------------
// group (8 lanes) owns one row; lane o covers dims [8o,8o+8); fp16 pk_fma accumulate.
__global__ void kg_agg(const int* __restrict__ off, const int* __restrict__ pack,
                       const float* __restrict__ relw, const half8_t* __restrict__ src,
                       half8_t* __restrict__ dst, half8_t* __restrict__ res,
                       const float4* __restrict__ res_init, int first, int last) {
    __shared__ half8_t srel[(N_REL - 1) * 9];   // stride 9 -> rotated banks
    int t = threadIdx.x;
    if (t < (N_REL - 1) * 8) {
        int rel = t >> 3, o = t & 7;
        const float4* r4 = (const float4*)relw;
        srel[rel * 9 + o] = f8_to_h8(f8_from2(r4[rel * 16 + o * 2], r4[rel * 16 + o * 2 + 1]));
    }
    __syncthreads();
    int row = blockIdx.x * 32 + (t >> 3);
    int o = t & 7;
    int s = off[row], e = off[row + 1];
    half8_t acc = h8_zero();
    int k = s;
    for (; k + 2 <= e; k += 2) {
        int p0 = pack[k], p1 = pack[k + 1];
        half8_t a0 = src[(p0 & 0x3FFFF) * 8 + o];
        half8_t b0 = srel[(p0 >> 18) * 9 + o];
        half8_t a1 = src[(p1 & 0x3FFFF) * 8 + o];
        half8_t b1 = srel[(p1 >> 18) * 9 + o];
        acc += a0 * b0;
        acc += a1 * b1;
    }
    if (k < e) {
        int p0 = pack[k];
        acc += src[(p0 & 0x3FFFF) * 8 + o] * srel[(p0 >> 18) * 9 + o];
    }
    float8_t f = h8_to_f8(acc);
    float inv = 1.0f / fmaxf((float)(e - s), 1.0f);
    f *= inv;
    float ss = grp_red8(sum_sq8(f));
    float rn = 1.0f / fmaxf(sqrtf(ss), 1e-12f);
    f *= rn;
    dst[row * 8 + o] = f8_to_h8(f);
    if (row < N_ITEMS) {
        float8_t rr;
        if (first) rr = f8_from2(res_init[row * 16 + o * 2], res_init[row * 16 + o * 2 + 1]);
        else       rr = h8_to_f8(res[row * 8 + o]);
        rr += f;
        if (last) {
            float s2 = grp_red8(sum_sq8(rr));
            rr *= 1.0f / fmaxf(sqrtf(s2), 1e-12f);
        }
        res[row * 8 + o] = f8_to_h8(rr);
    }
}

__global__ void user_agg(const int* __restrict__ off, const int2* __restrict__ u_pack,
                         const half8_t* __restrict__ ent_cur, const half8_t* __restrict__ cf_cur,
                         half8_t* __restrict__ usr_res, const float4* __restrict__ res_init,
                         half8_t* __restrict__ ucf, int first, int last) {
    int t = threadIdx.x;
    int row = blockIdx.x * 32 + (t >> 3);
    int o = t & 7;
    int s = off[row], e = off[row + 1];
    half8_t au = h8_zero();
    half8_t ac = h8_zero();
    int k = s;
    for (; k + 2 <= e; k += 2) {
        int2 p0 = u_pack[k], p1 = u_pack[k + 1];
        _Float16 v0 = (_Float16)__int_as_float(p0.y);
        _Float16 v1 = (_Float16)__int_as_float(p1.y);
        au += ent_cur[p0.x * 8 + o] * v0;
        ac += cf_cur[p0.x * 8 + o] * v0;
        au += ent_cur[p1.x * 8 + o] * v1;
        ac += cf_cur[p1.x * 8 + o] * v1;
    }
    if (k < e) {
        int2 p0 = u_pack[k];
        _Float16 v0 = (_Float16)__int_as_float(p0.y);
        au += ent_cur[p0.x * 8 + o] * v0;
        ac += cf_cur[p0.x * 8 + o] * v0;
    }
    float8_t f = h8_to_f8(au);
    float ss = grp_red8(sum_sq8(f));
    float rn = 1.0f / fmaxf(sqrtf(ss), 1e-12f);
    float8_t rr;
    if (first) rr = f8_from2(res_init[row * 16 + o * 2], res_init[row * 16 + o * 2 + 1]);
    else       rr = h8_to_f8(usr_res[row * 8 + o]);
    rr += f * rn;
    if (last) {
        float s2 = grp_red8(sum_sq8(rr));
        rr *= 1.0f / fmaxf(sqrtf(s2), 1e-12f);
    }
    usr_res[row * 8 + o] = f8_to_h8(rr);
    ucf[row * 8 + o] = ac;
}

__global__ void item_agg(const int* __restrict__ off, const int2* __restrict__ i_pack,
                         const half8_t* __restrict__ ucf, half8_t* __restrict__ dst,
                         half8_t* __restrict__ res, const float4* __restrict__ res_init,
                         int first, int last) {
    int t = threadIdx.x;
    int row = blockIdx.x * 32 + (t >> 3);
    int o = t & 7;
    if (row >= N_ITEMS) return;
    int s = off[row], e = off[row + 1];
    half8_t acc = h8_zero();
    int k = s;
    for (; k + 2 <= e; k += 2) {
        int2 p0 = i_pack[k], p1 = i_pack[k + 1];
        _Float16 v0 = (_Float16)__int_as_float(p0.y);
        _Float16 v1 = (_Float16)__int_as_float(p1.y);
        acc += ucf[p0.x * 8 + o] * v0;
        acc += ucf[p1.x * 8 + o] * v1;
    }
    if (k < e) {
        int2 p0 = i_pack[k];
        acc += ucf[p0.x * 8 + o] * (_Float16)__int_as_float(p0.y);
    }
    float8_t f = h8_to_f8(acc);
    float ss = grp_red8(sum_sq8(f));
    float rn = 1.0f / fmaxf(sqrtf(ss), 1e-12f);
    f *= rn;
    dst[row * 8 + o] = f8_to_h8(f);
    float8_t rr;
    if (first) rr = f8_from2(res_init[row * 16 + o * 2], res_init[row * 16 + o * 2 + 1]);
    else       rr = h8_to_f8(res[row * 8 + o]);
    rr += f;
    if (last) {
        float s2 = grp_red8(sum_sq8(rr));
        rr *= 1.0f / fmaxf(sqrtf(s2), 1e-12f);
    }
    res[row * 8 + o] = f8_to_h8(rr);
}

// ------------------------- losses -------------------------
__global__ void loss1_kernel(const int* __restrict__ user, const int* __restrict__ pos,
                             const int* __restrict__ neg, const half4_t* __restrict__ usr_res,
                             const half4_t* __restrict__ ent_res, const half4_t* __restrict__ cf_res,
                             float* __restrict__ l1p) {
    int b = blockIdx.x * 4 + (threadIdx.x >> 6);
    int lane = threadIdx.x & 63;
    int g = lane >> 4, q = lane & 15;
    int uid = user[b], pid = pos[b];
    float4 u = h2f(usr_res[uid * 16 + q]);
    float4 p = h2f(ent_res[pid * 16 + q]);
    float4 pc = h2f(cf_res[pid * 16 + q]);
    float dp = grp_red16(dot4(u, p) + dot4(u, pc));
    float ui_pos = fmaxf(2.0f - dp, 0.0f);
    float sum_n = 0.f, cnt_n = 0.f, sum_c = 0.f, cnt_c = 0.f;
    const int* nb = neg + b * NUM_NEG;
    for (int j = 0; j < NUM_NEG; j += 8) {
        int n0 = nb[j + g], n1 = nb[j + 4 + g];
        float4 e0 = h2f(ent_res[n0 * 16 + q]), c0 = h2f(cf_res[n0 * 16 + q]);
        float4 e1 = h2f(ent_res[n1 * 16 + q]), c1 = h2f(cf_res[n1 * 16 + q]);
        float dn0 = grp_red16(dot4(u, e0));
        float dc0 = grp_red16(dot4(u, c0));
        float dn1 = grp_red16(dot4(u, e1));
        float dc1 = grp_red16(dot4(u, c1));
        float s0 = fmaxf(dn0 - MARGIN_CCL, 0.f); sum_n += s0; if (s0 > 0.f) cnt_n += 1.f;
        float s1 = fmaxf(dn1 - MARGIN_CCL, 0.f); sum_n += s1; if (s1 > 0.f) cnt_n += 1.f;
        float t0 = fmaxf(dc0 - MARGIN_CCL, 0.f); sum_c += t0; if (t0 > 0.f) cnt_c += 1.f;
        float t1 = fmaxf(dc1 - MARGIN_CCL, 0.f); sum_c += t1; if (t1 > 0.f) cnt_c += 1.f;
    }
    sum_n = cross_grp_scalar(sum_n); cnt_n = cross_grp_scalar(cnt_n);
    sum_c = cross_grp_scalar(sum_c); cnt_c = cross_grp_scalar(cnt_c);
    if (lane == 0)
        l1p[b] = ui_pos + sum_n / (cnt_n + 1e-5f) + sum_c / (cnt_c + 1e-5f);
}

__global__ void angle_kernel(const float4* __restrict__ ent0,
                             const int* __restrict__ th, const int* __restrict__ tt,
                             float* __restrict__ l2blk) {
    int lane = threadIdx.x & 63;
    int g = lane >> 4, q = lane & 15;
    int trip = blockIdx.x * 16 + (threadIdx.x >> 6) * 4 + g;
    int h = th[trip], t = tt[trip];
    float4 hv = ent0[h * 16 + q];
    float4 tv = ent0[t * 16 + q];
    hv.x *= ANGLE_DROP; hv.y *= ANGLE_DROP; hv.z *= ANGLE_DROP; hv.w *= ANGLE_DROP;
    tv.x *= ANGLE_DROP; tv.y *= ANGLE_DROP; tv.z *= ANGLE_DROP; tv.w *= ANGLE_DROP;
    float4 dv = make_float4(hv.x - tv.x, hv.y - tv.y, hv.z - tv.z, hv.w - tv.w);
    float s_hh = grp_red16(dot4(hv, hv));
    float s_tt = grp_red16(dot4(tv, tv));
    float s_ht = grp_red16(dot4(hv, tv));
    float s_dd = grp_red16(dot4(dv, dv));
    __shared__ float sb[16];
    if (q == 0) {
        float nu = sqrtf(s_hh);
        float ed = sqrtf(s_dd);
        float sqnu = fminf(fmaxf(s_hh, 0.0f), 1.0f - EPSF);
        float ha_arg = fminf(fmaxf(0.1f * (1.0f - sqnu) / sqrtf(sqnu), -1.0f + EPSF), 1.0f - EPSF);
        float half_ap = asinf(ha_arg);
        float num = s_ht * (1.0f + s_hh) - s_hh * (1.0f + s_tt);
        float den = nu * ed * sqrtf(fmaxf(1.0f + s_tt * s_hh - 2.0f * s_ht, EPSF)) + EPSF;
        float ang = acosf(fminf(fmaxf(num / den, -1.0f + EPSF), 1.0f - EPSF));
        sb[threadIdx.x >> 4] = fmaxf(ang - half_ap, 0.0f);
    }
    __syncthreads();
    if (threadIdx.x == 0) {
        float tot = 0.f;
        #pragma unroll
        for (int i = 0; i < 16; ++i) tot += sb[i];
        l2blk[blockIdx.x] = tot;
    }
}

__global__ void finalize_kernel(const float* __restrict__ l1p, const float* __restrict__ l2b,
                                float* __restrict__ out) {
    __shared__ float sb[1024];
    float a1 = 0.f;
    for (int i = threadIdx.x; i < BATCH; i += 1024) a1 += l1p[i];
    float a2 = 0.f;
    for (int i = threadIdx.x; i < ANGLE_BLOCKS; i += 1024) a2 += l2b[i];
    sb[threadIdx.x] = a1 / (float)BATCH + ANGLE_W * a2 / (float)N_TRIPLETS;
    __syncthreads();
    for (int s = 512; s > 0; s >>= 1) {
        if (threadIdx.x < s) sb[threadIdx.x] += sb[threadIdx.x + s];
        __syncthreads();
    }
    if (threadIdx.x == 0) out[0] = sb[0];
}

extern "C" void kernel_launch(void* const* d_in, const int* in_sizes, int n_in,
                              void* d_out, int out_size, void* d_ws, size_t ws_size,
                              hipStream_t stream) {
    const float* all_embed = (const float*)d_in[0];
    const float* item_cf0  = (const float*)d_in[1];
    const float* relw      = (const float*)d_in[2];
    const float* vals      = (const float*)d_in[3];
    const int* user        = (const int*)d_in[4];
    const int* pos_item    = (const int*)d_in[5];
    const int* neg_item    = (const int*)d_in[6];
    const int* edge_head   = (const int*)d_in[7];
    const int* edge_tail   = edge_head + N_EDGES;
    const int* etype       = (const int*)d_in[8];
    const int* irows       = (const int*)d_in[9];
    const int* icols       = (const int*)d_in[10];
    const int* th          = (const int*)d_in[11];
    const int* tt          = (const int*)d_in[12];
    float* out             = (float*)d_out;

    // ---------------- workspace layout (256 B aligned chunks) ----------------
    char* base = (char*)d_ws;
    size_t woff = 0;
    auto alloc = [&](size_t bytes) -> void* {
        void* p = base + woff;
        woff = (woff + bytes + 255) & ~(size_t)255;
        return p;
    };
    half8_t* ent_a   = (half8_t*)alloc((size_t)N_ENTITIES * EMB * 2);
    half8_t* ent_b   = (half8_t*)alloc((size_t)N_ENTITIES * EMB * 2);
    half8_t* cf_a    = (half8_t*)alloc((size_t)N_ITEMS * EMB * 2);
    half8_t* cf_b    = (half8_t*)alloc((size_t)N_ITEMS * EMB * 2);
    half8_t* ucf     = (half8_t*)alloc((size_t)N_USERS * EMB * 2);
    half8_t* ent_res = (half8_t*)alloc((size_t)N_ITEMS * EMB * 2);
    half8_t* usr_res = (half8_t*)alloc((size_t)N_USERS * EMB * 2);
    half8_t* cf_res  = (half8_t*)alloc((size_t)N_ITEMS * EMB * 2);
    int2* u_pack     = (int2*)alloc((size_t)NNZ * 8);
    int2* i_pack     = (int2*)alloc((size_t)NNZ * 8);
    int* kg_pack     = (int*)alloc((size_t)N_EDGES * 4);
    int* keys_e      = (int*)alloc((size_t)N_EDGES * 4);
    int* keys_u      = (int*)alloc((size_t)NNZ * 4);
    int* keys_i      = (int*)alloc((size_t)NNZ * 4);
    float* l1p       = (float*)alloc((size_t)BATCH * 4);
    float* l2blk     = (float*)alloc((size_t)ANGLE_BLOCKS * 4);
    int* cnt_e       = (int*)alloc((size_t)N_ENTITIES * 4);
    int* cnt_u       = (int*)alloc((size_t)N_USERS * 4);
    int* cnt_i       = (int*)alloc((size_t)N_ITEMS * 4);
    int* off_e       = (int*)alloc((size_t)(N_ENTITIES + 1) * 4);
    int* off_u       = (int*)alloc((size_t)(N_USERS + 1) * 4);
    int* off_i       = (int*)alloc((size_t)(N_ITEMS + 1) * 4);
    int* bcur_e      = (int*)alloc(256 * 4);
    int* bcur_u      = (int*)alloc(256 * 4);
    int* bcur_i      = (int*)alloc(256 * 4);
    int* part_e      = (int*)alloc(256 * 4);
    int* part_u      = (int*)alloc(256 * 4);
    int* part_i      = (int*)alloc(256 * 4);

    const float* ent0 = all_embed + (size_t)N_USERS * EMB;

    // ---------------- fp16 conversions of hop-0 tables ----------------
    f32_to_f16<<<(N_ENTITIES * 16 + 255) / 256, 256, 0, stream>>>((const float4*)ent0,
                                                                  (half4_t*)ent_a, N_ENTITIES * 16);
    f32_to_f16<<<(N_ITEMS * 16 + 255) / 256, 256, 0, stream>>>((const float4*)item_cf0,
                                                               (half4_t*)cf_a, N_ITEMS * 16);

    // ---------------- CSR build ----------------
    hipMemsetAsync(cnt_e, 0, (size_t)N_ENTITIES * 4, stream);
    hipMemsetAsync(cnt_u, 0, (size_t)N_USERS * 4, stream);
    hipMemsetAsync(cnt_i, 0, (size_t)N_ITEMS * 4, stream);
    hist_edges<<<(N_EDGES + 255) / 256, 256, 0, stream>>>(edge_head, cnt_e);
    hist_inter<<<(NNZ + 255) / 256, 256, 0, stream>>>(irows, icols, cnt_u, cnt_i);

    const int nb_e = (N_ENTITIES + 1023) / 1024;
    const int nb_u = (N_USERS + 1023) / 1024;
    const int nb_i = (N_ITEMS + 1023) / 1024;
    scan_l1<<<nb_e, 256, 0, stream>>>(cnt_e, off_e, part_e, N_ENTITIES);
    scan_l2<<<1, 256, 0, stream>>>(part_e, nb_e);
    scan_l3<<<(N_ENTITIES + 255) / 256, 256, 0, stream>>>(off_e, part_e, N_ENTITIES, N_EDGES);
    scan_l1<<<nb_u, 256, 0, stream>>>(cnt_u, off_u, part_u, N_USERS);
    scan_l2<<<1, 256, 0, stream>>>(part_u, nb_u);
    scan_l3<<<(N_USERS + 255) / 256, 256, 0, stream>>>(off_u, part_u, N_USERS, NNZ);
    scan_l1<<<nb_i, 256, 0, stream>>>(cnt_i, off_i, part_i, N_ITEMS);
    scan_l2<<<1, 256, 0, stream>>>(part_i, nb_i);
    scan_l3<<<(N_ITEMS + 255) / 256, 256, 0, stream>>>(off_i, part_i, N_ITEMS, NNZ);

    init_bcur<<<1, 256, 0, stream>>>(off_e, off_u, off_i, bcur_e, bcur_u, bcur_i);

    const int np1_e = (N_EDGES + TILE1 - 1) / TILE1;
    const int np1_n = (NNZ + TILE1 - 1) / TILE1;
    phase1_edges<<<np1_e, 256, 0, stream>>>(edge_head, edge_tail, etype, bcur_e, keys_e, kg_pack);
    phase1_inter<<<np1_n, 256, 0, stream>>>(irows, icols, vals, bcur_u, keys_u, u_pack, 9);
    phase1_inter<<<np1_n, 256, 0, stream>>>(icols, irows, vals, bcur_i, keys_i, i_pack, 8);

    phase2_edges<<<NBUCK, 256, 0, stream>>>(off_e, keys_e, kg_pack);
    phase2_inter<<<NBUCK, 256, 0, stream>>>(off_u, keys_u, u_pack, 9, N_USERS);
    phase2_inter<<<NBUCK, 256, 0, stream>>>(off_i, keys_i, i_pack, 8, N_ITEMS);

    // ---------------- hops ----------------
    half8_t* ent_cur = ent_a; half8_t* ent_nxt = ent_b;
    half8_t* cf_cur  = cf_a;  half8_t* cf_nxt  = cf_b;

    for (int hop = 0; hop < HOPS; ++hop) {
        int first = (hop == 0) ? 1 : 0;
        int last = (hop == HOPS - 1) ? 1 : 0;
        kg_agg<<<N_ENTITIES / 32, 256, 0, stream>>>(off_e, kg_pack, relw, ent_cur, ent_nxt,
                                                    ent_res, (const float4*)ent0, first, last);
        user_agg<<<N_USERS / 32, 256, 0, stream>>>(off_u, u_pack, ent_cur, cf_cur, usr_res,
                                                   (const float4*)all_embed, ucf, first, last);
        item_agg<<<(N_ITEMS + 31) / 32, 256, 0, stream>>>(off_i, i_pack, ucf, cf_nxt, cf_res,
                                                          (const float4*)item_cf0, first, last);
        half8_t* tmp = ent_cur; ent_cur = ent_nxt; ent_nxt = tmp;
        tmp = cf_cur; cf_cur = cf_nxt; cf_nxt = tmp;
    }

    loss1_kernel<<<BATCH / 4, 256, 0, stream>>>(user, pos_item, neg_item, (const half4_t*)usr_res,
                                                (const half4_t*)ent_res, (const half4_t*)cf_res, l1p);
    angle_kernel<<<ANGLE_BLOCKS, 256, 0, stream>>>((const float4*)ent0, th, tt, l2blk);
    finalize_kernel<<<1, 1024, 0, stream>>>(l1p, l2blk, out);
}

// Round 7
// 552.909 us; speedup vs baseline: 4.4069x; 1.1306x over previous
//
#include <hip/hip_runtime.h>
#include <math.h>

#define N_USERS    100000
#define N_ITEMS    50000
#define N_ENTITIES 200000
#define N_REL      20
#define EMB        64
#define HOPS       2
#define MARGIN_CCL 0.8f
#define NUM_NEG    64
#define ANGLE_W    0.1f
#define ANGLE_DROP 0.5f
#define N_EDGES    1000000
#define NNZ        1000000
#define N_TRIPLETS 200000
#define BATCH      4096
#define EPSF       1e-6f

#define ANGLE_BLOCKS (N_TRIPLETS / 16)   // 12500
#define TILE1 4096
#define NBUCK 196
#define BCAP  9216
#define HBLK  ((N_EDGES + TILE1 - 1) / TILE1)   // 245 tiles for 1M items

typedef _Float16 half4_t __attribute__((ext_vector_type(4)));
typedef _Float16 half8_t __attribute__((ext_vector_type(8)));
typedef float float8_t __attribute__((ext_vector_type(8)));

__device__ inline float4 h2f(half4_t h) {
    return make_float4((float)h.x, (float)h.y, (float)h.z, (float)h.w);
}
__device__ inline half4_t f2h(float4 f) {
    half4_t h; h.x = (_Float16)f.x; h.y = (_Float16)f.y;
    h.z = (_Float16)f.z; h.w = (_Float16)f.w; return h;
}
__device__ inline float8_t h8_to_f8(half8_t h) { return __builtin_convertvector(h, float8_t); }
__device__ inline half8_t f8_to_h8(float8_t f) { return __builtin_convertvector(f, half8_t); }
__device__ inline half8_t h8_zero() {
    half8_t z;
    #pragma unroll
    for (int i = 0; i < 8; ++i) z[i] = (_Float16)0.0f;
    return z;
}
__device__ inline float sum_sq8(float8_t f) {
    float s = 0.f;
    #pragma unroll
    for (int i = 0; i < 8; ++i) s += f[i] * f[i];
    return s;
}
__device__ inline float8_t f8_from2(float4 lo, float4 hi) {
    float8_t f;
    f[0] = lo.x; f[1] = lo.y; f[2] = lo.z; f[3] = lo.w;
    f[4] = hi.x; f[5] = hi.y; f[6] = hi.z; f[7] = hi.w;
    return f;
}
__device__ inline float grp_red8(float v) {
    v += __shfl_xor(v, 1, 64); v += __shfl_xor(v, 2, 64); v += __shfl_xor(v, 4, 64);
    return v;
}
__device__ inline float dot4(float4 a, float4 b) {
    return a.x * b.x + a.y * b.y + a.z * b.z + a.w * b.w;
}
__device__ inline float grp_red16(float v) {
    v += __shfl_xor(v, 1, 64); v += __shfl_xor(v, 2, 64);
    v += __shfl_xor(v, 4, 64); v += __shfl_xor(v, 8, 64);
    return v;
}
__device__ inline float cross_grp_scalar(float v) {
    v += __shfl_xor(v, 16, 64); v += __shfl_xor(v, 32, 64);
    return v;
}

// ------------------------- fp32 -> fp16 table conversion -------------------------
__global__ void f32_to_f16(const float4* __restrict__ in, half4_t* __restrict__ out, int n4) {
    int i = blockIdx.x * blockDim.x + threadIdx.x;
    if (i < n4) out[i] = f2h(in[i]);
}

// ------------------------- bucket histogram (LDS-private, no global atomics) ----------
__global__ void bucket_hist(const int* __restrict__ keys, int n, int shift,
                            int* __restrict__ partials) {
    __shared__ int lh[NBUCK];
    int t = threadIdx.x;
    if (t < NBUCK) lh[t] = 0;
    __syncthreads();
    int s = blockIdx.x * TILE1;
    int e = min(s + TILE1, n);
    for (int i = s + t; i < e; i += 256) atomicAdd(&lh[keys[i] >> shift], 1);
    __syncthreads();
    if (t < NBUCK) partials[blockIdx.x * NBUCK + t] = lh[t];
}

// single block, 1024 threads: column-sum partials, exclusive-scan 196 bins
__global__ void bucket_scan(const int* __restrict__ partials, int nblk, int total,
                            int* __restrict__ boff, int* __restrict__ bcur) {
    __shared__ int a[4][256];
    __shared__ int s[256];
    int t = threadIdx.x & 255;
    int c = threadIdx.x >> 8;
    int v = 0;
    if (t < NBUCK)
        for (int j = c; j < nblk; j += 4) v += partials[j * NBUCK + t];
    a[c][t] = v;
    __syncthreads();
    int tot = a[0][t] + a[1][t] + a[2][t] + a[3][t];
    if (c == 0) s[t] = tot;
    __syncthreads();
    for (int d = 1; d < 256; d <<= 1) {
        int x = 0;
        if (c == 0 && t >= d) x = s[t - d];
        __syncthreads();
        if (c == 0) s[t] += x;
        __syncthreads();
    }
    if (c == 0 && t < NBUCK) {
        int excl = s[t] - tot;
        boff[t] = excl;
        bcur[t] = excl;
    }
    if (threadIdx.x == 0) boff[NBUCK] = total;
}

// ------------------------- phase 1: LDS-binned placement -------------------------
__global__ void phase1_edges(const int* __restrict__ head, const int* __restrict__ tail,
                             const int* __restrict__ etype, int* __restrict__ bcur,
                             int* __restrict__ keys, int* __restrict__ pay) {
    __shared__ int lhist[256], lstart[256], lcur[256], gbase[256];
    __shared__ int key_st[TILE1];
    __shared__ int pay_st[TILE1];
    int t = threadIdx.x;
    int tstart = blockIdx.x * TILE1;
    int valid = min(TILE1, N_EDGES - tstart);
    lhist[t] = 0;
    __syncthreads();
    for (int i = t; i < valid; i += 256) atomicAdd(&lhist[head[tstart + i] >> 10], 1);
    __syncthreads();
    int v = lhist[t];
    lstart[t] = v;
    __syncthreads();
    for (int d = 1; d < 256; d <<= 1) {
        int x = (t >= d) ? lstart[t - d] : 0;
        __syncthreads();
        lstart[t] += x;
        __syncthreads();
    }
    int excl = lstart[t] - v;
    lstart[t] = excl;
    lcur[t] = excl;
    gbase[t] = atomicAdd(&bcur[t], v);
    __syncthreads();
    for (int i = t; i < valid; i += 256) {
        int h = head[tstart + i];
        int p = tail[tstart + i] | ((etype[tstart + i] - 1) << 18);
        int sp = atomicAdd(&lcur[h >> 10], 1);
        key_st[sp] = h;
        pay_st[sp] = p;
    }
    __syncthreads();
    for (int j = t; j < valid; j += 256) {
        int k = key_st[j];
        int b = k >> 10;
        int pos = gbase[b] + (j - lstart[b]);
        keys[pos] = k;
        pay[pos] = pay_st[j];
    }
}

__global__ void phase1_inter(const int* __restrict__ key_arr, const int* __restrict__ other,
                             const float* __restrict__ vals, int* __restrict__ bcur,
                             int* __restrict__ keys, int2* __restrict__ pay, int shift) {
    __shared__ int lhist[256], lstart[256], lcur[256], gbase[256];
    __shared__ int key_st[TILE1];
    __shared__ int2 pay_st[TILE1];
    int t = threadIdx.x;
    int tstart = blockIdx.x * TILE1;
    int valid = min(TILE1, NNZ - tstart);
    lhist[t] = 0;
    __syncthreads();
    for (int i = t; i < valid; i += 256) atomicAdd(&lhist[key_arr[tstart + i] >> shift], 1);
    __syncthreads();
    int v = lhist[t];
    lstart[t] = v;
    __syncthreads();
    for (int d = 1; d < 256; d <<= 1) {
        int x = (t >= d) ? lstart[t - d] : 0;
        __syncthreads();
        lstart[t] += x;
        __syncthreads();
    }
    int excl = lstart[t] - v;
    lstart[t] = excl;
    lcur[t] = excl;
    gbase[t] = atomicAdd(&bcur[t], v);
    __syncthreads();
    for (int i = t; i < valid; i += 256) {
        int k = key_arr[tstart + i];
        int2 p = make_int2(other[tstart + i], __float_as_int(vals[tstart + i]));
        int sp = atomicAdd(&lcur[k >> shift], 1);
        key_st[sp] = k;
        pay_st[sp] = p;
    }
    __syncthreads();
    for (int j = t; j < valid; j += 256) {
        int k = key_st[j];
        int b = k >> shift;
        int pos = gbase[b] + (j - lstart[b]);
        keys[pos] = k;
        pay[pos] = pay_st[j];
    }
}

// --------- phase 2: row-level hist+scan in LDS, write off[], order payload ----------
__global__ void phase2_edges(const int* __restrict__ boff, const int* __restrict__ keys,
                             int* __restrict__ pay, int* __restrict__ off) {
    __shared__ int hist[1024];
    __shared__ int s[256];
    __shared__ int lout[BCAP];
    int b = blockIdx.x, t = threadIdx.x;
    int rs = b << 10;
    int re = min(rs + 1024, N_ENTITIES);
    int nr = re - rs;
    int base = boff[b];
    int len = boff[b + 1] - base;
    #pragma unroll
    for (int r = t; r < 1024; r += 256) hist[r] = 0;
    __syncthreads();
    for (int j = t; j < len; j += 256) atomicAdd(&hist[keys[base + j] - rs], 1);
    __syncthreads();
    int c0 = hist[4 * t], c1 = hist[4 * t + 1], c2 = hist[4 * t + 2], c3 = hist[4 * t + 3];
    int tot = c0 + c1 + c2 + c3;
    s[t] = tot;
    __syncthreads();
    for (int d = 1; d < 256; d <<= 1) {
        int x = (t >= d) ? s[t - d] : 0;
        __syncthreads();
        s[t] += x;
        __syncthreads();
    }
    int excl = s[t] - tot;
    hist[4 * t]     = excl;
    hist[4 * t + 1] = excl + c0;
    hist[4 * t + 2] = excl + c0 + c1;
    hist[4 * t + 3] = excl + c0 + c1 + c2;
    __syncthreads();
    for (int r = t; r < nr; r += 256) off[rs + r] = base + hist[r];
    if (b == NBUCK - 1 && t == 0) off[N_ENTITIES] = N_EDGES;
    __syncthreads();
    for (int j = t; j < len; j += 256) {
        int k = keys[base + j];
        int slot = atomicAdd(&hist[k - rs], 1);
        lout[slot] = pay[base + j];
    }
    __syncthreads();
    for (int j = t; j < len; j += 256) pay[base + j] = lout[j];
}

__global__ void phase2_inter(const int* __restrict__ boff, const int* __restrict__ keys,
                             int2* __restrict__ pay, int* __restrict__ off,
                             int shift, int n_rows, int total) {
    __shared__ int hist[512];
    __shared__ int s[256];
    __shared__ int2 lout[BCAP];
    int b = blockIdx.x, t = threadIdx.x;
    int bins = 1 << shift;      // 512 (users) or 256 (items)
    int own = bins >> 8;        // 2 or 1
    int rs = b << shift;
    int re = min(rs + bins, n_rows);
    int nr = re - rs;
    int base = boff[b];
    int len = boff[b + 1] - base;
    for (int r = t; r < bins; r += 256) hist[r] = 0;
    __syncthreads();
    for (int j = t; j < len; j += 256) atomicAdd(&hist[keys[base + j] - rs], 1);
    __syncthreads();
    int c[2]; int tot = 0;
    for (int i = 0; i < own; ++i) { c[i] = hist[t * own + i]; tot += c[i]; }
    s[t] = tot;
    __syncthreads();
    for (int d = 1; d < 256; d <<= 1) {
        int x = (t >= d) ? s[t - d] : 0;
        __syncthreads();
        s[t] += x;
        __syncthreads();
    }
    int run = s[t] - tot;
    for (int i = 0; i < own; ++i) { hist[t * own + i] = run; run += c[i]; }
    __syncthreads();
    for (int r = t; r < nr; r += 256) off[rs + r] = base + hist[r];
    if (b == NBUCK - 1 && t == 0) off[n_rows] = total;
    __syncthreads();
    for (int j = t; j < len; j += 256) {
        int k = keys[base + j];
        int slot = atomicAdd(&hist[k - rs], 1);
        lout[slot] = pay[base + j];
    }
    __syncthreads();
    for (int j = t; j < len; j += 256) pay[base + j] = lout[j];
}

// ------------------------- hop kernels: group-per-row, 8 lanes x half8 -------------
__global__ void kg_agg(const int* __restrict__ off, const int* __restrict__ pack,
                       const float* __restrict__ relw, const half8_t* __restrict__ src,
                       half8_t* __restrict__ dst, half8_t* __restrict__ res,
                       const float4* __restrict__ res_init, int first, int last) {
    __shared__ half8_t srel[(N_REL - 1) * 9];
    int t = threadIdx.x;
    if (t < (N_REL - 1) * 8) {
        int rel = t >> 3, o = t & 7;
        const float4* r4 = (const float4*)relw;
        srel[rel * 9 + o] = f8_to_h8(f8_from2(r4[rel * 16 + o * 2], r4[rel * 16 + o * 2 + 1]));
    }
    __syncthreads();
    int row = blockIdx.x * 32 + (t >> 3);
    int o = t & 7;
    int s = off[row], e = off[row + 1];
    half8_t acc = h8_zero();
    int k = s;
    for (; k + 2 <= e; k += 2) {
        int p0 = pack[k], p1 = pack[k + 1];
        half8_t a0 = src[(p0 & 0x3FFFF) * 8 + o];
        half8_t b0 = srel[(p0 >> 18) * 9 + o];
        half8_t a1 = src[(p1 & 0x3FFFF) * 8 + o];
        half8_t b1 = srel[(p1 >> 18) * 9 + o];
        acc += a0 * b0;
        acc += a1 * b1;
    }
    if (k < e) {
        int p0 = pack[k];
        acc += src[(p0 & 0x3FFFF) * 8 + o] * srel[(p0 >> 18) * 9 + o];
    }
    float8_t f = h8_to_f8(acc);
    float inv = 1.0f / fmaxf((float)(e - s), 1.0f);
    f *= inv;
    float ss = grp_red8(sum_sq8(f));
    float rn = 1.0f / fmaxf(sqrtf(ss), 1e-12f);
    f *= rn;
    dst[row * 8 + o] = f8_to_h8(f);
    if (row < N_ITEMS) {
        float8_t rr;
        if (first) rr = f8_from2(res_init[row * 16 + o * 2], res_init[row * 16 + o * 2 + 1]);
        else       rr = h8_to_f8(res[row * 8 + o]);
        rr += f;
        if (last) {
            float s2 = grp_red8(sum_sq8(rr));
            rr *= 1.0f / fmaxf(sqrtf(s2), 1e-12f);
        }
        res[row * 8 + o] = f8_to_h8(rr);
    }
}

__global__ void user_agg(const int* __restrict__ off, const int2* __restrict__ u_pack,
                         const half8_t* __restrict__ ent_cur, const half8_t* __restrict__ cf_cur,
                         half8_t* __restrict__ usr_res, const float4* __restrict__ res_init,
                         half8_t* __restrict__ ucf, int first, int last) {
    int t = threadIdx.x;
    int row = blockIdx.x * 32 + (t >> 3);
    int o = t & 7;
    int s = off[row], e = off[row + 1];
    half8_t au = h8_zero();
    half8_t ac = h8_zero();
    int k = s;
    for (; k + 2 <= e; k += 2) {
        int2 p0 = u_pack[k], p1 = u_pack[k + 1];
        _Float16 v0 = (_Float16)__int_as_float(p0.y);
        _Float16 v1 = (_Float16)__int_as_float(p1.y);
        au += ent_cur[p0.x * 8 + o] * v0;
        ac += cf_cur[p0.x * 8 + o] * v0;
        au += ent_cur[p1.x * 8 + o] * v1;
        ac += cf_cur[p1.x * 8 + o] * v1;
    }
    if (k < e) {
        int2 p0 = u_pack[k];
        _Float16 v0 = (_Float16)__int_as_float(p0.y);
        au += ent_cur[p0.x * 8 + o] * v0;
        ac += cf_cur[p0.x * 8 + o] * v0;
    }
    float8_t f = h8_to_f8(au);
    float ss = grp_red8(sum_sq8(f));
    float rn = 1.0f / fmaxf(sqrtf(ss), 1e-12f);
    float8_t rr;
    if (first) rr = f8_from2(res_init[row * 16 + o * 2], res_init[row * 16 + o * 2 + 1]);
    else       rr = h8_to_f8(usr_res[row * 8 + o]);
    rr += f * rn;
    if (last) {
        float s2 = grp_red8(sum_sq8(rr));
        rr *= 1.0f / fmaxf(sqrtf(s2), 1e-12f);
    }
    usr_res[row * 8 + o] = f8_to_h8(rr);
    ucf[row * 8 + o] = ac;
}

__global__ void item_agg(const int* __restrict__ off, const int2* __restrict__ i_pack,
                         const half8_t* __restrict__ ucf, half8_t* __restrict__ dst,
                         half8_t* __restrict__ res, const float4* __restrict__ res_init,
                         int first, int last) {
    int t = threadIdx.x;
    int row = blockIdx.x * 32 + (t >> 3);
    int o = t & 7;
    if (row >= N_ITEMS) return;
    int s = off[row], e = off[row + 1];
    half8_t acc = h8_zero();
    int k = s;
    for (; k + 2 <= e; k += 2) {
        int2 p0 = i_pack[k], p1 = i_pack[k + 1];
        _Float16 v0 = (_Float16)__int_as_float(p0.y);
        _Float16 v1 = (_Float16)__int_as_float(p1.y);
        acc += ucf[p0.x * 8 + o] * v0;
        acc += ucf[p1.x * 8 + o] * v1;
    }
    if (k < e) {
        int2 p0 = i_pack[k];
        acc += ucf[p0.x * 8 + o] * (_Float16)__int_as_float(p0.y);
    }
    float8_t f = h8_to_f8(acc);
    float ss = grp_red8(sum_sq8(f));
    float rn = 1.0f / fmaxf(sqrtf(ss), 1e-12f);
    f *= rn;
    dst[row * 8 + o] = f8_to_h8(f);
    float8_t rr;
    if (first) rr = f8_from2(res_init[row * 16 + o * 2], res_init[row * 16 + o * 2 + 1]);
    else       rr = h8_to_f8(res[row * 8 + o]);
    rr += f;
    if (last) {
        float s2 = grp_red8(sum_sq8(rr));
        rr *= 1.0f / fmaxf(sqrtf(s2), 1e-12f);
    }
    res[row * 8 + o] = f8_to_h8(rr);
}

// ------------------------- losses -------------------------
__global__ void loss1_kernel(const int* __restrict__ user, const int* __restrict__ pos,
                             const int* __restrict__ neg, const half4_t* __restrict__ usr_res,
                             const half4_t* __restrict__ ent_res, const half4_t* __restrict__ cf_res,
                             float* __restrict__ l1p) {
    int b = blockIdx.x * 4 + (threadIdx.x >> 6);
    int lane = threadIdx.x & 63;
    int g = lane >> 4, q = lane & 15;
    int uid = user[b], pid = pos[b];
    float4 u = h2f(usr_res[uid * 16 + q]);
    float4 p = h2f(ent_res[pid * 16 + q]);
    float4 pc = h2f(cf_res[pid * 16 + q]);
    float dp = grp_red16(dot4(u, p) + dot4(u, pc));
    float ui_pos = fmaxf(2.0f - dp, 0.0f);
    float sum_n = 0.f, cnt_n = 0.f, sum_c = 0.f, cnt_c = 0.f;
    const int* nb = neg + b * NUM_NEG;
    for (int j = 0; j < NUM_NEG; j += 8) {
        int n0 = nb[j + g], n1 = nb[j + 4 + g];
        float4 e0 = h2f(ent_res[n0 * 16 + q]), c0 = h2f(cf_res[n0 * 16 + q]);
        float4 e1 = h2f(ent_res[n1 * 16 + q]), c1 = h2f(cf_res[n1 * 16 + q]);
        float dn0 = grp_red16(dot4(u, e0));
        float dc0 = grp_red16(dot4(u, c0));
        float dn1 = grp_red16(dot4(u, e1));
        float dc1 = grp_red16(dot4(u, c1));
        float s0 = fmaxf(dn0 - MARGIN_CCL, 0.f); sum_n += s0; if (s0 > 0.f) cnt_n += 1.f;
        float s1 = fmaxf(dn1 - MARGIN_CCL, 0.f); sum_n += s1; if (s1 > 0.f) cnt_n += 1.f;
        float t0 = fmaxf(dc0 - MARGIN_CCL, 0.f); sum_c += t0; if (t0 > 0.f) cnt_c += 1.f;
        float t1 = fmaxf(dc1 - MARGIN_CCL, 0.f); sum_c += t1; if (t1 > 0.f) cnt_c += 1.f;
    }
    sum_n = cross_grp_scalar(sum_n); cnt_n = cross_grp_scalar(cnt_n);
    sum_c = cross_grp_scalar(sum_c); cnt_c = cross_grp_scalar(cnt_c);
    if (lane == 0)
        l1p[b] = ui_pos + sum_n / (cnt_n + 1e-5f) + sum_c / (cnt_c + 1e-5f);
}

__global__ void angle_kernel(const float4* __restrict__ ent0,
                             const int* __restrict__ th, const int* __restrict__ tt,
                             float* __restrict__ l2blk) {
    int lane = threadIdx.x & 63;
    int g = lane >> 4, q = lane & 15;
    int trip = blockIdx.x * 16 + (threadIdx.x >> 6) * 4 + g;
    int h = th[trip], t = tt[trip];
    float4 hv = ent0[h * 16 + q];
    float4 tv = ent0[t * 16 + q];
    hv.x *= ANGLE_DROP; hv.y *= ANGLE_DROP; hv.z *= ANGLE_DROP; hv.w *= ANGLE_DROP;
    tv.x *= ANGLE_DROP; tv.y *= ANGLE_DROP; tv.z *= ANGLE_DROP; tv.w *= ANGLE_DROP;
    float4 dv = make_float4(hv.x - tv.x, hv.y - tv.y, hv.z - tv.z, hv.w - tv.w);
    float s_hh = grp_red16(dot4(hv, hv));
    float s_tt = grp_red16(dot4(tv, tv));
    float s_ht = grp_red16(dot4(hv, tv));
    float s_dd = grp_red16(dot4(dv, dv));
    __shared__ float sb[16];
    if (q == 0) {
        float nu = sqrtf(s_hh);
        float ed = sqrtf(s_dd);
        float sqnu = fminf(fmaxf(s_hh, 0.0f), 1.0f - EPSF);
        float ha_arg = fminf(fmaxf(0.1f * (1.0f - sqnu) / sqrtf(sqnu), -1.0f + EPSF), 1.0f - EPSF);
        float half_ap = asinf(ha_arg);
        float num = s_ht * (1.0f + s_hh) - s_hh * (1.0f + s_tt);
        float den = nu * ed * sqrtf(fmaxf(1.0f + s_tt * s_hh - 2.0f * s_ht, EPSF)) + EPSF;
        float ang = acosf(fminf(fmaxf(num / den, -1.0f + EPSF), 1.0f - EPSF));
        sb[threadIdx.x >> 4] = fmaxf(ang - half_ap, 0.0f);
    }
    __syncthreads();
    if (threadIdx.x == 0) {
        float tot = 0.f;
        #pragma unroll
        for (int i = 0; i < 16; ++i) tot += sb[i];
        l2blk[blockIdx.x] = tot;
    }
}

__global__ void finalize_kernel(const float* __restrict__ l1p, const float* __restrict__ l2b,
                                float* __restrict__ out) {
    __shared__ float sb[1024];
    float a1 = 0.f;
    for (int i = threadIdx.x; i < BATCH; i += 1024) a1 += l1p[i];
    float a2 = 0.f;
    for (int i = threadIdx.x; i < ANGLE_BLOCKS; i += 1024) a2 += l2b[i];
    sb[threadIdx.x] = a1 / (float)BATCH + ANGLE_W * a2 / (float)N_TRIPLETS;
    __syncthreads();
    for (int s = 512; s > 0; s >>= 1) {
        if (threadIdx.x < s) sb[threadIdx.x] += sb[threadIdx.x + s];
        __syncthreads();
    }
    if (threadIdx.x == 0) out[0] = sb[0];
}

extern "C" void kernel_launch(void* const* d_in, const int* in_sizes, int n_in,
                              void* d_out, int out_size, void* d_ws, size_t ws_size,
                              hipStream_t stream) {
    const float* all_embed = (const float*)d_in[0];
    const float* item_cf0  = (const float*)d_in[1];
    const float* relw      = (const float*)d_in[2];
    const float* vals      = (const float*)d_in[3];
    const int* user        = (const int*)d_in[4];
    const int* pos_item    = (const int*)d_in[5];
    const int* neg_item    = (const int*)d_in[6];
    const int* edge_head   = (const int*)d_in[7];
    const int* edge_tail   = edge_head + N_EDGES;
    const int* etype       = (const int*)d_in[8];
    const int* irows       = (const int*)d_in[9];
    const int* icols       = (const int*)d_in[10];
    const int* th          = (const int*)d_in[11];
    const int* tt          = (const int*)d_in[12];
    float* out             = (float*)d_out;

    // ---------------- workspace layout (256 B aligned chunks) ----------------
    char* base = (char*)d_ws;
    size_t woff = 0;
    auto alloc = [&](size_t bytes) -> void* {
        void* p = base + woff;
        woff = (woff + bytes + 255) & ~(size_t)255;
        return p;
    };
    half8_t* ent_a   = (half8_t*)alloc((size_t)N_ENTITIES * EMB * 2);
    half8_t* ent_b   = (half8_t*)alloc((size_t)N_ENTITIES * EMB * 2);
    half8_t* cf_a    = (half8_t*)alloc((size_t)N_ITEMS * EMB * 2);
    half8_t* cf_b    = (half8_t*)alloc((size_t)N_ITEMS * EMB * 2);
    half8_t* ucf     = (half8_t*)alloc((size_t)N_USERS * EMB * 2);
    half8_t* ent_res = (half8_t*)alloc((size_t)N_ITEMS * EMB * 2);
    half8_t* usr_res = (half8_t*)alloc((size_t)N_USERS * EMB * 2);
    half8_t* cf_res  = (half8_t*)alloc((size_t)N_ITEMS * EMB * 2);
    int2* u_pack     = (int2*)alloc((size_t)NNZ * 8);
    int2* i_pack     = (int2*)alloc((size_t)NNZ * 8);
    int* kg_pack     = (int*)alloc((size_t)N_EDGES * 4);
    int* keys_e      = (int*)alloc((size_t)N_EDGES * 4);
    int* keys_u      = (int*)alloc((size_t)NNZ * 4);
    int* keys_i      = (int*)alloc((size_t)NNZ * 4);
    float* l1p       = (float*)alloc((size_t)BATCH * 4);
    float* l2blk     = (float*)alloc((size_t)ANGLE_BLOCKS * 4);
    int* off_e       = (int*)alloc((size_t)(N_ENTITIES + 1) * 4);
    int* off_u       = (int*)alloc((size_t)(N_USERS + 1) * 4);
    int* off_i       = (int*)alloc((size_t)(N_ITEMS + 1) * 4);
    int* boff_e      = (int*)alloc((NBUCK + 1) * 4);
    int* boff_u      = (int*)alloc((NBUCK + 1) * 4);
    int* boff_i      = (int*)alloc((NBUCK + 1) * 4);
    int* bcur_e      = (int*)alloc(256 * 4);
    int* bcur_u      = (int*)alloc(256 * 4);
    int* bcur_i      = (int*)alloc(256 * 4);
    int* ph_e        = (int*)alloc((size_t)HBLK * NBUCK * 4);
    int* ph_u        = (int*)alloc((size_t)HBLK * NBUCK * 4);
    int* ph_i        = (int*)alloc((size_t)HBLK * NBUCK * 4);

    const float* ent0 = all_embed + (size_t)N_USERS * EMB;

    // ---------------- fp16 conversions of hop-0 tables ----------------
    f32_to_f16<<<(N_ENTITIES * 16 + 255) / 256, 256, 0, stream>>>((const float4*)ent0,
                                                                  (half4_t*)ent_a, N_ENTITIES * 16);
    f32_to_f16<<<(N_ITEMS * 16 + 255) / 256, 256, 0, stream>>>((const float4*)item_cf0,
                                                               (half4_t*)cf_a, N_ITEMS * 16);

    // ---------------- bucket histograms (no global atomics) ----------------
    bucket_hist<<<HBLK, 256, 0, stream>>>(edge_head, N_EDGES, 10, ph_e);
    bucket_hist<<<HBLK, 256, 0, stream>>>(irows, NNZ, 9, ph_u);
    bucket_hist<<<HBLK, 256, 0, stream>>>(icols, NNZ, 8, ph_i);
    bucket_scan<<<1, 1024, 0, stream>>>(ph_e, HBLK, N_EDGES, boff_e, bcur_e);
    bucket_scan<<<1, 1024, 0, stream>>>(ph_u, HBLK, NNZ, boff_u, bcur_u);
    bucket_scan<<<1, 1024, 0, stream>>>(ph_i, HBLK, NNZ, boff_i, bcur_i);

    // ---------------- phase 1: bucket-grouped placement ----------------
    phase1_edges<<<HBLK, 256, 0, stream>>>(edge_head, edge_tail, etype, bcur_e, keys_e, kg_pack);
    phase1_inter<<<HBLK, 256, 0, stream>>>(irows, icols, vals, bcur_u, keys_u, u_pack, 9);
    phase1_inter<<<HBLK, 256, 0, stream>>>(icols, irows, vals, bcur_i, keys_i, i_pack, 8);

    // ---------------- phase 2: row offsets + in-bucket ordering ----------------
    phase2_edges<<<NBUCK, 256, 0, stream>>>(boff_e, keys_e, kg_pack, off_e);
    phase2_inter<<<NBUCK, 256, 0, stream>>>(boff_u, keys_u, u_pack, off_u, 9, N_USERS, NNZ);
    phase2_inter<<<NBUCK, 256, 0, stream>>>(boff_i, keys_i, i_pack, off_i, 8, N_ITEMS, NNZ);

    // ---------------- hops ----------------
    half8_t* ent_cur = ent_a; half8_t* ent_nxt = ent_b;
    half8_t* cf_cur  = cf_a;  half8_t* cf_nxt  = cf_b;

    for (int hop = 0; hop < HOPS; ++hop) {
        int first = (hop == 0) ? 1 : 0;
        int last = (hop == HOPS - 1) ? 1 : 0;
        kg_agg<<<N_ENTITIES / 32, 256, 0, stream>>>(off_e, kg_pack, relw, ent_cur, ent_nxt,
                                                    ent_res, (const float4*)ent0, first, last);
        user_agg<<<N_USERS / 32, 256, 0, stream>>>(off_u, u_pack, ent_cur, cf_cur, usr_res,
                                                   (const float4*)all_embed, ucf, first, last);
        item_agg<<<(N_ITEMS + 31) / 32, 256, 0, stream>>>(off_i, i_pack, ucf, cf_nxt, cf_res,
                                                          (const float4*)item_cf0, first, last);
        half8_t* tmp = ent_cur; ent_cur = ent_nxt; ent_nxt = tmp;
        tmp = cf_cur; cf_cur = cf_nxt; cf_nxt = tmp;
    }

    loss1_kernel<<<BATCH / 4, 256, 0, stream>>>(user, pos_item, neg_item, (const half4_t*)usr_res,
                                                (const half4_t*)ent_res, (const half4_t*)cf_res, l1p);
    angle_kernel<<<ANGLE_BLOCKS, 256, 0, stream>>>((const float4*)ent0, th, tt, l2blk);
    finalize_kernel<<<1, 1024, 0, stream>>>(l1p, l2blk, out);
}

// Round 8
// 442.087 us; speedup vs baseline: 5.5116x; 1.2507x over previous
//
#include <hip/hip_runtime.h>
#include <math.h>

#define N_USERS    100000
#define N_ITEMS    50000
#define N_ENTITIES 200000
#define N_REL      20
#define EMB        64
#define HOPS       2
#define MARGIN_CCL 0.8f
#define NUM_NEG    64
#define ANGLE_W    0.1f
#define ANGLE_DROP 0.5f
#define N_EDGES    1000000
#define NNZ        1000000
#define N_TRIPLETS 200000
#define BATCH      4096
#define EPSF       1e-6f

#define ANGLE_BLOCKS (N_TRIPLETS / 16)      // 12500
#define TILE1 4096
#define NBUCK 196
#define BCAP  9216
#define HBLK  ((N_EDGES + TILE1 - 1) / TILE1)  // 245
#define KGB   (N_ENTITIES / 32)             // 6250
#define USERB (N_USERS / 32)                // 3125
#define ITEMB ((N_ITEMS + 31) / 32)         // 1563
#define CONVE (N_ENTITIES * 16 / 256)       // 12500
#define CONVI (N_ITEMS * 16 / 256)          // 3125

typedef _Float16 half4_t __attribute__((ext_vector_type(4)));
typedef _Float16 half8_t __attribute__((ext_vector_type(8)));
typedef float float8_t __attribute__((ext_vector_type(8)));

__device__ inline float4 h2f(half4_t h) {
    return make_float4((float)h.x, (float)h.y, (float)h.z, (float)h.w);
}
__device__ inline half4_t f2h(float4 f) {
    half4_t h; h.x = (_Float16)f.x; h.y = (_Float16)f.y;
    h.z = (_Float16)f.z; h.w = (_Float16)f.w; return h;
}
__device__ inline float8_t h8_to_f8(half8_t h) { return __builtin_convertvector(h, float8_t); }
__device__ inline half8_t f8_to_h8(float8_t f) { return __builtin_convertvector(f, half8_t); }
__device__ inline half8_t h8_zero() {
    half8_t z;
    #pragma unroll
    for (int i = 0; i < 8; ++i) z[i] = (_Float16)0.0f;
    return z;
}
__device__ inline float sum_sq8(float8_t f) {
    float s = 0.f;
    #pragma unroll
    for (int i = 0; i < 8; ++i) s += f[i] * f[i];
    return s;
}
__device__ inline float8_t f8_from2(float4 lo, float4 hi) {
    float8_t f;
    f[0] = lo.x; f[1] = lo.y; f[2] = lo.z; f[3] = lo.w;
    f[4] = hi.x; f[5] = hi.y; f[6] = hi.z; f[7] = hi.w;
    return f;
}
__device__ inline float grp_red8(float v) {
    v += __shfl_xor(v, 1, 64); v += __shfl_xor(v, 2, 64); v += __shfl_xor(v, 4, 64);
    return v;
}
__device__ inline float dot4(float4 a, float4 b) {
    return a.x * b.x + a.y * b.y + a.z * b.z + a.w * b.w;
}
__device__ inline float grp_red16(float v) {
    v += __shfl_xor(v, 1, 64); v += __shfl_xor(v, 2, 64);
    v += __shfl_xor(v, 4, 64); v += __shfl_xor(v, 8, 64);
    return v;
}
__device__ inline float cross_grp_scalar(float v) {
    v += __shfl_xor(v, 16, 64); v += __shfl_xor(v, 32, 64);
    return v;
}

// ------------- device bodies for the hop kernels (called from fused launches) ---------
__device__ inline void kg_body(int bid, int t, const int* __restrict__ off,
                               const int* __restrict__ pack, half8_t* srel,
                               const float* __restrict__ relw,
                               const half8_t* __restrict__ src, half8_t* __restrict__ dst,
                               half8_t* __restrict__ res, const float4* __restrict__ res_init,
                               int first, int last) {
    if (t < (N_REL - 1) * 8) {
        int rel = t >> 3, o = t & 7;
        const float4* r4 = (const float4*)relw;
        srel[rel * 9 + o] = f8_to_h8(f8_from2(r4[rel * 16 + o * 2], r4[rel * 16 + o * 2 + 1]));
    }
    __syncthreads();
    int row = bid * 32 + (t >> 3);
    int o = t & 7;
    int s = off[row], e = off[row + 1];
    half8_t acc = h8_zero();
    int k = s;
    for (; k + 2 <= e; k += 2) {
        int p0 = pack[k], p1 = pack[k + 1];
        half8_t a0 = src[(p0 & 0x3FFFF) * 8 + o];
        half8_t b0 = srel[(p0 >> 18) * 9 + o];
        half8_t a1 = src[(p1 & 0x3FFFF) * 8 + o];
        half8_t b1 = srel[(p1 >> 18) * 9 + o];
        acc += a0 * b0;
        acc += a1 * b1;
    }
    if (k < e) {
        int p0 = pack[k];
        acc += src[(p0 & 0x3FFFF) * 8 + o] * srel[(p0 >> 18) * 9 + o];
    }
    float8_t f = h8_to_f8(acc);
    f *= 1.0f / fmaxf((float)(e - s), 1.0f);
    float ss = grp_red8(sum_sq8(f));
    f *= 1.0f / fmaxf(sqrtf(ss), 1e-12f);
    dst[row * 8 + o] = f8_to_h8(f);
    if (row < N_ITEMS) {
        float8_t rr;
        if (first) rr = f8_from2(res_init[row * 16 + o * 2], res_init[row * 16 + o * 2 + 1]);
        else       rr = h8_to_f8(res[row * 8 + o]);
        rr += f;
        if (last) {
            float s2 = grp_red8(sum_sq8(rr));
            rr *= 1.0f / fmaxf(sqrtf(s2), 1e-12f);
        }
        res[row * 8 + o] = f8_to_h8(rr);
    }
}

__device__ inline void user_body(int bid, int t, const int* __restrict__ off,
                                 const int2* __restrict__ u_pack,
                                 const half8_t* __restrict__ ent_cur,
                                 const half8_t* __restrict__ cf_cur,
                                 half8_t* __restrict__ usr_res,
                                 const float4* __restrict__ res_init,
                                 half8_t* __restrict__ ucf, int first, int last) {
    int row = bid * 32 + (t >> 3);
    int o = t & 7;
    int s = off[row], e = off[row + 1];
    half8_t au = h8_zero();
    half8_t ac = h8_zero();
    int k = s;
    for (; k + 2 <= e; k += 2) {
        int2 p0 = u_pack[k], p1 = u_pack[k + 1];
        _Float16 v0 = (_Float16)__int_as_float(p0.y);
        _Float16 v1 = (_Float16)__int_as_float(p1.y);
        au += ent_cur[p0.x * 8 + o] * v0;
        ac += cf_cur[p0.x * 8 + o] * v0;
        au += ent_cur[p1.x * 8 + o] * v1;
        ac += cf_cur[p1.x * 8 + o] * v1;
    }
    if (k < e) {
        int2 p0 = u_pack[k];
        _Float16 v0 = (_Float16)__int_as_float(p0.y);
        au += ent_cur[p0.x * 8 + o] * v0;
        ac += cf_cur[p0.x * 8 + o] * v0;
    }
    float8_t f = h8_to_f8(au);
    float ss = grp_red8(sum_sq8(f));
    float rn = 1.0f / fmaxf(sqrtf(ss), 1e-12f);
    float8_t rr;
    if (first) rr = f8_from2(res_init[row * 16 + o * 2], res_init[row * 16 + o * 2 + 1]);
    else       rr = h8_to_f8(usr_res[row * 8 + o]);
    rr += f * rn;
    if (last) {
        float s2 = grp_red8(sum_sq8(rr));
        rr *= 1.0f / fmaxf(sqrtf(s2), 1e-12f);
    }
    usr_res[row * 8 + o] = f8_to_h8(rr);
    ucf[row * 8 + o] = ac;
}

__device__ inline void item_body(int bid, int t, const int* __restrict__ off,
                                 const int2* __restrict__ i_pack,
                                 const half8_t* __restrict__ ucf, half8_t* __restrict__ dst,
                                 half8_t* __restrict__ res, const float4* __restrict__ res_init,
                                 int first, int last) {
    int row = bid * 32 + (t >> 3);
    int o = t & 7;
    if (row >= N_ITEMS) return;
    int s = off[row], e = off[row + 1];
    half8_t acc = h8_zero();
    int k = s;
    for (; k + 2 <= e; k += 2) {
        int2 p0 = i_pack[k], p1 = i_pack[k + 1];
        _Float16 v0 = (_Float16)__int_as_float(p0.y);
        _Float16 v1 = (_Float16)__int_as_float(p1.y);
        acc += ucf[p0.x * 8 + o] * v0;
        acc += ucf[p1.x * 8 + o] * v1;
    }
    if (k < e) {
        int2 p0 = i_pack[k];
        acc += ucf[p0.x * 8 + o] * (_Float16)__int_as_float(p0.y);
    }
    float8_t f = h8_to_f8(acc);
    float ss = grp_red8(sum_sq8(f));
    f *= 1.0f / fmaxf(sqrtf(ss), 1e-12f);
    dst[row * 8 + o] = f8_to_h8(f);
    float8_t rr;
    if (first) rr = f8_from2(res_init[row * 16 + o * 2], res_init[row * 16 + o * 2 + 1]);
    else       rr = h8_to_f8(res[row * 8 + o]);
    rr += f;
    if (last) {
        float s2 = grp_red8(sum_sq8(rr));
        rr *= 1.0f / fmaxf(sqrtf(s2), 1e-12f);
    }
    res[row * 8 + o] = f8_to_h8(rr);
}

__device__ inline void angle_body(int ablk, int t, const float4* __restrict__ ent0,
                                  const int* __restrict__ th, const int* __restrict__ tt,
                                  float* sb, float* __restrict__ l2blk) {
    int lane = t & 63;
    int g = lane >> 4, q = lane & 15;
    int trip = ablk * 16 + (t >> 6) * 4 + g;
    int h = th[trip], tt_ = tt[trip];
    float4 hv = ent0[h * 16 + q];
    float4 tv = ent0[tt_ * 16 + q];
    hv.x *= ANGLE_DROP; hv.y *= ANGLE_DROP; hv.z *= ANGLE_DROP; hv.w *= ANGLE_DROP;
    tv.x *= ANGLE_DROP; tv.y *= ANGLE_DROP; tv.z *= ANGLE_DROP; tv.w *= ANGLE_DROP;
    float4 dv = make_float4(hv.x - tv.x, hv.y - tv.y, hv.z - tv.z, hv.w - tv.w);
    float s_hh = grp_red16(dot4(hv, hv));
    float s_tt = grp_red16(dot4(tv, tv));
    float s_ht = grp_red16(dot4(hv, tv));
    float s_dd = grp_red16(dot4(dv, dv));
    if (q == 0) {
        float nu = sqrtf(s_hh);
        float ed = sqrtf(s_dd);
        float sqnu = fminf(fmaxf(s_hh, 0.0f), 1.0f - EPSF);
        float ha_arg = fminf(fmaxf(0.1f * (1.0f - sqnu) / sqrtf(sqnu), -1.0f + EPSF), 1.0f - EPSF);
        float half_ap = asinf(ha_arg);
        float num = s_ht * (1.0f + s_hh) - s_hh * (1.0f + s_tt);
        float den = nu * ed * sqrtf(fmaxf(1.0f + s_tt * s_hh - 2.0f * s_ht, EPSF)) + EPSF;
        float ang = acosf(fminf(fmaxf(num / den, -1.0f + EPSF), 1.0f - EPSF));
        sb[t >> 4] = fmaxf(ang - half_ap, 0.0f);
    }
    __syncthreads();
    if (t == 0) {
        float tot = 0.f;
        #pragma unroll
        for (int i = 0; i < 16; ++i) tot += sb[i];
        l2blk[ablk] = tot;
    }
}

// ------------------------- prep: conversions + bucket hists, one launch ---------------
__global__ void __launch_bounds__(256) prep_kernel(
        const float4* __restrict__ ent0, const float4* __restrict__ cf0,
        half4_t* __restrict__ ent_a, half4_t* __restrict__ cf_a,
        const int* __restrict__ head, const int* __restrict__ rows,
        const int* __restrict__ cols,
        int* __restrict__ ph_e, int* __restrict__ ph_u, int* __restrict__ ph_i) {
    __shared__ int lh[NBUCK];
    int bx = blockIdx.x, t = threadIdx.x;
    if (bx < CONVE) { int i = bx * 256 + t; ent_a[i] = f2h(ent0[i]); return; }
    bx -= CONVE;
    if (bx < CONVI) { int i = bx * 256 + t; cf_a[i] = f2h(cf0[i]); return; }
    bx -= CONVI;
    const int* keys; int shift; int* outp;
    if (bx < HBLK)            { keys = head; shift = 10; outp = ph_e; }
    else if (bx < 2 * HBLK)   { bx -= HBLK; keys = rows; shift = 9; outp = ph_u; }
    else                      { bx -= 2 * HBLK; keys = cols; shift = 8; outp = ph_i; }
    if (t < NBUCK) lh[t] = 0;
    __syncthreads();
    int s = bx * TILE1, e = min(s + TILE1, N_EDGES);
    for (int i = s + t; i < e; i += 256) atomicAdd(&lh[keys[i] >> shift], 1);
    __syncthreads();
    if (t < NBUCK) outp[bx * NBUCK + t] = lh[t];
}

// ------------------------- bucket scan: 3 datasets, one launch -------------------------
__global__ void bucket_scan3(const int* __restrict__ ph_e, const int* __restrict__ ph_u,
                             const int* __restrict__ ph_i, int* __restrict__ boff_e,
                             int* __restrict__ boff_u, int* __restrict__ boff_i,
                             int* __restrict__ bcur_e, int* __restrict__ bcur_u,
                             int* __restrict__ bcur_i) {
    const int* partials; int* boff; int* bcur;
    if (blockIdx.x == 0)      { partials = ph_e; boff = boff_e; bcur = bcur_e; }
    else if (blockIdx.x == 1) { partials = ph_u; boff = boff_u; bcur = bcur_u; }
    else                      { partials = ph_i; boff = boff_i; bcur = bcur_i; }
    __shared__ int a[4][256];
    __shared__ int s[256];
    int t = threadIdx.x & 255;
    int c = threadIdx.x >> 8;
    int v = 0;
    if (t < NBUCK)
        for (int j = c; j < HBLK; j += 4) v += partials[j * NBUCK + t];
    a[c][t] = v;
    __syncthreads();
    int tot = a[0][t] + a[1][t] + a[2][t] + a[3][t];
    if (c == 0) s[t] = tot;
    __syncthreads();
    for (int d = 1; d < 256; d <<= 1) {
        int x = 0;
        if (c == 0 && t >= d) x = s[t - d];
        __syncthreads();
        if (c == 0) s[t] += x;
        __syncthreads();
    }
    if (c == 0 && t < NBUCK) {
        int excl = s[t] - tot;
        boff[t] = excl;
        bcur[t] = excl;
    }
    if (threadIdx.x == 0) boff[NBUCK] = N_EDGES;
}

// ------------------------- phase 1: 3 segments, one launch -----------------------------
__global__ void __launch_bounds__(256) phase1_all(
        const int* __restrict__ head, const int* __restrict__ tail,
        const int* __restrict__ etype, const int* __restrict__ rows,
        const int* __restrict__ cols, const float* __restrict__ vals,
        int* __restrict__ bcur_e, int* __restrict__ bcur_u, int* __restrict__ bcur_i,
        int* __restrict__ keys_e, int* __restrict__ kg_pay,
        int* __restrict__ keys_u, int2* __restrict__ u_pay,
        int* __restrict__ keys_i, int2* __restrict__ i_pay) {
    __shared__ int lhist[256], lstart[256], lcur[256], gbase[256];
    __shared__ int key_st[TILE1];
    __shared__ int2 pay_st[TILE1];
    int seg = blockIdx.x / HBLK;
    int tb  = blockIdx.x % HBLK;
    int t = threadIdx.x;
    int tstart = tb * TILE1;
    int valid = min(TILE1, N_EDGES - tstart);
    const int* karr = (seg == 0) ? head : (seg == 1) ? rows : cols;
    int shift = (seg == 0) ? 10 : (seg == 1) ? 9 : 8;
    int* bcur = (seg == 0) ? bcur_e : (seg == 1) ? bcur_u : bcur_i;
    lhist[t] = 0;
    __syncthreads();
    for (int i = t; i < valid; i += 256) atomicAdd(&lhist[karr[tstart + i] >> shift], 1);
    __syncthreads();
    int v = lhist[t];
    lstart[t] = v;
    __syncthreads();
    for (int d = 1; d < 256; d <<= 1) {
        int x = (t >= d) ? lstart[t - d] : 0;
        __syncthreads();
        lstart[t] += x;
        __syncthreads();
    }
    int excl = lstart[t] - v;
    lstart[t] = excl;
    lcur[t] = excl;
    gbase[t] = atomicAdd(&bcur[t], v);
    __syncthreads();
    if (seg == 0) {
        int* ps = (int*)pay_st;
        for (int i = t; i < valid; i += 256) {
            int h = head[tstart + i];
            int p = tail[tstart + i] | ((etype[tstart + i] - 1) << 18);
            int sp = atomicAdd(&lcur[h >> 10], 1);
            key_st[sp] = h;
            ps[sp] = p;
        }
        __syncthreads();
        for (int j = t; j < valid; j += 256) {
            int k = key_st[j];
            int b = k >> 10;
            int pos = gbase[b] + (j - lstart[b]);
            keys_e[pos] = k;
            kg_pay[pos] = ps[j];
        }
    } else {
        const int* oth = (seg == 1) ? cols : rows;
        int* keys = (seg == 1) ? keys_u : keys_i;
        int2* pay = (seg == 1) ? u_pay : i_pay;
        for (int i = t; i < valid; i += 256) {
            int k = karr[tstart + i];
            int2 p = make_int2(oth[tstart + i], __float_as_int(vals[tstart + i]));
            int sp = atomicAdd(&lcur[k >> shift], 1);
            key_st[sp] = k;
            pay_st[sp] = p;
        }
        __syncthreads();
        for (int j = t; j < valid; j += 256) {
            int k = key_st[j];
            int b = k >> shift;
            int pos = gbase[b] + (j - lstart[b]);
            keys[pos] = k;
            pay[pos] = pay_st[j];
        }
    }
}

// ------------------------- phase 2: 3 segments, one launch -----------------------------
__global__ void __launch_bounds__(256) phase2_all(
        const int* __restrict__ boff_e, const int* __restrict__ keys_e,
        int* __restrict__ kg_pay, int* __restrict__ off_e,
        const int* __restrict__ boff_u, const int* __restrict__ keys_u,
        int2* __restrict__ u_pay, int* __restrict__ off_u,
        const int* __restrict__ boff_i, const int* __restrict__ keys_i,
        int2* __restrict__ i_pay, int* __restrict__ off_i) {
    __shared__ int hist[1024];
    __shared__ int s[256];
    __shared__ int2 lout2[BCAP];
    int seg = blockIdx.x / NBUCK;
    int b   = blockIdx.x % NBUCK;
    int t = threadIdx.x;
    int bins  = (seg == 0) ? 1024 : (seg == 1) ? 512 : 256;
    int shift = (seg == 0) ? 10 : (seg == 1) ? 9 : 8;
    int n_rows = (seg == 0) ? N_ENTITIES : (seg == 1) ? N_USERS : N_ITEMS;
    const int* boff = (seg == 0) ? boff_e : (seg == 1) ? boff_u : boff_i;
    const int* keys = (seg == 0) ? keys_e : (seg == 1) ? keys_u : keys_i;
    int* off = (seg == 0) ? off_e : (seg == 1) ? off_u : off_i;
    int rs = b << shift;
    int re = min(rs + bins, n_rows);
    int nr = re - rs;
    int base = boff[b];
    int len = boff[b + 1] - base;
    for (int r = t; r < bins; r += 256) hist[r] = 0;
    __syncthreads();
    for (int j = t; j < len; j += 256) atomicAdd(&hist[keys[base + j] - rs], 1);
    __syncthreads();
    int own = bins >> 8;
    int c[4]; int tot = 0;
    #pragma unroll 4
    for (int i = 0; i < own; ++i) { c[i] = hist[t * own + i]; tot += c[i]; }
    s[t] = tot;
    __syncthreads();
    for (int d = 1; d < 256; d <<= 1) {
        int x = (t >= d) ? s[t - d] : 0;
        __syncthreads();
        s[t] += x;
        __syncthreads();
    }
    int run = s[t] - tot;
    #pragma unroll 4
    for (int i = 0; i < own; ++i) { hist[t * own + i] = run; run += c[i]; }
    __syncthreads();
    for (int r = t; r < nr; r += 256) off[rs + r] = base + hist[r];
    if (b == NBUCK - 1 && t == 0) off[n_rows] = (seg == 0) ? N_EDGES : NNZ;
    __syncthreads();
    if (seg == 0) {
        int* lo = (int*)lout2;
        for (int j = t; j < len; j += 256) {
            int k = keys[base + j];
            int slot = atomicAdd(&hist[k - rs], 1);
            lo[slot] = kg_pay[base + j];
        }
        __syncthreads();
        for (int j = t; j < len; j += 256) kg_pay[base + j] = lo[j];
    } else {
        int2* pay = (seg == 1) ? u_pay : i_pay;
        for (int j = t; j < len; j += 256) {
            int k = keys[base + j];
            int slot = atomicAdd(&hist[k - rs], 1);
            lout2[slot] = pay[base + j];
        }
        __syncthreads();
        for (int j = t; j < len; j += 256) pay[base + j] = lout2[j];
    }
}

// --------------- fused hop launches (independent kernels share one grid) ---------------
// L1: kg hop0 + user hop0 + angle
__global__ void __launch_bounds__(256) fused_h0(
        const int* __restrict__ off_e, const int* __restrict__ kg_pack,
        const float* __restrict__ relw, const half8_t* __restrict__ ent_cur,
        half8_t* __restrict__ ent_nxt, half8_t* __restrict__ ent_res,
        const float4* __restrict__ ent0f,
        const int* __restrict__ off_u, const int2* __restrict__ u_pack,
        const half8_t* __restrict__ cf_cur, half8_t* __restrict__ usr_res,
        const float4* __restrict__ usr0f, half8_t* __restrict__ ucf,
        const int* __restrict__ th, const int* __restrict__ tt,
        float* __restrict__ l2blk) {
    __shared__ half8_t srel[(N_REL - 1) * 9];
    __shared__ float sb[16];
    int bx = blockIdx.x, t = threadIdx.x;
    if (bx < KGB) {
        kg_body(bx, t, off_e, kg_pack, srel, relw, ent_cur, ent_nxt, ent_res, ent0f, 1, 0);
    } else if (bx < KGB + USERB) {
        user_body(bx - KGB, t, off_u, u_pack, ent_cur, cf_cur, usr_res, usr0f, ucf, 1, 0);
    } else {
        angle_body(bx - KGB - USERB, t, ent0f, th, tt, sb, l2blk);
    }
}

// L2: kg hop1 + item hop0
__global__ void __launch_bounds__(256) fused_ik(
        const int* __restrict__ off_e, const int* __restrict__ kg_pack,
        const float* __restrict__ relw, const half8_t* __restrict__ ent_cur,
        half8_t* __restrict__ ent_nxt, half8_t* __restrict__ ent_res,
        const float4* __restrict__ ent0f,
        const int* __restrict__ off_i, const int2* __restrict__ i_pack,
        const half8_t* __restrict__ ucf, half8_t* __restrict__ cf_nxt,
        half8_t* __restrict__ cf_res, const float4* __restrict__ cf0f) {
    __shared__ half8_t srel[(N_REL - 1) * 9];
    int bx = blockIdx.x, t = threadIdx.x;
    if (bx < KGB) {
        kg_body(bx, t, off_e, kg_pack, srel, relw, ent_cur, ent_nxt, ent_res, ent0f, 0, 1);
    } else {
        item_body(bx - KGB, t, off_i, i_pack, ucf, cf_nxt, cf_res, cf0f, 1, 0);
    }
}

// L3: user hop1 alone
__global__ void __launch_bounds__(256) user_h1(
        const int* __restrict__ off_u, const int2* __restrict__ u_pack,
        const half8_t* __restrict__ ent_cur, const half8_t* __restrict__ cf_cur,
        half8_t* __restrict__ usr_res, const float4* __restrict__ usr0f,
        half8_t* __restrict__ ucf) {
    user_body(blockIdx.x, threadIdx.x, off_u, u_pack, ent_cur, cf_cur, usr_res, usr0f, ucf, 0, 1);
}

// L4: item hop1 alone
__global__ void __launch_bounds__(256) item_h1(
        const int* __restrict__ off_i, const int2* __restrict__ i_pack,
        const half8_t* __restrict__ ucf, half8_t* __restrict__ cf_nxt,
        half8_t* __restrict__ cf_res, const float4* __restrict__ cf0f) {
    item_body(blockIdx.x, threadIdx.x, off_i, i_pack, ucf, cf_nxt, cf_res, cf0f, 0, 1);
}

// ------------------------- losses -------------------------
__global__ void loss1_kernel(const int* __restrict__ user, const int* __restrict__ pos,
                             const int* __restrict__ neg, const half4_t* __restrict__ usr_res,
                             const half4_t* __restrict__ ent_res, const half4_t* __restrict__ cf_res,
                             float* __restrict__ l1p) {
    int b = blockIdx.x * 4 + (threadIdx.x >> 6);
    int lane = threadIdx.x & 63;
    int g = lane >> 4, q = lane & 15;
    int uid = user[b], pid = pos[b];
    float4 u = h2f(usr_res[uid * 16 + q]);
    float4 p = h2f(ent_res[pid * 16 + q]);
    float4 pc = h2f(cf_res[pid * 16 + q]);
    float dp = grp_red16(dot4(u, p) + dot4(u, pc));
    float ui_pos = fmaxf(2.0f - dp, 0.0f);
    float sum_n = 0.f, cnt_n = 0.f, sum_c = 0.f, cnt_c = 0.f;
    const int* nb = neg + b * NUM_NEG;
    for (int j = 0; j < NUM_NEG; j += 8) {
        int n0 = nb[j + g], n1 = nb[j + 4 + g];
        float4 e0 = h2f(ent_res[n0 * 16 + q]), c0 = h2f(cf_res[n0 * 16 + q]);
        float4 e1 = h2f(ent_res[n1 * 16 + q]), c1 = h2f(cf_res[n1 * 16 + q]);
        float dn0 = grp_red16(dot4(u, e0));
        float dc0 = grp_red16(dot4(u, c0));
        float dn1 = grp_red16(dot4(u, e1));
        float dc1 = grp_red16(dot4(u, c1));
        float s0 = fmaxf(dn0 - MARGIN_CCL, 0.f); sum_n += s0; if (s0 > 0.f) cnt_n += 1.f;
        float s1 = fmaxf(dn1 - MARGIN_CCL, 0.f); sum_n += s1; if (s1 > 0.f) cnt_n += 1.f;
        float t0 = fmaxf(dc0 - MARGIN_CCL, 0.f); sum_c += t0; if (t0 > 0.f) cnt_c += 1.f;
        float t1 = fmaxf(dc1 - MARGIN_CCL, 0.f); sum_c += t1; if (t1 > 0.f) cnt_c += 1.f;
    }
    sum_n = cross_grp_scalar(sum_n); cnt_n = cross_grp_scalar(cnt_n);
    sum_c = cross_grp_scalar(sum_c); cnt_c = cross_grp_scalar(cnt_c);
    if (lane == 0)
        l1p[b] = ui_pos + sum_n / (cnt_n + 1e-5f) + sum_c / (cnt_c + 1e-5f);
}

__global__ void finalize_kernel(const float* __restrict__ l1p, const float* __restrict__ l2b,
                                float* __restrict__ out) {
    __shared__ float sb[1024];
    float a1 = 0.f;
    for (int i = threadIdx.x; i < BATCH; i += 1024) a1 += l1p[i];
    float a2 = 0.f;
    for (int i = threadIdx.x; i < ANGLE_BLOCKS; i += 1024) a2 += l2b[i];
    sb[threadIdx.x] = a1 / (float)BATCH + ANGLE_W * a2 / (float)N_TRIPLETS;
    __syncthreads();
    for (int s = 512; s > 0; s >>= 1) {
        if (threadIdx.x < s) sb[threadIdx.x] += sb[threadIdx.x + s];
        __syncthreads();
    }
    if (threadIdx.x == 0) out[0] = sb[0];
}

extern "C" void kernel_launch(void* const* d_in, const int* in_sizes, int n_in,
                              void* d_out, int out_size, void* d_ws, size_t ws_size,
                              hipStream_t stream) {
    const float* all_embed = (const float*)d_in[0];
    const float* item_cf0  = (const float*)d_in[1];
    const float* relw      = (const float*)d_in[2];
    const float* vals      = (const float*)d_in[3];
    const int* user        = (const int*)d_in[4];
    const int* pos_item    = (const int*)d_in[5];
    const int* neg_item    = (const int*)d_in[6];
    const int* edge_head   = (const int*)d_in[7];
    const int* edge_tail   = edge_head + N_EDGES;
    const int* etype       = (const int*)d_in[8];
    const int* irows       = (const int*)d_in[9];
    const int* icols       = (const int*)d_in[10];
    const int* th          = (const int*)d_in[11];
    const int* tt          = (const int*)d_in[12];
    float* out             = (float*)d_out;

    char* base = (char*)d_ws;
    size_t woff = 0;
    auto alloc = [&](size_t bytes) -> void* {
        void* p = base + woff;
        woff = (woff + bytes + 255) & ~(size_t)255;
        return p;
    };
    half8_t* ent_a   = (half8_t*)alloc((size_t)N_ENTITIES * EMB * 2);
    half8_t* ent_b   = (half8_t*)alloc((size_t)N_ENTITIES * EMB * 2);
    half8_t* cf_a    = (half8_t*)alloc((size_t)N_ITEMS * EMB * 2);
    half8_t* cf_b    = (half8_t*)alloc((size_t)N_ITEMS * EMB * 2);
    half8_t* ucf     = (half8_t*)alloc((size_t)N_USERS * EMB * 2);
    half8_t* ent_res = (half8_t*)alloc((size_t)N_ITEMS * EMB * 2);
    half8_t* usr_res = (half8_t*)alloc((size_t)N_USERS * EMB * 2);
    half8_t* cf_res  = (half8_t*)alloc((size_t)N_ITEMS * EMB * 2);
    int2* u_pack     = (int2*)alloc((size_t)NNZ * 8);
    int2* i_pack     = (int2*)alloc((size_t)NNZ * 8);
    int* kg_pack     = (int*)alloc((size_t)N_EDGES * 4);
    int* keys_e      = (int*)alloc((size_t)N_EDGES * 4);
    int* keys_u      = (int*)alloc((size_t)NNZ * 4);
    int* keys_i      = (int*)alloc((size_t)NNZ * 4);
    float* l1p       = (float*)alloc((size_t)BATCH * 4);
    float* l2blk     = (float*)alloc((size_t)ANGLE_BLOCKS * 4);
    int* off_e       = (int*)alloc((size_t)(N_ENTITIES + 1) * 4);
    int* off_u       = (int*)alloc((size_t)(N_USERS + 1) * 4);
    int* off_i       = (int*)alloc((size_t)(N_ITEMS + 1) * 4);
    int* boff_e      = (int*)alloc((NBUCK + 1) * 4);
    int* boff_u      = (int*)alloc((NBUCK + 1) * 4);
    int* boff_i      = (int*)alloc((NBUCK + 1) * 4);
    int* bcur_e      = (int*)alloc(256 * 4);
    int* bcur_u      = (int*)alloc(256 * 4);
    int* bcur_i      = (int*)alloc(256 * 4);
    int* ph_e        = (int*)alloc((size_t)HBLK * NBUCK * 4);
    int* ph_u        = (int*)alloc((size_t)HBLK * NBUCK * 4);
    int* ph_i        = (int*)alloc((size_t)HBLK * NBUCK * 4);

    const float* ent0 = all_embed + (size_t)N_USERS * EMB;

    // 1) conversions + bucket hists
    prep_kernel<<<CONVE + CONVI + 3 * HBLK, 256, 0, stream>>>(
        (const float4*)ent0, (const float4*)item_cf0, (half4_t*)ent_a, (half4_t*)cf_a,
        edge_head, irows, icols, ph_e, ph_u, ph_i);
    // 2) bucket scans
    bucket_scan3<<<3, 1024, 0, stream>>>(ph_e, ph_u, ph_i, boff_e, boff_u, boff_i,
                                         bcur_e, bcur_u, bcur_i);
    // 3) phase 1 placement
    phase1_all<<<3 * HBLK, 256, 0, stream>>>(edge_head, edge_tail, etype, irows, icols, vals,
                                             bcur_e, bcur_u, bcur_i,
                                             keys_e, kg_pack, keys_u, u_pack, keys_i, i_pack);
    // 4) phase 2: row offsets + ordering
    phase2_all<<<3 * NBUCK, 256, 0, stream>>>(boff_e, keys_e, kg_pack, off_e,
                                              boff_u, keys_u, u_pack, off_u,
                                              boff_i, keys_i, i_pack, off_i);
    // 5) kg0 + user0 + angle
    fused_h0<<<KGB + USERB + ANGLE_BLOCKS, 256, 0, stream>>>(
        off_e, kg_pack, relw, ent_a, ent_b, ent_res, (const float4*)ent0,
        off_u, u_pack, cf_a, usr_res, (const float4*)all_embed, ucf,
        th, tt, l2blk);
    // 6) kg1 + item0
    fused_ik<<<KGB + ITEMB, 256, 0, stream>>>(
        off_e, kg_pack, relw, ent_b, ent_a, ent_res, (const float4*)ent0,
        off_i, i_pack, ucf, cf_b, cf_res, (const float4*)item_cf0);
    // 7) user1
    user_h1<<<USERB, 256, 0, stream>>>(off_u, u_pack, ent_b, cf_b, usr_res,
                                       (const float4*)all_embed, ucf);
    // 8) item1
    item_h1<<<ITEMB, 256, 0, stream>>>(off_i, i_pack, ucf, cf_a, cf_res,
                                       (const float4*)item_cf0);
    // 9) contrastive loss
    loss1_kernel<<<BATCH / 4, 256, 0, stream>>>(user, pos_item, neg_item, (const half4_t*)usr_res,
                                                (const half4_t*)ent_res, (const half4_t*)cf_res, l1p);
    // 10) final reduction
    finalize_kernel<<<1, 1024, 0, stream>>>(l1p, l2blk, out);
}

// Round 9
// 423.974 us; speedup vs baseline: 5.7471x; 1.0427x over previous
//
#include <hip/hip_runtime.h>
#include <math.h>

#define N_USERS    100000
#define N_ITEMS    50000
#define N_ENTITIES 200000
#define N_REL      20
#define EMB        64
#define HOPS       2
#define MARGIN_CCL 0.8f
#define NUM_NEG    64
#define ANGLE_W    0.1f
#define ANGLE_DROP 0.5f
#define N_EDGES    1000000
#define NNZ        1000000
#define N_TRIPLETS 200000
#define BATCH      4096
#define EPSF       1e-6f

#define TILE1 4096
#define NBUCK 196
#define BCAP  9216
#define ACAP  8192                           // arena slots per bucket (mean 5102, +43 sigma)
#define HBLK  ((N_EDGES + TILE1 - 1) / TILE1)   // 245
#define KGB   (N_ENTITIES / 32)              // 6250
#define USERB (N_USERS / 16)                 // 6250 (16-lane groups)
#define ITEMB ((N_ITEMS + 31) / 32)          // 1563
#define ANGB  (N_TRIPLETS / 32)              // 6250
#define LOSSB (BATCH / 4)                    // 1024
#define CONVE (N_ENTITIES * 16 / 256)        // 12500
#define CONVI (N_ITEMS * 16 / 256)           // 3125

typedef _Float16 half4_t __attribute__((ext_vector_type(4)));
typedef _Float16 half8_t __attribute__((ext_vector_type(8)));
typedef float float8_t __attribute__((ext_vector_type(8)));

__device__ inline float4 h2f(half4_t h) {
    return make_float4((float)h.x, (float)h.y, (float)h.z, (float)h.w);
}
__device__ inline half4_t f2h(float4 f) {
    half4_t h; h.x = (_Float16)f.x; h.y = (_Float16)f.y;
    h.z = (_Float16)f.z; h.w = (_Float16)f.w; return h;
}
__device__ inline float8_t h8_to_f8(half8_t h) { return __builtin_convertvector(h, float8_t); }
__device__ inline half8_t f8_to_h8(float8_t f) { return __builtin_convertvector(f, half8_t); }
__device__ inline half8_t h8_zero() {
    half8_t z;
    #pragma unroll
    for (int i = 0; i < 8; ++i) z[i] = (_Float16)0.0f;
    return z;
}
__device__ inline float sum_sq8(float8_t f) {
    float s = 0.f;
    #pragma unroll
    for (int i = 0; i < 8; ++i) s += f[i] * f[i];
    return s;
}
__device__ inline float dot8(float8_t a, float8_t b) {
    float s = 0.f;
    #pragma unroll
    for (int i = 0; i < 8; ++i) s += a[i] * b[i];
    return s;
}
__device__ inline float8_t f8_from2(float4 lo, float4 hi) {
    float8_t f;
    f[0] = lo.x; f[1] = lo.y; f[2] = lo.z; f[3] = lo.w;
    f[4] = hi.x; f[5] = hi.y; f[6] = hi.z; f[7] = hi.w;
    return f;
}
__device__ inline float grp_red8(float v) {
    v += __shfl_xor(v, 1, 64); v += __shfl_xor(v, 2, 64); v += __shfl_xor(v, 4, 64);
    return v;
}
__device__ inline float dot4(float4 a, float4 b) {
    return a.x * b.x + a.y * b.y + a.z * b.z + a.w * b.w;
}
__device__ inline float grp_red16(float v) {
    v += __shfl_xor(v, 1, 64); v += __shfl_xor(v, 2, 64);
    v += __shfl_xor(v, 4, 64); v += __shfl_xor(v, 8, 64);
    return v;
}
__device__ inline float cross_grp_scalar(float v) {
    v += __shfl_xor(v, 16, 64); v += __shfl_xor(v, 32, 64);
    return v;
}

// ------------------- prep: conversions + combined table + arena cursors ----------------
__global__ void __launch_bounds__(256) prep_kernel(
        const float4* __restrict__ ent0, const float4* __restrict__ cf0,
        half4_t* __restrict__ ent_a, half4_t* __restrict__ comb_a,
        int* __restrict__ bcur_e, int* __restrict__ bcur_u, int* __restrict__ bcur_i) {
    int bx = blockIdx.x, t = threadIdx.x;
    if (bx < CONVE) { int i = bx * 256 + t; ent_a[i] = f2h(ent0[i]); return; }
    bx -= CONVE;
    if (bx < CONVI) {   // combined table, ent half (items only)
        int i = bx * 256 + t;
        int row = i >> 4, o4 = i & 15;
        comb_a[row * 32 + o4] = f2h(ent0[i]);
        return;
    }
    bx -= CONVI;
    if (bx < CONVI) {   // combined table, cf half
        int i = bx * 256 + t;
        int row = i >> 4, o4 = i & 15;
        comb_a[row * 32 + 16 + o4] = f2h(cf0[i]);
        return;
    }
    if (t < NBUCK) {    // arena cursors
        bcur_e[t] = t * ACAP;
        bcur_u[t] = t * ACAP;
        bcur_i[t] = t * ACAP;
    }
}

// ------------------------- phase 1: 3 segments, one launch -----------------------------
__global__ void __launch_bounds__(256) phase1_all(
        const int* __restrict__ head, const int* __restrict__ tail,
        const int* __restrict__ etype, const int* __restrict__ rows,
        const int* __restrict__ cols, const float* __restrict__ vals,
        int* __restrict__ bcur_e, int* __restrict__ bcur_u, int* __restrict__ bcur_i,
        int* __restrict__ keys_e, int* __restrict__ kg_pay,
        int* __restrict__ keys_u, int2* __restrict__ u_pay,
        int* __restrict__ keys_i, int2* __restrict__ i_pay) {
    __shared__ int lhist[256], lstart[256], lcur[256], gbase[256];
    __shared__ int key_st[TILE1];
    __shared__ int2 pay_st[TILE1];
    int seg = blockIdx.x / HBLK;
    int tb  = blockIdx.x % HBLK;
    int t = threadIdx.x;
    int tstart = tb * TILE1;
    int valid = min(TILE1, N_EDGES - tstart);
    const int* karr = (seg == 0) ? head : (seg == 1) ? rows : cols;
    int shift = (seg == 0) ? 10 : (seg == 1) ? 9 : 8;
    int* bcur = (seg == 0) ? bcur_e : (seg == 1) ? bcur_u : bcur_i;
    lhist[t] = 0;
    __syncthreads();
    for (int i = t; i < valid; i += 256) atomicAdd(&lhist[karr[tstart + i] >> shift], 1);
    __syncthreads();
    int v = lhist[t];
    lstart[t] = v;
    __syncthreads();
    for (int d = 1; d < 256; d <<= 1) {
        int x = (t >= d) ? lstart[t - d] : 0;
        __syncthreads();
        lstart[t] += x;
        __syncthreads();
    }
    int excl = lstart[t] - v;
    lstart[t] = excl;
    lcur[t] = excl;
    gbase[t] = atomicAdd(&bcur[t], v);
    __syncthreads();
    if (seg == 0) {
        int* ps = (int*)pay_st;
        for (int i = t; i < valid; i += 256) {
            int h = head[tstart + i];
            int p = tail[tstart + i] | ((etype[tstart + i] - 1) << 18);
            int sp = atomicAdd(&lcur[h >> 10], 1);
            key_st[sp] = h;
            ps[sp] = p;
        }
        __syncthreads();
        for (int j = t; j < valid; j += 256) {
            int k = key_st[j];
            int b = k >> 10;
            int pos = gbase[b] + (j - lstart[b]);
            keys_e[pos] = k;
            kg_pay[pos] = ps[j];
        }
    } else {
        const int* oth = (seg == 1) ? cols : rows;
        int* keys = (seg == 1) ? keys_u : keys_i;
        int2* pay = (seg == 1) ? u_pay : i_pay;
        for (int i = t; i < valid; i += 256) {
            int k = karr[tstart + i];
            int2 p = make_int2(oth[tstart + i], __float_as_int(vals[tstart + i]));
            int sp = atomicAdd(&lcur[k >> shift], 1);
            key_st[sp] = k;
            pay_st[sp] = p;
        }
        __syncthreads();
        for (int j = t; j < valid; j += 256) {
            int k = key_st[j];
            int b = k >> shift;
            int pos = gbase[b] + (j - lstart[b]);
            keys[pos] = k;
            pay[pos] = pay_st[j];
        }
    }
}

// ------------- phase 2: row offsets (with per-bucket sentinel) + ordering --------------
__global__ void __launch_bounds__(256) phase2_all(
        const int* __restrict__ bcur_e, const int* __restrict__ keys_e,
        int* __restrict__ kg_pay, int* __restrict__ off_e,
        const int* __restrict__ bcur_u, const int* __restrict__ keys_u,
        int2* __restrict__ u_pay, int* __restrict__ off_u,
        const int* __restrict__ bcur_i, const int* __restrict__ keys_i,
        int2* __restrict__ i_pay, int* __restrict__ off_i) {
    __shared__ int hist[1024];
    __shared__ int s[256];
    __shared__ int2 lout2[BCAP];
    int seg = blockIdx.x / NBUCK;
    int b   = blockIdx.x % NBUCK;
    int t = threadIdx.x;
    int bins  = (seg == 0) ? 1024 : (seg == 1) ? 512 : 256;
    int shift = (seg == 0) ? 10 : (seg == 1) ? 9 : 8;
    int n_rows = (seg == 0) ? N_ENTITIES : (seg == 1) ? N_USERS : N_ITEMS;
    const int* bcur = (seg == 0) ? bcur_e : (seg == 1) ? bcur_u : bcur_i;
    const int* keys = (seg == 0) ? keys_e : (seg == 1) ? keys_u : keys_i;
    int* off = (seg == 0) ? off_e : (seg == 1) ? off_u : off_i;
    int rs = b << shift;
    int re = min(rs + bins, n_rows);
    int nr = re - rs;
    int base = b * ACAP;
    int len = bcur[b] - base;
    for (int r = t; r < bins; r += 256) hist[r] = 0;
    __syncthreads();
    for (int j = t; j < len; j += 256) atomicAdd(&hist[keys[base + j] - rs], 1);
    __syncthreads();
    int own = bins >> 8;
    int c[4]; int tot = 0;
    #pragma unroll 4
    for (int i = 0; i < own; ++i) { c[i] = hist[t * own + i]; tot += c[i]; }
    s[t] = tot;
    __syncthreads();
    for (int d = 1; d < 256; d <<= 1) {
        int x = (t >= d) ? s[t - d] : 0;
        __syncthreads();
        s[t] += x;
        __syncthreads();
    }
    int run = s[t] - tot;
    #pragma unroll 4
    for (int i = 0; i < own; ++i) { hist[t * own + i] = run; run += c[i]; }
    __syncthreads();
    // off with sentinel: idx(row) = row + bucket; slot rs+b+nr = bucket end
    for (int r = t; r < nr; r += 256) off[rs + b + r] = base + hist[r];
    if (t == 0) off[rs + b + nr] = base + len;
    __syncthreads();
    if (seg == 0) {
        int* lo = (int*)lout2;
        for (int j = t; j < len; j += 256) {
            int k = keys[base + j];
            int slot = atomicAdd(&hist[k - rs], 1);
            lo[slot] = kg_pay[base + j];
        }
        __syncthreads();
        for (int j = t; j < len; j += 256) kg_pay[base + j] = lo[j];
    } else {
        int2* pay = (seg == 1) ? u_pay : i_pay;
        for (int j = t; j < len; j += 256) {
            int k = keys[base + j];
            int slot = atomicAdd(&hist[k - rs], 1);
            lout2[slot] = pay[base + j];
        }
        __syncthreads();
        for (int j = t; j < len; j += 256) pay[base + j] = lout2[j];
    }
}

// ------------------------------ hop bodies ------------------------------
__device__ inline void kg_body(int bid, int t, const int* __restrict__ off,
                               const int* __restrict__ pack, half8_t* srel,
                               const float* __restrict__ relw,
                               const half8_t* __restrict__ src, half8_t* __restrict__ dst,
                               half8_t* __restrict__ comb_nxt, half8_t* __restrict__ res,
                               const float4* __restrict__ res_init, int first, int last) {
    if (t < (N_REL - 1) * 8) {
        int rel = t >> 3, o = t & 7;
        const float4* r4 = (const float4*)relw;
        srel[rel * 9 + o] = f8_to_h8(f8_from2(r4[rel * 16 + o * 2], r4[rel * 16 + o * 2 + 1]));
    }
    __syncthreads();
    int row = bid * 32 + (t >> 3);
    int o = t & 7;
    int idx = row + (row >> 10);
    int s = off[idx], e = off[idx + 1];
    half8_t acc = h8_zero();
    int k = s;
    for (; k + 2 <= e; k += 2) {
        int p0 = pack[k], p1 = pack[k + 1];
        half8_t a0 = src[(p0 & 0x3FFFF) * 8 + o];
        half8_t b0 = srel[(p0 >> 18) * 9 + o];
        half8_t a1 = src[(p1 & 0x3FFFF) * 8 + o];
        half8_t b1 = srel[(p1 >> 18) * 9 + o];
        acc += a0 * b0;
        acc += a1 * b1;
    }
    if (k < e) {
        int p0 = pack[k];
        acc += src[(p0 & 0x3FFFF) * 8 + o] * srel[(p0 >> 18) * 9 + o];
    }
    float8_t f = h8_to_f8(acc);
    f *= 1.0f / fmaxf((float)(e - s), 1.0f);
    float ss = grp_red8(sum_sq8(f));
    f *= 1.0f / fmaxf(sqrtf(ss), 1e-12f);
    half8_t oh = f8_to_h8(f);
    dst[row * 8 + o] = oh;
    if (row < N_ITEMS) {
        if (!last) comb_nxt[row * 16 + o] = oh;   // ent half of combined table
        float8_t rr;
        if (first) rr = f8_from2(res_init[row * 16 + o * 2], res_init[row * 16 + o * 2 + 1]);
        else       rr = h8_to_f8(res[row * 8 + o]);
        rr += f;
        if (last) {
            float s2 = grp_red8(sum_sq8(rr));
            rr *= 1.0f / fmaxf(sqrtf(s2), 1e-12f);
        }
        res[row * 8 + o] = f8_to_h8(rr);
    }
}

// 16-lane groups over the combined [ent|cf] table: one 256 B line per edge
__device__ inline void user_body(int bid, int t, const int* __restrict__ off,
                                 const int2* __restrict__ u_pack,
                                 const half8_t* __restrict__ comb,
                                 half8_t* __restrict__ usr_res,
                                 const float4* __restrict__ res_init,
                                 half8_t* __restrict__ ucf, int first, int last) {
    int row = bid * 16 + (t >> 4);
    int o = t & 15;
    int idx = row + (row >> 9);
    int s = off[idx], e = off[idx + 1];
    half8_t acc = h8_zero();
    int k = s;
    for (; k + 2 <= e; k += 2) {
        int2 p0 = u_pack[k], p1 = u_pack[k + 1];
        _Float16 v0 = (_Float16)__int_as_float(p0.y);
        _Float16 v1 = (_Float16)__int_as_float(p1.y);
        acc += comb[p0.x * 16 + o] * v0;
        acc += comb[p1.x * 16 + o] * v1;
    }
    if (k < e) {
        int2 p0 = u_pack[k];
        acc += comb[p0.x * 16 + o] * (_Float16)__int_as_float(p0.y);
    }
    float8_t f = h8_to_f8(acc);
    float ss = grp_red8(sum_sq8(f));   // per 8-lane half
    if (o < 8) {
        float rn = 1.0f / fmaxf(sqrtf(ss), 1e-12f);
        float8_t rr;
        if (first) rr = f8_from2(res_init[row * 16 + o * 2], res_init[row * 16 + o * 2 + 1]);
        else       rr = h8_to_f8(usr_res[row * 8 + o]);
        rr += f * rn;
        if (last) {
            float s2 = grp_red8(sum_sq8(rr));
            rr *= 1.0f / fmaxf(sqrtf(s2), 1e-12f);
        }
        usr_res[row * 8 + o] = f8_to_h8(rr);
    } else {
        ucf[row * 8 + (o - 8)] = acc;   // raw cf aggregate
    }
}

__device__ inline void item_body(int bid, int t, const int* __restrict__ off,
                                 const int2* __restrict__ i_pack,
                                 const half8_t* __restrict__ ucf,
                                 half8_t* __restrict__ comb_nxt, half8_t* __restrict__ res,
                                 const float4* __restrict__ res_init, int first, int last) {
    int row = bid * 32 + (t >> 3);
    int o = t & 7;
    if (row >= N_ITEMS) return;
    int idx = row + (row >> 8);
    int s = off[idx], e = off[idx + 1];
    half8_t acc = h8_zero();
    int k = s;
    for (; k + 2 <= e; k += 2) {
        int2 p0 = i_pack[k], p1 = i_pack[k + 1];
        _Float16 v0 = (_Float16)__int_as_float(p0.y);
        _Float16 v1 = (_Float16)__int_as_float(p1.y);
        acc += ucf[p0.x * 8 + o] * v0;
        acc += ucf[p1.x * 8 + o] * v1;
    }
    if (k < e) {
        int2 p0 = i_pack[k];
        acc += ucf[p0.x * 8 + o] * (_Float16)__int_as_float(p0.y);
    }
    float8_t f = h8_to_f8(acc);
    float ss = grp_red8(sum_sq8(f));
    f *= 1.0f / fmaxf(sqrtf(ss), 1e-12f);
    if (!last) comb_nxt[row * 16 + 8 + o] = f8_to_h8(f);   // cf half of combined table
    float8_t rr;
    if (first) rr = f8_from2(res_init[row * 16 + o * 2], res_init[row * 16 + o * 2 + 1]);
    else       rr = h8_to_f8(res[row * 8 + o]);
    rr += f;
    if (last) {
        float s2 = grp_red8(sum_sq8(rr));
        rr *= 1.0f / fmaxf(sqrtf(s2), 1e-12f);
    }
    res[row * 8 + o] = f8_to_h8(rr);
}

// fp16 angle: 8-lane groups, 32 triplets/block
__device__ inline void angle_body(int ablk, int t, const half8_t* __restrict__ ent_h,
                                  const int* __restrict__ th, const int* __restrict__ tt,
                                  float* sb, float* __restrict__ l2blk) {
    int o = t & 7;
    int grp = t >> 3;
    int trip = ablk * 32 + grp;
    int h = th[trip], t2 = tt[trip];
    float8_t hv = h8_to_f8(ent_h[h * 8 + o]);
    float8_t tv = h8_to_f8(ent_h[t2 * 8 + o]);
    hv *= ANGLE_DROP;
    tv *= ANGLE_DROP;
    float8_t dv = hv - tv;
    float s_hh = grp_red8(sum_sq8(hv));
    float s_tt = grp_red8(sum_sq8(tv));
    float s_ht = grp_red8(dot8(hv, tv));
    float s_dd = grp_red8(sum_sq8(dv));
    if (o == 0) {
        float nu = sqrtf(s_hh);
        float ed = sqrtf(s_dd);
        float sqnu = fminf(fmaxf(s_hh, 0.0f), 1.0f - EPSF);
        float ha_arg = fminf(fmaxf(0.1f * (1.0f - sqnu) / sqrtf(sqnu), -1.0f + EPSF), 1.0f - EPSF);
        float half_ap = asinf(ha_arg);
        float num = s_ht * (1.0f + s_hh) - s_hh * (1.0f + s_tt);
        float den = nu * ed * sqrtf(fmaxf(1.0f + s_tt * s_hh - 2.0f * s_ht, EPSF)) + EPSF;
        float ang = acosf(fminf(fmaxf(num / den, -1.0f + EPSF), 1.0f - EPSF));
        sb[grp] = fmaxf(ang - half_ap, 0.0f);
    }
    __syncthreads();
    if (t == 0) {
        float tot = 0.f;
        #pragma unroll
        for (int i = 0; i < 32; ++i) tot += sb[i];
        l2blk[ablk] = tot;
    }
}

// loss halves: ent part (dpe + neg-ent quotient), cf part (combine + neg-cf)
__device__ inline void loss_ent_body(int b, int t, const int* __restrict__ user,
                                     const int* __restrict__ pos, const int* __restrict__ neg,
                                     const half4_t* __restrict__ usr4,
                                     const half4_t* __restrict__ ent4,
                                     float* __restrict__ dpe, float* __restrict__ l1pe) {
    int lane = t & 63;
    int g = lane >> 4, q = lane & 15;
    int uid = user[b], pid = pos[b];
    float4 u = h2f(usr4[uid * 16 + q]);
    float4 p = h2f(ent4[pid * 16 + q]);
    float dpe_v = grp_red16(dot4(u, p));
    float sum_n = 0.f, cnt_n = 0.f;
    const int* nb = neg + b * NUM_NEG;
    for (int j = 0; j < NUM_NEG; j += 8) {
        int n0 = nb[j + g], n1 = nb[j + 4 + g];
        float dn0 = grp_red16(dot4(u, h2f(ent4[n0 * 16 + q])));
        float dn1 = grp_red16(dot4(u, h2f(ent4[n1 * 16 + q])));
        float s0 = fmaxf(dn0 - MARGIN_CCL, 0.f); sum_n += s0; if (s0 > 0.f) cnt_n += 1.f;
        float s1 = fmaxf(dn1 - MARGIN_CCL, 0.f); sum_n += s1; if (s1 > 0.f) cnt_n += 1.f;
    }
    sum_n = cross_grp_scalar(sum_n); cnt_n = cross_grp_scalar(cnt_n);
    if (lane == 0) {
        dpe[b] = dpe_v;
        l1pe[b] = sum_n / (cnt_n + 1e-5f);
    }
}

__global__ void __launch_bounds__(256) loss_cf_kernel(
        const int* __restrict__ user, const int* __restrict__ pos,
        const int* __restrict__ neg, const half4_t* __restrict__ usr4,
        const half4_t* __restrict__ cf4, const float* __restrict__ dpe,
        const float* __restrict__ l1pe, float* __restrict__ l1p) {
    int b = blockIdx.x * 4 + (threadIdx.x >> 6);
    int lane = threadIdx.x & 63;
    int g = lane >> 4, q = lane & 15;
    int uid = user[b], pid = pos[b];
    float4 u = h2f(usr4[uid * 16 + q]);
    float4 pc = h2f(cf4[pid * 16 + q]);
    float dpc = grp_red16(dot4(u, pc));
    float sum_c = 0.f, cnt_c = 0.f;
    const int* nb = neg + b * NUM_NEG;
    for (int j = 0; j < NUM_NEG; j += 8) {
        int n0 = nb[j + g], n1 = nb[j + 4 + g];
        float dc0 = grp_red16(dot4(u, h2f(cf4[n0 * 16 + q])));
        float dc1 = grp_red16(dot4(u, h2f(cf4[n1 * 16 + q])));
        float t0 = fmaxf(dc0 - MARGIN_CCL, 0.f); sum_c += t0; if (t0 > 0.f) cnt_c += 1.f;
        float t1 = fmaxf(dc1 - MARGIN_CCL, 0.f); sum_c += t1; if (t1 > 0.f) cnt_c += 1.f;
    }
    sum_c = cross_grp_scalar(sum_c); cnt_c = cross_grp_scalar(cnt_c);
    if (lane == 0) {
        float ui_pos = fmaxf(2.0f - dpe[b] - dpc, 0.0f);
        l1p[b] = ui_pos + l1pe[b] + sum_c / (cnt_c + 1e-5f);
    }
}

// --------------------------- fused launches ---------------------------
__global__ void __launch_bounds__(256) fused_h0(
        const int* __restrict__ off_e, const int* __restrict__ kg_pack,
        const float* __restrict__ relw, const half8_t* __restrict__ ent_a,
        half8_t* __restrict__ ent_b, half8_t* __restrict__ comb_b,
        half8_t* __restrict__ ent_res, const float4* __restrict__ ent0f,
        const int* __restrict__ off_u, const int2* __restrict__ u_pack,
        const half8_t* __restrict__ comb_a, half8_t* __restrict__ usr_res,
        const float4* __restrict__ usr0f, half8_t* __restrict__ ucf,
        const int* __restrict__ th, const int* __restrict__ tt,
        float* __restrict__ l2blk) {
    __shared__ half8_t srel[(N_REL - 1) * 9];
    __shared__ float sb[32];
    int bx = blockIdx.x, t = threadIdx.x;
    if (bx < KGB) {
        kg_body(bx, t, off_e, kg_pack, srel, relw, ent_a, ent_b, comb_b, ent_res, ent0f, 1, 0);
    } else if (bx < KGB + USERB) {
        user_body(bx - KGB, t, off_u, u_pack, comb_a, usr_res, usr0f, ucf, 1, 0);
    } else {
        angle_body(bx - KGB - USERB, t, ent_a, th, tt, sb, l2blk);
    }
}

__global__ void __launch_bounds__(256) fused_ik(
        const int* __restrict__ off_e, const int* __restrict__ kg_pack,
        const float* __restrict__ relw, const half8_t* __restrict__ ent_b,
        half8_t* __restrict__ ent_a, half8_t* __restrict__ ent_res,
        const float4* __restrict__ ent0f,
        const int* __restrict__ off_i, const int2* __restrict__ i_pack,
        const half8_t* __restrict__ ucf, half8_t* __restrict__ comb_b,
        half8_t* __restrict__ cf_res, const float4* __restrict__ cf0f) {
    __shared__ half8_t srel[(N_REL - 1) * 9];
    int bx = blockIdx.x, t = threadIdx.x;
    if (bx < KGB) {
        // kg hop1: last=1 (ent_res normalized); dst=ent_a (scratch), comb write skipped
        kg_body(bx, t, off_e, kg_pack, srel, relw, ent_b, ent_a, comb_b, ent_res, ent0f, 0, 1);
    } else {
        // item hop0: writes cf half of comb_b
        item_body(bx - KGB, t, off_i, i_pack, ucf, comb_b, cf_res, cf0f, 1, 0);
    }
}

__global__ void __launch_bounds__(256) user_h1(
        const int* __restrict__ off_u, const int2* __restrict__ u_pack,
        const half8_t* __restrict__ comb_b, half8_t* __restrict__ usr_res,
        const float4* __restrict__ usr0f, half8_t* __restrict__ ucf) {
    user_body(blockIdx.x, threadIdx.x, off_u, u_pack, comb_b, usr_res, usr0f, ucf, 0, 1);
}

// item hop1 + loss ent-half (both runnable after user_h1)
__global__ void __launch_bounds__(256) fused_item_loss(
        const int* __restrict__ off_i, const int2* __restrict__ i_pack,
        const half8_t* __restrict__ ucf, half8_t* __restrict__ comb_unused,
        half8_t* __restrict__ cf_res, const float4* __restrict__ cf0f,
        const int* __restrict__ user, const int* __restrict__ pos,
        const int* __restrict__ neg, const half4_t* __restrict__ usr4,
        const half4_t* __restrict__ ent4, float* __restrict__ dpe,
        float* __restrict__ l1pe) {
    int bx = blockIdx.x, t = threadIdx.x;
    if (bx < ITEMB) {
        item_body(bx, t, off_i, i_pack, ucf, comb_unused, cf_res, cf0f, 0, 1);
    } else {
        int b = (bx - ITEMB) * 4 + (t >> 6);
        loss_ent_body(b, t, user, pos, neg, usr4, ent4, dpe, l1pe);
    }
}

__global__ void finalize_kernel(const float* __restrict__ l1p, const float* __restrict__ l2b,
                                float* __restrict__ out) {
    __shared__ float sb[1024];
    float a1 = 0.f;
    for (int i = threadIdx.x; i < BATCH; i += 1024) a1 += l1p[i];
    float a2 = 0.f;
    for (int i = threadIdx.x; i < ANGB; i += 1024) a2 += l2b[i];
    sb[threadIdx.x] = a1 / (float)BATCH + ANGLE_W * a2 / (float)N_TRIPLETS;
    __syncthreads();
    for (int s = 512; s > 0; s >>= 1) {
        if (threadIdx.x < s) sb[threadIdx.x] += sb[threadIdx.x + s];
        __syncthreads();
    }
    if (threadIdx.x == 0) out[0] = sb[0];
}

extern "C" void kernel_launch(void* const* d_in, const int* in_sizes, int n_in,
                              void* d_out, int out_size, void* d_ws, size_t ws_size,
                              hipStream_t stream) {
    const float* all_embed = (const float*)d_in[0];
    const float* item_cf0  = (const float*)d_in[1];
    const float* relw      = (const float*)d_in[2];
    const float* vals      = (const float*)d_in[3];
    const int* user        = (const int*)d_in[4];
    const int* pos_item    = (const int*)d_in[5];
    const int* neg_item    = (const int*)d_in[6];
    const int* edge_head   = (const int*)d_in[7];
    const int* edge_tail   = edge_head + N_EDGES;
    const int* etype       = (const int*)d_in[8];
    const int* irows       = (const int*)d_in[9];
    const int* icols       = (const int*)d_in[10];
    const int* th          = (const int*)d_in[11];
    const int* tt          = (const int*)d_in[12];
    float* out             = (float*)d_out;

    char* base = (char*)d_ws;
    size_t woff = 0;
    auto alloc = [&](size_t bytes) -> void* {
        void* p = base + woff;
        woff = (woff + bytes + 255) & ~(size_t)255;
        return p;
    };
    half8_t* ent_a   = (half8_t*)alloc((size_t)N_ENTITIES * EMB * 2);
    half8_t* ent_b   = (half8_t*)alloc((size_t)N_ENTITIES * EMB * 2);
    half8_t* comb_a  = (half8_t*)alloc((size_t)N_ITEMS * EMB * 4);   // [ent|cf] interleave
    half8_t* comb_b  = (half8_t*)alloc((size_t)N_ITEMS * EMB * 4);
    half8_t* ucf     = (half8_t*)alloc((size_t)N_USERS * EMB * 2);
    half8_t* ent_res = (half8_t*)alloc((size_t)N_ITEMS * EMB * 2);
    half8_t* usr_res = (half8_t*)alloc((size_t)N_USERS * EMB * 2);
    half8_t* cf_res  = (half8_t*)alloc((size_t)N_ITEMS * EMB * 2);
    int2* u_pack     = (int2*)alloc((size_t)NBUCK * ACAP * 8);
    int2* i_pack     = (int2*)alloc((size_t)NBUCK * ACAP * 8);
    int* kg_pack     = (int*)alloc((size_t)NBUCK * ACAP * 4);
    int* keys_e      = (int*)alloc((size_t)NBUCK * ACAP * 4);
    int* keys_u      = (int*)alloc((size_t)NBUCK * ACAP * 4);
    int* keys_i      = (int*)alloc((size_t)NBUCK * ACAP * 4);
    float* l1p       = (float*)alloc((size_t)BATCH * 4);
    float* dpe       = (float*)alloc((size_t)BATCH * 4);
    float* l1pe      = (float*)alloc((size_t)BATCH * 4);
    float* l2blk     = (float*)alloc((size_t)ANGB * 4);
    int* off_e       = (int*)alloc((size_t)(N_ENTITIES + NBUCK + 1) * 4);
    int* off_u       = (int*)alloc((size_t)(N_USERS + NBUCK + 1) * 4);
    int* off_i       = (int*)alloc((size_t)(N_ITEMS + NBUCK + 1) * 4);
    int* bcur_e      = (int*)alloc(256 * 4);
    int* bcur_u      = (int*)alloc(256 * 4);
    int* bcur_i      = (int*)alloc(256 * 4);

    const float* ent0 = all_embed + (size_t)N_USERS * EMB;

    // 1) conversions + combined table + arena cursors
    prep_kernel<<<CONVE + 2 * CONVI + 1, 256, 0, stream>>>(
        (const float4*)ent0, (const float4*)item_cf0, (half4_t*)ent_a, (half4_t*)comb_a,
        bcur_e, bcur_u, bcur_i);
    // 2) phase 1: bucket-grouped placement into arenas
    phase1_all<<<3 * HBLK, 256, 0, stream>>>(edge_head, edge_tail, etype, irows, icols, vals,
                                             bcur_e, bcur_u, bcur_i,
                                             keys_e, kg_pack, keys_u, u_pack, keys_i, i_pack);
    // 3) phase 2: row offsets (sentinel layout) + in-bucket ordering
    phase2_all<<<3 * NBUCK, 256, 0, stream>>>(bcur_e, keys_e, kg_pack, off_e,
                                              bcur_u, keys_u, u_pack, off_u,
                                              bcur_i, keys_i, i_pack, off_i);
    // 4) kg0 + user0 + angle
    fused_h0<<<KGB + USERB + ANGB, 256, 0, stream>>>(
        off_e, kg_pack, relw, ent_a, ent_b, comb_b, ent_res, (const float4*)ent0,
        off_u, u_pack, comb_a, usr_res, (const float4*)all_embed, ucf,
        th, tt, l2blk);
    // 5) kg1 + item0
    fused_ik<<<KGB + ITEMB, 256, 0, stream>>>(
        off_e, kg_pack, relw, ent_b, ent_a, ent_res, (const float4*)ent0,
        off_i, i_pack, ucf, comb_b, cf_res, (const float4*)item_cf0);
    // 6) user1
    user_h1<<<USERB, 256, 0, stream>>>(off_u, u_pack, comb_b, usr_res,
                                       (const float4*)all_embed, ucf);
    // 7) item1 + loss ent-half
    fused_item_loss<<<ITEMB + LOSSB, 256, 0, stream>>>(
        off_i, i_pack, ucf, comb_a, cf_res, (const float4*)item_cf0,
        user, pos_item, neg_item, (const half4_t*)usr_res, (const half4_t*)ent_res,
        dpe, l1pe);
    // 8) loss cf-half + combine
    loss_cf_kernel<<<LOSSB, 256, 0, stream>>>(user, pos_item, neg_item,
                                              (const half4_t*)usr_res, (const half4_t*)cf_res,
                                              dpe, l1pe, l1p);
    // 9) final reduction
    finalize_kernel<<<1, 1024, 0, stream>>>(l1p, l2blk, out);
}

// Round 10
// 413.848 us; speedup vs baseline: 5.8877x; 1.0245x over previous
//
#include <hip/hip_runtime.h>
#include <math.h>

#define N_USERS    100000
#define N_ITEMS    50000
#define N_ENTITIES 200000
#define N_REL      20
#define EMB        64
#define HOPS       2
#define MARGIN_CCL 0.8f
#define NUM_NEG    64
#define ANGLE_W    0.1f
#define ANGLE_DROP 0.5f
#define N_EDGES    1000000
#define NNZ        1000000
#define N_TRIPLETS 200000
#define BATCH      4096
#define EPSF       1e-6f

#define TILE1 4096
#define NBUCK 196
#define BCAP  9216
#define ACAP  8192
#define HBLK  ((N_EDGES + TILE1 - 1) / TILE1)   // 245
#define P1B   (3 * HBLK)                     // 735
#define KGB   (N_ENTITIES / 32)              // 6250
#define USERB (N_USERS / 16)                 // 6250
#define ITEMB ((N_ITEMS + 31) / 32)          // 1563
#define ANGB  (N_TRIPLETS / 32)              // 6250
#define LOSSB (BATCH / 4)                    // 1024
#define CONVE (N_ENTITIES * 16 / 256)        // 12500
#define CONVI (N_ITEMS * 16 / 256)           // 3125

typedef _Float16 half4_t __attribute__((ext_vector_type(4)));
typedef _Float16 half8_t __attribute__((ext_vector_type(8)));
typedef float float8_t __attribute__((ext_vector_type(8)));

__device__ inline float4 h2f(half4_t h) {
    return make_float4((float)h.x, (float)h.y, (float)h.z, (float)h.w);
}
__device__ inline half4_t f2h(float4 f) {
    half4_t h; h.x = (_Float16)f.x; h.y = (_Float16)f.y;
    h.z = (_Float16)f.z; h.w = (_Float16)f.w; return h;
}
__device__ inline float8_t h8_to_f8(half8_t h) { return __builtin_convertvector(h, float8_t); }
__device__ inline half8_t f8_to_h8(float8_t f) { return __builtin_convertvector(f, half8_t); }
__device__ inline half8_t h8_zero() {
    half8_t z;
    #pragma unroll
    for (int i = 0; i < 8; ++i) z[i] = (_Float16)0.0f;
    return z;
}
__device__ inline float sum_sq8(float8_t f) {
    float s = 0.f;
    #pragma unroll
    for (int i = 0; i < 8; ++i) s += f[i] * f[i];
    return s;
}
__device__ inline float dot8(float8_t a, float8_t b) {
    float s = 0.f;
    #pragma unroll
    for (int i = 0; i < 8; ++i) s += a[i] * b[i];
    return s;
}
__device__ inline float8_t f8_from2(float4 lo, float4 hi) {
    float8_t f;
    f[0] = lo.x; f[1] = lo.y; f[2] = lo.z; f[3] = lo.w;
    f[4] = hi.x; f[5] = hi.y; f[6] = hi.z; f[7] = hi.w;
    return f;
}
__device__ inline float grp_red8(float v) {
    v += __shfl_xor(v, 1, 64); v += __shfl_xor(v, 2, 64); v += __shfl_xor(v, 4, 64);
    return v;
}
__device__ inline float dot4(float4 a, float4 b) {
    return a.x * b.x + a.y * b.y + a.z * b.z + a.w * b.w;
}
__device__ inline float grp_red16(float v) {
    v += __shfl_xor(v, 1, 64); v += __shfl_xor(v, 2, 64);
    v += __shfl_xor(v, 4, 64); v += __shfl_xor(v, 8, 64);
    return v;
}
__device__ inline float cross_grp_scalar(float v) {
    v += __shfl_xor(v, 16, 64); v += __shfl_xor(v, 32, 64);
    return v;
}

// ------------------- prep: conversions + combined table + arena cursors ----------------
__global__ void __launch_bounds__(256) prep_kernel(
        const float4* __restrict__ ent0, const float4* __restrict__ cf0,
        half4_t* __restrict__ ent_a, half4_t* __restrict__ comb_a,
        int* __restrict__ bcur_e, int* __restrict__ bcur_u, int* __restrict__ bcur_i) {
    int bx = blockIdx.x, t = threadIdx.x;
    if (bx < CONVE) { int i = bx * 256 + t; ent_a[i] = f2h(ent0[i]); return; }
    bx -= CONVE;
    if (bx < CONVI) {
        int i = bx * 256 + t;
        int row = i >> 4, o4 = i & 15;
        comb_a[row * 32 + o4] = f2h(ent0[i]);
        return;
    }
    bx -= CONVI;
    if (bx < CONVI) {
        int i = bx * 256 + t;
        int row = i >> 4, o4 = i & 15;
        comb_a[row * 32 + 16 + o4] = f2h(cf0[i]);
        return;
    }
    if (t < NBUCK) {
        bcur_e[t] = t * ACAP;
        bcur_u[t] = t * ACAP;
        bcur_i[t] = t * ACAP;
    }
}

// fp16 angle body: 8-lane groups, 32 triplets/block
__device__ inline void angle_body(int ablk, int t, const half8_t* __restrict__ ent_h,
                                  const int* __restrict__ th, const int* __restrict__ tt,
                                  float* sb, float* __restrict__ l2blk) {
    int o = t & 7;
    int grp = t >> 3;
    int trip = ablk * 32 + grp;
    int h = th[trip], t2 = tt[trip];
    float8_t hv = h8_to_f8(ent_h[h * 8 + o]);
    float8_t tv = h8_to_f8(ent_h[t2 * 8 + o]);
    hv *= ANGLE_DROP;
    tv *= ANGLE_DROP;
    float8_t dv = hv - tv;
    float s_hh = grp_red8(sum_sq8(hv));
    float s_tt = grp_red8(sum_sq8(tv));
    float s_ht = grp_red8(dot8(hv, tv));
    float s_dd = grp_red8(sum_sq8(dv));
    if (o == 0) {
        float nu = sqrtf(s_hh);
        float ed = sqrtf(s_dd);
        float sqnu = fminf(fmaxf(s_hh, 0.0f), 1.0f - EPSF);
        float ha_arg = fminf(fmaxf(0.1f * (1.0f - sqnu) / sqrtf(sqnu), -1.0f + EPSF), 1.0f - EPSF);
        float half_ap = asinf(ha_arg);
        float num = s_ht * (1.0f + s_hh) - s_hh * (1.0f + s_tt);
        float den = nu * ed * sqrtf(fmaxf(1.0f + s_tt * s_hh - 2.0f * s_ht, EPSF)) + EPSF;
        float ang = acosf(fminf(fmaxf(num / den, -1.0f + EPSF), 1.0f - EPSF));
        sb[grp] = fmaxf(ang - half_ap, 0.0f);
    }
    __syncthreads();
    if (t == 0) {
        float tot = 0.f;
        #pragma unroll
        for (int i = 0; i < 32; ++i) tot += sb[i];
        l2blk[ablk] = tot;
    }
}

// -------------- phase 1 (+angle overlap): bucket-grouped placement ---------------------
// u/i keys embedded in payload .x: u: col(16b) | (row&511)<<16 ; i: row(17b) | (col&255)<<17
__global__ void __launch_bounds__(256) phase1_angle(
        const int* __restrict__ head, const int* __restrict__ tail,
        const int* __restrict__ etype, const int* __restrict__ rows,
        const int* __restrict__ cols, const float* __restrict__ vals,
        int* __restrict__ bcur_e, int* __restrict__ bcur_u, int* __restrict__ bcur_i,
        int* __restrict__ keys_e, int* __restrict__ kg_pay,
        int2* __restrict__ u_pay, int2* __restrict__ i_pay,
        const half8_t* __restrict__ ent_a, const int* __restrict__ th,
        const int* __restrict__ tt, float* __restrict__ l2blk) {
    __shared__ int2 pay_st[TILE1];          // 32 KB; edges alias: key_st / ps halves
    __shared__ int lhist[256], lstart[256], lcur[256], gbase[256];
    __shared__ float sb[32];
    int bx = blockIdx.x, t = threadIdx.x;
    if (bx >= P1B) {
        angle_body(bx - P1B, t, ent_a, th, tt, sb, l2blk);
        return;
    }
    int seg = bx / HBLK;
    int tb  = bx % HBLK;
    int tstart = tb * TILE1;
    int valid = min(TILE1, N_EDGES - tstart);
    const int* karr = (seg == 0) ? head : (seg == 1) ? rows : cols;
    int shift = (seg == 0) ? 10 : (seg == 1) ? 9 : 8;
    int* bcur = (seg == 0) ? bcur_e : (seg == 1) ? bcur_u : bcur_i;
    lhist[t] = 0;
    __syncthreads();
    for (int i = t; i < valid; i += 256) atomicAdd(&lhist[karr[tstart + i] >> shift], 1);
    __syncthreads();
    int v = lhist[t];
    lstart[t] = v;
    __syncthreads();
    for (int d = 1; d < 256; d <<= 1) {
        int x = (t >= d) ? lstart[t - d] : 0;
        __syncthreads();
        lstart[t] += x;
        __syncthreads();
    }
    int excl = lstart[t] - v;
    lstart[t] = excl;
    lcur[t] = excl;
    gbase[t] = atomicAdd(&bcur[t], v);
    __syncthreads();
    if (seg == 0) {
        int* key_st = (int*)pay_st;
        int* ps = key_st + TILE1;
        for (int i = t; i < valid; i += 256) {
            int h = head[tstart + i];
            int p = tail[tstart + i] | ((etype[tstart + i] - 1) << 18);
            int sp = atomicAdd(&lcur[h >> 10], 1);
            key_st[sp] = h;
            ps[sp] = p;
        }
        __syncthreads();
        for (int j = t; j < valid; j += 256) {
            int k = key_st[j];
            int b = k >> 10;
            int pos = gbase[b] + (j - lstart[b]);
            keys_e[pos] = k;
            kg_pay[pos] = ps[j];
        }
    } else {
        int2* pay = (seg == 1) ? u_pay : i_pay;
        for (int i = t; i < valid; i += 256) {
            int k = karr[tstart + i];
            int px;
            if (seg == 1) px = cols[tstart + i] | ((k & 511) << 16);
            else          px = rows[tstart + i] | ((k & 255) << 17);
            int2 p = make_int2(px, __float_as_int(vals[tstart + i]));
            int sp = atomicAdd(&lcur[k >> shift], 1);
            pay_st[sp] = p;
        }
        __syncthreads();
        for (int j = t; j < valid; j += 256) {
            int2 p = pay_st[j];
            int key = (seg == 1) ? ((p.x >> 16) & 511) : ((p.x >> 17) & 255);
            int b = (gbase[0], 0);   // placeholder, recomputed below
            // bucket id: need original row; reconstruct from key + which bucket this slot
            // belongs to — we stored per-bucket runs in LDS order, so find bucket via lstart.
            (void)b;
            // Recompute bucket by binary property: runs are contiguous; use lstart table.
            // Simple approach: store bucket implicitly — since runs are ordered by bucket,
            // find bucket b s.t. lstart[b] <= j < lstart[b]+count. Binary search over 256.
            int lo = 0, hi = 255;
            while (lo < hi) {
                int mid = (lo + hi + 1) >> 1;
                if (lstart[mid] <= j) lo = mid; else hi = mid - 1;
            }
            int bb = lo;
            int pos = gbase[bb] + (j - lstart[bb]);
            pay[pos] = p;
        }
    }
}

// ------------- phase 2: row offsets (with per-bucket sentinel) + ordering --------------
__global__ void __launch_bounds__(256) phase2_all(
        const int* __restrict__ bcur_e, const int* __restrict__ keys_e,
        int* __restrict__ kg_pay, int* __restrict__ off_e,
        const int* __restrict__ bcur_u, int2* __restrict__ u_pay, int* __restrict__ off_u,
        const int* __restrict__ bcur_i, int2* __restrict__ i_pay, int* __restrict__ off_i) {
    __shared__ int hist[1024];
    __shared__ int s[256];
    __shared__ int2 lout2[BCAP];
    int seg = blockIdx.x / NBUCK;
    int b   = blockIdx.x % NBUCK;
    int t = threadIdx.x;
    int bins  = (seg == 0) ? 1024 : (seg == 1) ? 512 : 256;
    int shift = (seg == 0) ? 10 : (seg == 1) ? 9 : 8;
    int n_rows = (seg == 0) ? N_ENTITIES : (seg == 1) ? N_USERS : N_ITEMS;
    const int* bcur = (seg == 0) ? bcur_e : (seg == 1) ? bcur_u : bcur_i;
    int* off = (seg == 0) ? off_e : (seg == 1) ? off_u : off_i;
    int rs = b << shift;
    int re = min(rs + bins, n_rows);
    int nr = re - rs;
    int base = b * ACAP;
    int len = bcur[b] - base;
    for (int r = t; r < bins; r += 256) hist[r] = 0;
    __syncthreads();
    if (seg == 0) {
        for (int j = t; j < len; j += 256) atomicAdd(&hist[keys_e[base + j] - rs], 1);
    } else if (seg == 1) {
        for (int j = t; j < len; j += 256) atomicAdd(&hist[(u_pay[base + j].x >> 16) & 511], 1);
    } else {
        for (int j = t; j < len; j += 256) atomicAdd(&hist[(i_pay[base + j].x >> 17) & 255], 1);
    }
    __syncthreads();
    int own = bins >> 8;
    int c[4]; int tot = 0;
    #pragma unroll 4
    for (int i = 0; i < own; ++i) { c[i] = hist[t * own + i]; tot += c[i]; }
    s[t] = tot;
    __syncthreads();
    for (int d = 1; d < 256; d <<= 1) {
        int x = (t >= d) ? s[t - d] : 0;
        __syncthreads();
        s[t] += x;
        __syncthreads();
    }
    int run = s[t] - tot;
    #pragma unroll 4
    for (int i = 0; i < own; ++i) { hist[t * own + i] = run; run += c[i]; }
    __syncthreads();
    for (int r = t; r < nr; r += 256) off[rs + b + r] = base + hist[r];
    if (t == 0) off[rs + b + nr] = base + len;
    __syncthreads();
    if (seg == 0) {
        int* lo = (int*)lout2;
        for (int j = t; j < len; j += 256) {
            int k = keys_e[base + j];
            int slot = atomicAdd(&hist[k - rs], 1);
            lo[slot] = kg_pay[base + j];
        }
        __syncthreads();
        for (int j = t; j < len; j += 256) kg_pay[base + j] = lo[j];
    } else {
        int2* pay = (seg == 1) ? u_pay : i_pay;
        int sh = (seg == 1) ? 16 : 17;
        int msk = (seg == 1) ? 511 : 255;
        for (int j = t; j < len; j += 256) {
            int2 p = pay[base + j];
            int slot = atomicAdd(&hist[(p.x >> sh) & msk], 1);
            lout2[slot] = p;
        }
        __syncthreads();
        for (int j = t; j < len; j += 256) pay[base + j] = lout2[j];
    }
}

// ------------------------------ hop bodies ------------------------------
__device__ inline void kg_body(int bid, int t, const int* __restrict__ off,
                               const int* __restrict__ pack, half8_t* srel,
                               const float* __restrict__ relw,
                               const half8_t* __restrict__ src, half8_t* __restrict__ dst,
                               half8_t* __restrict__ comb_nxt, half8_t* __restrict__ res,
                               const float4* __restrict__ res_init, int first, int last) {
    if (t < (N_REL - 1) * 8) {
        int rel = t >> 3, o = t & 7;
        const float4* r4 = (const float4*)relw;
        srel[rel * 9 + o] = f8_to_h8(f8_from2(r4[rel * 16 + o * 2], r4[rel * 16 + o * 2 + 1]));
    }
    __syncthreads();
    int row = bid * 32 + (t >> 3);
    int o = t & 7;
    int idx = row + (row >> 10);
    int s = off[idx], e = off[idx + 1];
    half8_t acc = h8_zero();
    int k = s;
    for (; k + 2 <= e; k += 2) {
        int p0 = pack[k], p1 = pack[k + 1];
        half8_t a0 = src[(p0 & 0x3FFFF) * 8 + o];
        half8_t b0 = srel[(p0 >> 18) * 9 + o];
        half8_t a1 = src[(p1 & 0x3FFFF) * 8 + o];
        half8_t b1 = srel[(p1 >> 18) * 9 + o];
        acc += a0 * b0;
        acc += a1 * b1;
    }
    if (k < e) {
        int p0 = pack[k];
        acc += src[(p0 & 0x3FFFF) * 8 + o] * srel[(p0 >> 18) * 9 + o];
    }
    float8_t f = h8_to_f8(acc);
    f *= 1.0f / fmaxf((float)(e - s), 1.0f);
    float ss = grp_red8(sum_sq8(f));
    f *= 1.0f / fmaxf(sqrtf(ss), 1e-12f);
    half8_t oh = f8_to_h8(f);
    dst[row * 8 + o] = oh;
    if (row < N_ITEMS) {
        if (!last) comb_nxt[row * 16 + o] = oh;
        float8_t rr;
        if (first) rr = f8_from2(res_init[row * 16 + o * 2], res_init[row * 16 + o * 2 + 1]);
        else       rr = h8_to_f8(res[row * 8 + o]);
        rr += f;
        if (last) {
            float s2 = grp_red8(sum_sq8(rr));
            rr *= 1.0f / fmaxf(sqrtf(s2), 1e-12f);
        }
        res[row * 8 + o] = f8_to_h8(rr);
    }
}

__device__ inline void user_body(int bid, int t, const int* __restrict__ off,
                                 const int2* __restrict__ u_pack,
                                 const half8_t* __restrict__ comb,
                                 half8_t* __restrict__ usr_res,
                                 const float4* __restrict__ res_init,
                                 half8_t* __restrict__ ucf, int first, int last) {
    int row = bid * 16 + (t >> 4);
    int o = t & 15;
    int idx = row + (row >> 9);
    int s = off[idx], e = off[idx + 1];
    half8_t acc = h8_zero();
    int k = s;
    for (; k + 2 <= e; k += 2) {
        int2 p0 = u_pack[k], p1 = u_pack[k + 1];
        _Float16 v0 = (_Float16)__int_as_float(p0.y);
        _Float16 v1 = (_Float16)__int_as_float(p1.y);
        acc += comb[(p0.x & 0xFFFF) * 16 + o] * v0;
        acc += comb[(p1.x & 0xFFFF) * 16 + o] * v1;
    }
    if (k < e) {
        int2 p0 = u_pack[k];
        acc += comb[(p0.x & 0xFFFF) * 16 + o] * (_Float16)__int_as_float(p0.y);
    }
    float8_t f = h8_to_f8(acc);
    float ss = grp_red8(sum_sq8(f));
    if (o < 8) {
        float rn = 1.0f / fmaxf(sqrtf(ss), 1e-12f);
        float8_t rr;
        if (first) rr = f8_from2(res_init[row * 16 + o * 2], res_init[row * 16 + o * 2 + 1]);
        else       rr = h8_to_f8(usr_res[row * 8 + o]);
        rr += f * rn;
        if (last) {
            float s2 = grp_red8(sum_sq8(rr));
            rr *= 1.0f / fmaxf(sqrtf(s2), 1e-12f);
        }
        usr_res[row * 8 + o] = f8_to_h8(rr);
    } else {
        ucf[row * 8 + (o - 8)] = acc;
    }
}

__device__ inline void item_body(int bid, int t, const int* __restrict__ off,
                                 const int2* __restrict__ i_pack,
                                 const half8_t* __restrict__ ucf,
                                 half8_t* __restrict__ comb_nxt, half8_t* __restrict__ res,
                                 const float4* __restrict__ res_init, int first, int last) {
    int row = bid * 32 + (t >> 3);
    int o = t & 7;
    if (row >= N_ITEMS) return;
    int idx = row + (row >> 8);
    int s = off[idx], e = off[idx + 1];
    half8_t acc = h8_zero();
    int k = s;
    for (; k + 2 <= e; k += 2) {
        int2 p0 = i_pack[k], p1 = i_pack[k + 1];
        _Float16 v0 = (_Float16)__int_as_float(p0.y);
        _Float16 v1 = (_Float16)__int_as_float(p1.y);
        acc += ucf[(p0.x & 0x1FFFF) * 8 + o] * v0;
        acc += ucf[(p1.x & 0x1FFFF) * 8 + o] * v1;
    }
    if (k < e) {
        int2 p0 = i_pack[k];
        acc += ucf[(p0.x & 0x1FFFF) * 8 + o] * (_Float16)__int_as_float(p0.y);
    }
    float8_t f = h8_to_f8(acc);
    float ss = grp_red8(sum_sq8(f));
    f *= 1.0f / fmaxf(sqrtf(ss), 1e-12f);
    if (!last) comb_nxt[row * 16 + 8 + o] = f8_to_h8(f);
    float8_t rr;
    if (first) rr = f8_from2(res_init[row * 16 + o * 2], res_init[row * 16 + o * 2 + 1]);
    else       rr = h8_to_f8(res[row * 8 + o]);
    rr += f;
    if (last) {
        float s2 = grp_red8(sum_sq8(rr));
        rr *= 1.0f / fmaxf(sqrtf(s2), 1e-12f);
    }
    res[row * 8 + o] = f8_to_h8(rr);
}

// loss halves
__device__ inline void loss_ent_body(int b, int t, const int* __restrict__ user,
                                     const int* __restrict__ pos, const int* __restrict__ neg,
                                     const half4_t* __restrict__ usr4,
                                     const half4_t* __restrict__ ent4,
                                     float* __restrict__ dpe, float* __restrict__ l1pe) {
    int lane = t & 63;
    int g = lane >> 4, q = lane & 15;
    int uid = user[b], pid = pos[b];
    float4 u = h2f(usr4[uid * 16 + q]);
    float4 p = h2f(ent4[pid * 16 + q]);
    float dpe_v = grp_red16(dot4(u, p));
    float sum_n = 0.f, cnt_n = 0.f;
    const int* nb = neg + b * NUM_NEG;
    for (int j = 0; j < NUM_NEG; j += 8) {
        int n0 = nb[j + g], n1 = nb[j + 4 + g];
        float dn0 = grp_red16(dot4(u, h2f(ent4[n0 * 16 + q])));
        float dn1 = grp_red16(dot4(u, h2f(ent4[n1 * 16 + q])));
        float s0 = fmaxf(dn0 - MARGIN_CCL, 0.f); sum_n += s0; if (s0 > 0.f) cnt_n += 1.f;
        float s1 = fmaxf(dn1 - MARGIN_CCL, 0.f); sum_n += s1; if (s1 > 0.f) cnt_n += 1.f;
    }
    sum_n = cross_grp_scalar(sum_n); cnt_n = cross_grp_scalar(cnt_n);
    if (lane == 0) {
        dpe[b] = dpe_v;
        l1pe[b] = sum_n / (cnt_n + 1e-5f);
    }
}

__global__ void __launch_bounds__(256) loss_cf_kernel(
        const int* __restrict__ user, const int* __restrict__ pos,
        const int* __restrict__ neg, const half4_t* __restrict__ usr4,
        const half4_t* __restrict__ cf4, const float* __restrict__ dpe,
        const float* __restrict__ l1pe, float* __restrict__ l1p) {
    int b = blockIdx.x * 4 + (threadIdx.x >> 6);
    int lane = threadIdx.x & 63;
    int g = lane >> 4, q = lane & 15;
    int uid = user[b], pid = pos[b];
    float4 u = h2f(usr4[uid * 16 + q]);
    float4 pc = h2f(cf4[pid * 16 + q]);
    float dpc = grp_red16(dot4(u, pc));
    float sum_c = 0.f, cnt_c = 0.f;
    const int* nb = neg + b * NUM_NEG;
    for (int j = 0; j < NUM_NEG; j += 8) {
        int n0 = nb[j + g], n1 = nb[j + 4 + g];
        float dc0 = grp_red16(dot4(u, h2f(cf4[n0 * 16 + q])));
        float dc1 = grp_red16(dot4(u, h2f(cf4[n1 * 16 + q])));
        float t0 = fmaxf(dc0 - MARGIN_CCL, 0.f); sum_c += t0; if (t0 > 0.f) cnt_c += 1.f;
        float t1 = fmaxf(dc1 - MARGIN_CCL, 0.f); sum_c += t1; if (t1 > 0.f) cnt_c += 1.f;
    }
    sum_c = cross_grp_scalar(sum_c); cnt_c = cross_grp_scalar(cnt_c);
    if (lane == 0) {
        float ui_pos = fmaxf(2.0f - dpe[b] - dpc, 0.0f);
        l1p[b] = ui_pos + l1pe[b] + sum_c / (cnt_c + 1e-5f);
    }
}

// --------------------------- fused launches ---------------------------
__global__ void __launch_bounds__(256) fused_h0(
        const int* __restrict__ off_e, const int* __restrict__ kg_pack,
        const float* __restrict__ relw, const half8_t* __restrict__ ent_a,
        half8_t* __restrict__ ent_b, half8_t* __restrict__ comb_b,
        half8_t* __restrict__ ent_res, const float4* __restrict__ ent0f,
        const int* __restrict__ off_u, const int2* __restrict__ u_pack,
        const half8_t* __restrict__ comb_a, half8_t* __restrict__ usr_res,
        const float4* __restrict__ usr0f, half8_t* __restrict__ ucf) {
    __shared__ half8_t srel[(N_REL - 1) * 9];
    int bx = blockIdx.x, t = threadIdx.x;
    if (bx < KGB) {
        kg_body(bx, t, off_e, kg_pack, srel, relw, ent_a, ent_b, comb_b, ent_res, ent0f, 1, 0);
    } else {
        user_body(bx - KGB, t, off_u, u_pack, comb_a, usr_res, usr0f, ucf, 1, 0);
    }
}

__global__ void __launch_bounds__(256) fused_ik(
        const int* __restrict__ off_e, const int* __restrict__ kg_pack,
        const float* __restrict__ relw, const half8_t* __restrict__ ent_b,
        half8_t* __restrict__ ent_a, half8_t* __restrict__ ent_res,
        const float4* __restrict__ ent0f,
        const int* __restrict__ off_i, const int2* __restrict__ i_pack,
        const half8_t* __restrict__ ucf, half8_t* __restrict__ comb_b,
        half8_t* __restrict__ cf_res, const float4* __restrict__ cf0f) {
    __shared__ half8_t srel[(N_REL - 1) * 9];
    int bx = blockIdx.x, t = threadIdx.x;
    if (bx < KGB) {
        kg_body(bx, t, off_e, kg_pack, srel, relw, ent_b, ent_a, comb_b, ent_res, ent0f, 0, 1);
    } else {
        item_body(bx - KGB, t, off_i, i_pack, ucf, comb_b, cf_res, cf0f, 1, 0);
    }
}

__global__ void __launch_bounds__(256) user_h1(
        const int* __restrict__ off_u, const int2* __restrict__ u_pack,
        const half8_t* __restrict__ comb_b, half8_t* __restrict__ usr_res,
        const float4* __restrict__ usr0f, half8_t* __restrict__ ucf) {
    user_body(blockIdx.x, threadIdx.x, off_u, u_pack, comb_b, usr_res, usr0f, ucf, 0, 1);
}

__global__ void __launch_bounds__(256) fused_item_loss(
        const int* __restrict__ off_i, const int2* __restrict__ i_pack,
        const half8_t* __restrict__ ucf, half8_t* __restrict__ comb_unused,
        half8_t* __restrict__ cf_res, const float4* __restrict__ cf0f,
        const int* __restrict__ user, const int* __restrict__ pos,
        const int* __restrict__ neg, const half4_t* __restrict__ usr4,
        const half4_t* __restrict__ ent4, float* __restrict__ dpe,
        float* __restrict__ l1pe) {
    int bx = blockIdx.x, t = threadIdx.x;
    if (bx < ITEMB) {
        item_body(bx, t, off_i, i_pack, ucf, comb_unused, cf_res, cf0f, 0, 1);
    } else {
        int b = (bx - ITEMB) * 4 + (t >> 6);
        loss_ent_body(b, t, user, pos, neg, usr4, ent4, dpe, l1pe);
    }
}

__global__ void finalize_kernel(const float* __restrict__ l1p, const float* __restrict__ l2b,
                                float* __restrict__ out) {
    __shared__ float sb[1024];
    float a1 = 0.f;
    for (int i = threadIdx.x; i < BATCH; i += 1024) a1 += l1p[i];
    float a2 = 0.f;
    for (int i = threadIdx.x; i < ANGB; i += 1024) a2 += l2b[i];
    sb[threadIdx.x] = a1 / (float)BATCH + ANGLE_W * a2 / (float)N_TRIPLETS;
    __syncthreads();
    for (int s = 512; s > 0; s >>= 1) {
        if (threadIdx.x < s) sb[threadIdx.x] += sb[threadIdx.x + s];
        __syncthreads();
    }
    if (threadIdx.x == 0) out[0] = sb[0];
}

extern "C" void kernel_launch(void* const* d_in, const int* in_sizes, int n_in,
                              void* d_out, int out_size, void* d_ws, size_t ws_size,
                              hipStream_t stream) {
    const float* all_embed = (const float*)d_in[0];
    const float* item_cf0  = (const float*)d_in[1];
    const float* relw      = (const float*)d_in[2];
    const float* vals      = (const float*)d_in[3];
    const int* user        = (const int*)d_in[4];
    const int* pos_item    = (const int*)d_in[5];
    const int* neg_item    = (const int*)d_in[6];
    const int* edge_head   = (const int*)d_in[7];
    const int* edge_tail   = edge_head + N_EDGES;
    const int* etype       = (const int*)d_in[8];
    const int* irows       = (const int*)d_in[9];
    const int* icols       = (const int*)d_in[10];
    const int* th          = (const int*)d_in[11];
    const int* tt          = (const int*)d_in[12];
    float* out             = (float*)d_out;

    char* base = (char*)d_ws;
    size_t woff = 0;
    auto alloc = [&](size_t bytes) -> void* {
        void* p = base + woff;
        woff = (woff + bytes + 255) & ~(size_t)255;
        return p;
    };
    half8_t* ent_a   = (half8_t*)alloc((size_t)N_ENTITIES * EMB * 2);
    half8_t* ent_b   = (half8_t*)alloc((size_t)N_ENTITIES * EMB * 2);
    half8_t* comb_a  = (half8_t*)alloc((size_t)N_ITEMS * EMB * 4);
    half8_t* comb_b  = (half8_t*)alloc((size_t)N_ITEMS * EMB * 4);
    half8_t* ucf     = (half8_t*)alloc((size_t)N_USERS * EMB * 2);
    half8_t* ent_res = (half8_t*)alloc((size_t)N_ITEMS * EMB * 2);
    half8_t* usr_res = (half8_t*)alloc((size_t)N_USERS * EMB * 2);
    half8_t* cf_res  = (half8_t*)alloc((size_t)N_ITEMS * EMB * 2);
    int2* u_pack     = (int2*)alloc((size_t)NBUCK * ACAP * 8);
    int2* i_pack     = (int2*)alloc((size_t)NBUCK * ACAP * 8);
    int* kg_pack     = (int*)alloc((size_t)NBUCK * ACAP * 4);
    int* keys_e      = (int*)alloc((size_t)NBUCK * ACAP * 4);
    float* l1p       = (float*)alloc((size_t)BATCH * 4);
    float* dpe       = (float*)alloc((size_t)BATCH * 4);
    float* l1pe      = (float*)alloc((size_t)BATCH * 4);
    float* l2blk     = (float*)alloc((size_t)ANGB * 4);
    int* off_e       = (int*)alloc((size_t)(N_ENTITIES + NBUCK + 1) * 4);
    int* off_u       = (int*)alloc((size_t)(N_USERS + NBUCK + 1) * 4);
    int* off_i       = (int*)alloc((size_t)(N_ITEMS + NBUCK + 1) * 4);
    int* bcur_e      = (int*)alloc(256 * 4);
    int* bcur_u      = (int*)alloc(256 * 4);
    int* bcur_i      = (int*)alloc(256 * 4);

    const float* ent0 = all_embed + (size_t)N_USERS * EMB;

    // 1) conversions + combined table + arena cursors
    prep_kernel<<<CONVE + 2 * CONVI + 1, 256, 0, stream>>>(
        (const float4*)ent0, (const float4*)item_cf0, (half4_t*)ent_a, (half4_t*)comb_a,
        bcur_e, bcur_u, bcur_i);
    // 2) phase 1 placement + angle (overlapped)
    phase1_angle<<<P1B + ANGB, 256, 0, stream>>>(
        edge_head, edge_tail, etype, irows, icols, vals,
        bcur_e, bcur_u, bcur_i, keys_e, kg_pack, u_pack, i_pack,
        ent_a, th, tt, l2blk);
    // 3) phase 2: row offsets + in-bucket ordering
    phase2_all<<<3 * NBUCK, 256, 0, stream>>>(bcur_e, keys_e, kg_pack, off_e,
                                              bcur_u, u_pack, off_u,
                                              bcur_i, i_pack, off_i);
    // 4) kg0 + user0
    fused_h0<<<KGB + USERB, 256, 0, stream>>>(
        off_e, kg_pack, relw, ent_a, ent_b, comb_b, ent_res, (const float4*)ent0,
        off_u, u_pack, comb_a, usr_res, (const float4*)all_embed, ucf);
    // 5) kg1 + item0
    fused_ik<<<KGB + ITEMB, 256, 0, stream>>>(
        off_e, kg_pack, relw, ent_b, ent_a, ent_res, (const float4*)ent0,
        off_i, i_pack, ucf, comb_b, cf_res, (const float4*)item_cf0);
    // 6) user1
    user_h1<<<USERB, 256, 0, stream>>>(off_u, u_pack, comb_b, usr_res,
                                       (const float4*)all_embed, ucf);
    // 7) item1 + loss ent-half
    fused_item_loss<<<ITEMB + LOSSB, 256, 0, stream>>>(
        off_i, i_pack, ucf, comb_a, cf_res, (const float4*)item_cf0,
        user, pos_item, neg_item, (const half4_t*)usr_res, (const half4_t*)ent_res,
        dpe, l1pe);
    // 8) loss cf-half + combine
    loss_cf_kernel<<<LOSSB, 256, 0, stream>>>(user, pos_item, neg_item,
                                              (const half4_t*)usr_res, (const half4_t*)cf_res,
                                              dpe, l1pe, l1p);
    // 9) final reduction
    finalize_kernel<<<1, 1024, 0, stream>>>(l1p, l2blk, out);
}